// Round 11
// baseline (313.444 us; speedup 1.0000x reference)
//
#include <hip/hip_runtime.h>
#include <hip/hip_bf16.h>

#define B_    4
#define KL_   128
#define XL_   4096
#define DIM_  256
#define H_    8
#define HD_   32
#define PB_   8
#define NDIS_ 66
#define TDIM_ 768
#define SCALE_ 0.17677669529663687f
#define NCH2_ 64
#define KC2_  16
#define NS2_  32               // flash x-chunks
#define XC2_  (XL_ / NS2_)     // 128 x per chunk
#define GM_PITCH_ 133

// preamble grid partition
#define NB_CVT_  4096
#define NB_PACK_ 2048
#define NB_WQ_   768
#define NB_WP_   256
#define NB_PP_   1024          // polar 4-bit pack + rp16 pack: B*KL*XL/8/256

typedef float v4f __attribute__((ext_vector_type(4)));
typedef short v8s __attribute__((ext_vector_type(8)));

__device__ __forceinline__ unsigned short f2bf(float f) {
    __hip_bfloat16 h = __float2bfloat16(f);
    return __builtin_bit_cast(unsigned short, h);
}
__device__ __forceinline__ float bf2f(unsigned short u) {
    return __bfloat162float(__builtin_bit_cast(__hip_bfloat16, u));
}
__device__ __forceinline__ void cvt_hilo(float v, unsigned short& hi, unsigned short& lo) {
    hi = f2bf(v);
    lo = f2bf(v - bf2f(hi));
}

// ---------------------------------------------------------------------------
// preamble: pack_mask (ballot, coalesced) + cvt_mat(x) + cvt_wT(W_qkv/W_proj)
//           + {pp4 (4-bit polar) + rp16 (rd|polar<<8)}
// ---------------------------------------------------------------------------
__global__ __launch_bounds__(256) void preamble(const float* __restrict__ x,
                                                const int* __restrict__ att_mask,
                                                const float* __restrict__ W_qkv,
                                                const float* __restrict__ W_proj,
                                                const int* __restrict__ polar_pos,
                                                const int* __restrict__ rd,
                                                unsigned short* __restrict__ xh,
                                                unsigned short* __restrict__ xl,
                                                unsigned int* __restrict__ mbits,
                                                unsigned short* __restrict__ wqh,
                                                unsigned short* __restrict__ wql,
                                                unsigned short* __restrict__ wph,
                                                unsigned short* __restrict__ wpl,
                                                unsigned int* __restrict__ pp4,
                                                unsigned short* __restrict__ rp16) {
    const int bid = blockIdx.x, tid = threadIdx.x;
    if (bid < NB_CVT_) {
        size_t i = (size_t)bid * 256 + tid;
        float4 v = *(const float4*)&x[i * 4];
        ushort4 h, l;
        cvt_hilo(v.x, h.x, l.x);
        cvt_hilo(v.y, h.y, l.y);
        cvt_hilo(v.z, h.z, l.z);
        cvt_hilo(v.w, h.w, l.w);
        *(ushort4*)&xh[i * 4] = h;
        *(ushort4*)&xl[i * 4] = l;
    } else if (bid < NB_CVT_ + NB_PACK_) {
        // ballot pack: lane l loads att_mask[base + i*64 + l] (256B/wave
        // coalesced); ballot bit l == mask bit for that int; 2 u32 words
        // per ballot stored as one uint2 by lane 0. Bit order identical to
        // the per-thread pack (bit = int index mod 32).
        const int w = tid >> 6, lane = tid & 63;
        const size_t ibase = (((size_t)(bid - NB_CVT_) * 4 + w) * 32) * 64;
#pragma unroll
        for (int u = 0; u < 4; ++u) {
            int vals[8];
#pragma unroll
            for (int i = 0; i < 8; ++i)
                vals[i] = att_mask[ibase + (size_t)(u * 8 + i) * 64 + lane];
            unsigned long long bm0 = __ballot(vals[0] != 0);
            unsigned long long bm1 = __ballot(vals[1] != 0);
            unsigned long long bm2 = __ballot(vals[2] != 0);
            unsigned long long bm3 = __ballot(vals[3] != 0);
            unsigned long long bm4 = __ballot(vals[4] != 0);
            unsigned long long bm5 = __ballot(vals[5] != 0);
            unsigned long long bm6 = __ballot(vals[6] != 0);
            unsigned long long bm7 = __ballot(vals[7] != 0);
            if (lane == 0) {
                size_t wb = ibase / 32 + (size_t)u * 16;
                *(uint2*)&mbits[wb + 0]  = make_uint2((unsigned)bm0, (unsigned)(bm0 >> 32));
                *(uint2*)&mbits[wb + 2]  = make_uint2((unsigned)bm1, (unsigned)(bm1 >> 32));
                *(uint2*)&mbits[wb + 4]  = make_uint2((unsigned)bm2, (unsigned)(bm2 >> 32));
                *(uint2*)&mbits[wb + 6]  = make_uint2((unsigned)bm3, (unsigned)(bm3 >> 32));
                *(uint2*)&mbits[wb + 8]  = make_uint2((unsigned)bm4, (unsigned)(bm4 >> 32));
                *(uint2*)&mbits[wb + 10] = make_uint2((unsigned)bm5, (unsigned)(bm5 >> 32));
                *(uint2*)&mbits[wb + 12] = make_uint2((unsigned)bm6, (unsigned)(bm6 >> 32));
                *(uint2*)&mbits[wb + 14] = make_uint2((unsigned)bm7, (unsigned)(bm7 >> 32));
            }
        }
    } else if (bid < NB_CVT_ + NB_PACK_ + NB_WQ_) {
        int n = bid - (NB_CVT_ + NB_PACK_), k = tid;
        float v = W_qkv[(size_t)k * TDIM_ + n];
        unsigned short h, l;
        cvt_hilo(v, h, l);
        wqh[(size_t)n * DIM_ + k] = h;
        wql[(size_t)n * DIM_ + k] = l;
    } else if (bid < NB_CVT_ + NB_PACK_ + NB_WQ_ + NB_WP_) {
        int n = bid - (NB_CVT_ + NB_PACK_ + NB_WQ_), k = tid;
        float v = W_proj[(size_t)k * DIM_ + n];
        unsigned short h, l;
        cvt_hilo(v, h, l);
        wph[(size_t)n * DIM_ + k] = h;
        wpl[(size_t)n * DIM_ + k] = l;
    } else {
        // pp4: 8 polar values -> one u32; rp16: rd | polar<<8 per element
        size_t wid = (size_t)(bid - (NB_CVT_ + NB_PACK_ + NB_WQ_ + NB_WP_)) * 256 + tid;
        const int* srcp = &polar_pos[wid * 8];
        const int* srcr = &rd[wid * 8];
        int4 a = *(const int4*)&srcp[0];
        int4 b4 = *(const int4*)&srcp[4];
        int4 ra = *(const int4*)&srcr[0];
        int4 rb = *(const int4*)&srcr[4];
        unsigned pk = (unsigned)(a.x & 7) | ((unsigned)(a.y & 7) << 4) |
                      ((unsigned)(a.z & 7) << 8) | ((unsigned)(a.w & 7) << 12) |
                      ((unsigned)(b4.x & 7) << 16) | ((unsigned)(b4.y & 7) << 20) |
                      ((unsigned)(b4.z & 7) << 24) | ((unsigned)(b4.w & 7) << 28);
        pp4[wid] = pk;
        unsigned short rp[8];
        rp[0] = (unsigned short)(ra.x | ((a.x & 7) << 8));
        rp[1] = (unsigned short)(ra.y | ((a.y & 7) << 8));
        rp[2] = (unsigned short)(ra.z | ((a.z & 7) << 8));
        rp[3] = (unsigned short)(ra.w | ((a.w & 7) << 8));
        rp[4] = (unsigned short)(rb.x | ((b4.x & 7) << 8));
        rp[5] = (unsigned short)(rb.y | ((b4.y & 7) << 8));
        rp[6] = (unsigned short)(rb.z | ((b4.z & 7) << 8));
        rp[7] = (unsigned short)(rb.w | ((b4.w & 7) << 8));
        *(uint4*)&rp16[wid * 8] = *(uint4*)&rp[0];
    }
}

// ---------------------------------------------------------------------------
// gemm_out: split-bf16 MFMA GEMM -> f32 C (+bias), XCD-swizzled linear grid.
// ---------------------------------------------------------------------------
__global__ __launch_bounds__(256) void gemm_out(const unsigned short* __restrict__ Ah,
                                                const unsigned short* __restrict__ Al,
                                                const unsigned short* __restrict__ Bh,
                                                const unsigned short* __restrict__ Bl,
                                                float* __restrict__ C,
                                                const float* __restrict__ bias,
                                                int M, int N, int K) {
    __shared__ __align__(16) unsigned short Ah_s[128 * 32];
    __shared__ __align__(16) unsigned short Al_s[128 * 32];
    __shared__ __align__(16) unsigned short Bh_s[128 * 32];
    __shared__ __align__(16) unsigned short Bl_s[128 * 32];
    const int tid = threadIdx.x;
    const int w = tid >> 6, lane = tid & 63;
    const int c = lane & 15, q = lane >> 4;

    const int NBX = N >> 7;
    const int id = blockIdx.x;
    const int xcd = id & 7, grp = id >> 3;
    const int bm = ((grp / NBX) * 8 + xcd) * 128;
    const int bn = (grp % NBX) * 128;

    const int lrow = lane >> 2;
    const int lcol = (lane & 3) * 8;

    v4f acc[2][8] = {};
    for (int k0 = 0; k0 < K; k0 += 32) {
        __syncthreads();
#pragma unroll
        for (int i = 0; i < 2; ++i) {
            const int chunk = w * 2 + i;
            const int row = chunk * 16 + lrow;
            const size_t ga = (size_t)(bm + row) * K + k0 + lcol;
            const size_t gb = (size_t)(bn + row) * K + k0 + lcol;
            const int lo = chunk * 512;
            __builtin_amdgcn_global_load_lds(
                (const __attribute__((address_space(1))) unsigned int*)&Ah[ga],
                (__attribute__((address_space(3))) unsigned int*)&Ah_s[lo], 16, 0, 0);
            __builtin_amdgcn_global_load_lds(
                (const __attribute__((address_space(1))) unsigned int*)&Al[ga],
                (__attribute__((address_space(3))) unsigned int*)&Al_s[lo], 16, 0, 0);
            __builtin_amdgcn_global_load_lds(
                (const __attribute__((address_space(1))) unsigned int*)&Bh[gb],
                (__attribute__((address_space(3))) unsigned int*)&Bh_s[lo], 16, 0, 0);
            __builtin_amdgcn_global_load_lds(
                (const __attribute__((address_space(1))) unsigned int*)&Bl[gb],
                (__attribute__((address_space(3))) unsigned int*)&Bl_s[lo], 16, 0, 0);
        }
        asm volatile("s_waitcnt vmcnt(0)" ::: "memory");
        __syncthreads();
        v8s afh[2], afl[2];
#pragma unroll
        for (int mt = 0; mt < 2; ++mt) {
            afh[mt] = *(v8s*)&Ah_s[(w * 32 + mt * 16 + c) * 32 + q * 8];
            afl[mt] = *(v8s*)&Al_s[(w * 32 + mt * 16 + c) * 32 + q * 8];
        }
#pragma unroll
        for (int nt = 0; nt < 8; ++nt) {
            v8s bfh = *(v8s*)&Bh_s[(nt * 16 + c) * 32 + q * 8];
            v8s bfl = *(v8s*)&Bl_s[(nt * 16 + c) * 32 + q * 8];
#pragma unroll
            for (int mt = 0; mt < 2; ++mt) {
                acc[mt][nt] = __builtin_amdgcn_mfma_f32_16x16x32_bf16(afl[mt], bfh, acc[mt][nt], 0, 0, 0);
                acc[mt][nt] = __builtin_amdgcn_mfma_f32_16x16x32_bf16(afh[mt], bfl, acc[mt][nt], 0, 0, 0);
                acc[mt][nt] = __builtin_amdgcn_mfma_f32_16x16x32_bf16(afh[mt], bfh, acc[mt][nt], 0, 0, 0);
            }
        }
    }
#pragma unroll
    for (int mt = 0; mt < 2; ++mt) {
#pragma unroll
        for (int nt = 0; nt < 8; ++nt) {
            int col = bn + nt * 16 + c;
            float bv = bias ? bias[col] : 0.0f;
#pragma unroll
            for (int r = 0; r < 4; ++r) {
                int row = bm + w * 32 + mt * 16 + q * 4 + r;
                C[(size_t)row * N + col] = acc[mt][nt][r] + bv;
            }
        }
    }
}

// ---------------------------------------------------------------------------
// gemm_qkv: typed qkv epilogue. q->qh bf16, k->kh/kl hi/lo (LDS-staged,
// pitch-133), v->VTx bf16 TRANSPOSED [bh][d][x] (ushort4 stores).
// ---------------------------------------------------------------------------
__global__ __launch_bounds__(256) void gemm_qkv(const unsigned short* __restrict__ Ah,
                                                const unsigned short* __restrict__ Al,
                                                const unsigned short* __restrict__ Bh,
                                                const unsigned short* __restrict__ Bl,
                                                int M, int N, int K,
                                                unsigned short* __restrict__ qh,
                                                unsigned short* __restrict__ kh,
                                                unsigned short* __restrict__ kl2,
                                                unsigned short* __restrict__ VTx) {
    __shared__ __align__(16) char SMEM[64 * GM_PITCH_ * 4];
    unsigned short* Ah_s = (unsigned short*)SMEM;
    unsigned short* Al_s = Ah_s + 4096;
    unsigned short* Bh_s = Ah_s + 8192;
    unsigned short* Bl_s = Ah_s + 12288;
    float* scratch = (float*)SMEM;

    const int tid = threadIdx.x;
    const int w = tid >> 6, lane = tid & 63;
    const int c = lane & 15, q = lane >> 4;

    const int NBX = N >> 7;
    const int id = blockIdx.x;
    const int xcd = id & 7, grp = id >> 3;
    const int bm = ((grp / NBX) * 8 + xcd) * 128;
    const int bn = (grp % NBX) * 128;

    const int lrow = lane >> 2;
    const int lcol = (lane & 3) * 8;

    v4f acc[2][8] = {};
    for (int k0 = 0; k0 < K; k0 += 32) {
        __syncthreads();
#pragma unroll
        for (int i = 0; i < 2; ++i) {
            const int chunk = w * 2 + i;
            const int row = chunk * 16 + lrow;
            const size_t ga = (size_t)(bm + row) * K + k0 + lcol;
            const size_t gb = (size_t)(bn + row) * K + k0 + lcol;
            const int lo = chunk * 512;
            __builtin_amdgcn_global_load_lds(
                (const __attribute__((address_space(1))) unsigned int*)&Ah[ga],
                (__attribute__((address_space(3))) unsigned int*)&Ah_s[lo], 16, 0, 0);
            __builtin_amdgcn_global_load_lds(
                (const __attribute__((address_space(1))) unsigned int*)&Al[ga],
                (__attribute__((address_space(3))) unsigned int*)&Al_s[lo], 16, 0, 0);
            __builtin_amdgcn_global_load_lds(
                (const __attribute__((address_space(1))) unsigned int*)&Bh[gb],
                (__attribute__((address_space(3))) unsigned int*)&Bh_s[lo], 16, 0, 0);
            __builtin_amdgcn_global_load_lds(
                (const __attribute__((address_space(1))) unsigned int*)&Bl[gb],
                (__attribute__((address_space(3))) unsigned int*)&Bl_s[lo], 16, 0, 0);
        }
        asm volatile("s_waitcnt vmcnt(0)" ::: "memory");
        __syncthreads();
        v8s afh[2], afl[2];
#pragma unroll
        for (int mt = 0; mt < 2; ++mt) {
            afh[mt] = *(v8s*)&Ah_s[(w * 32 + mt * 16 + c) * 32 + q * 8];
            afl[mt] = *(v8s*)&Al_s[(w * 32 + mt * 16 + c) * 32 + q * 8];
        }
#pragma unroll
        for (int nt = 0; nt < 8; ++nt) {
            v8s bfh = *(v8s*)&Bh_s[(nt * 16 + c) * 32 + q * 8];
            v8s bfl = *(v8s*)&Bl_s[(nt * 16 + c) * 32 + q * 8];
#pragma unroll
            for (int mt = 0; mt < 2; ++mt) {
                acc[mt][nt] = __builtin_amdgcn_mfma_f32_16x16x32_bf16(afl[mt], bfh, acc[mt][nt], 0, 0, 0);
                acc[mt][nt] = __builtin_amdgcn_mfma_f32_16x16x32_bf16(afh[mt], bfl, acc[mt][nt], 0, 0, 0);
                acc[mt][nt] = __builtin_amdgcn_mfma_f32_16x16x32_bf16(afh[mt], bfh, acc[mt][nt], 0, 0, 0);
            }
        }
    }
    if (bn >= 2 * DIM_) {
        // v segment: transposed bf16 store VTx[bh][d][x], 8B chunks
#pragma unroll
        for (int mt = 0; mt < 2; ++mt) {
#pragma unroll
            for (int nt = 0; nt < 8; ++nt) {
                int nn = bn + nt * 16 + c - 2 * DIM_;
                int h = nn >> 5, d = nn & 31;
                int row0 = bm + w * 32 + mt * 16 + q * 4;
                int b = row0 >> 12, x = row0 & (XL_ - 1);
                unsigned short t4[4];
#pragma unroll
                for (int r = 0; r < 4; ++r) t4[r] = f2bf(acc[mt][nt][r]);
                *(ushort4*)&VTx[((size_t)(b * H_ + h) * HD_ + d) * XL_ + x] = *(ushort4*)&t4[0];
            }
        }
    } else {
        for (int mt = 0; mt < 2; ++mt) {
            __syncthreads();
#pragma unroll
            for (int nt = 0; nt < 8; ++nt)
#pragma unroll
                for (int r = 0; r < 4; ++r)
                    scratch[(w * 16 + q * 4 + r) * GM_PITCH_ + nt * 16 + c] = acc[mt][nt][r];
            __syncthreads();
            const int or_ = tid & 63, oc = (tid >> 6) * 32;
            const int grow = bm + (or_ >> 4) * 32 + mt * 16 + (or_ & 15);
            const float* src = &scratch[or_ * GM_PITCH_ + oc];
            if (bn < DIM_) {
                unsigned short* dst = &qh[(size_t)grow * DIM_ + bn + oc];
#pragma unroll
                for (int j4 = 0; j4 < 4; ++j4) {
                    unsigned short tmp[8];
#pragma unroll
                    for (int j = 0; j < 8; ++j) tmp[j] = f2bf(src[j4 * 8 + j]);
                    *(uint4*)&dst[j4 * 8] = *(uint4*)&tmp[0];
                }
            } else {
                const size_t o = (size_t)grow * DIM_ + bn - DIM_ + oc;
#pragma unroll
                for (int j4 = 0; j4 < 4; ++j4) {
                    unsigned short th[8], tl[8];
#pragma unroll
                    for (int j = 0; j < 8; ++j) cvt_hilo(src[j4 * 8 + j], th[j], tl[j]);
                    *(uint4*)&kh[o + j4 * 8] = *(uint4*)&th[0];
                    *(uint4*)&kl2[o + j4 * 8] = *(uint4*)&tl[0];
                }
            }
        }
    }
}

// ---------------------------------------------------------------------------
// 64x64 f32 GEMM (small-M) — proj path
// ---------------------------------------------------------------------------
__global__ __launch_bounds__(256) void gemm64(const float* __restrict__ A,
                                              const float* __restrict__ Bw,
                                              float* __restrict__ C,
                                              const float* __restrict__ bias,
                                              int M, int N, int K) {
    __shared__ __align__(16) float As[16][68];
    __shared__ __align__(16) float Bs[16][64];
    const int tid = threadIdx.x;
    const int tx = tid & 15, ty = tid >> 4;
    const int bn = blockIdx.x * 64, bm = blockIdx.y * 64;
    const int am = tid >> 2, ac = tid & 3;
    float acc[4][4] = {};
    for (int k0 = 0; k0 < K; k0 += 16) {
        float4 a4 = *(const float4*)&A[(size_t)(bm + am) * K + k0 + ac * 4];
        As[ac * 4 + 0][am] = a4.x;
        As[ac * 4 + 1][am] = a4.y;
        As[ac * 4 + 2][am] = a4.z;
        As[ac * 4 + 3][am] = a4.w;
        *(float4*)&Bs[ty][tx * 4] = *(const float4*)&Bw[(size_t)(k0 + ty) * N + bn + tx * 4];
        __syncthreads();
#pragma unroll
        for (int kk = 0; kk < 16; ++kk) {
            float4 av = *(const float4*)&As[kk][ty * 4];
            float4 bv = *(const float4*)&Bs[kk][tx * 4];
            float a[4] = {av.x, av.y, av.z, av.w};
            float b[4] = {bv.x, bv.y, bv.z, bv.w};
#pragma unroll
            for (int i = 0; i < 4; ++i)
#pragma unroll
                for (int j = 0; j < 4; ++j) acc[i][j] += a[i] * b[j];
        }
        __syncthreads();
    }
#pragma unroll
    for (int i = 0; i < 4; ++i) {
        int m = bm + ty * 4 + i;
#pragma unroll
        for (int j = 0; j < 4; ++j) {
            int n = bn + tx * 4 + j;
            float v = acc[i][j];
            if (bias) v += bias[n];
            C[(size_t)m * N + n] = v;
        }
    }
}

// ---------------------------------------------------------------------------
// gemm64_qkv: kernal @ W_qkv with typed epilogue (unchanged)
// ---------------------------------------------------------------------------
__global__ __launch_bounds__(256) void gemm64_qkv(const float* __restrict__ A,
                                                  const float* __restrict__ Bw,
                                                  unsigned short* __restrict__ Kqh,
                                                  unsigned short* __restrict__ Kql,
                                                  unsigned short* __restrict__ Kk_bf,
                                                  unsigned short* __restrict__ VT_bf,
                                                  int M, int N, int K) {
    __shared__ __align__(16) float As[16][68];
    __shared__ __align__(16) float Bs[16][64];
    const int tid = threadIdx.x;
    const int tx = tid & 15, ty = tid >> 4;
    const int bn = blockIdx.x * 64, bm = blockIdx.y * 64;
    const int am = tid >> 2, ac = tid & 3;
    float acc[4][4] = {};
    for (int k0 = 0; k0 < K; k0 += 16) {
        float4 a4 = *(const float4*)&A[(size_t)(bm + am) * K + k0 + ac * 4];
        As[ac * 4 + 0][am] = a4.x;
        As[ac * 4 + 1][am] = a4.y;
        As[ac * 4 + 2][am] = a4.z;
        As[ac * 4 + 3][am] = a4.w;
        *(float4*)&Bs[ty][tx * 4] = *(const float4*)&Bw[(size_t)(k0 + ty) * N + bn + tx * 4];
        __syncthreads();
#pragma unroll
        for (int kk = 0; kk < 16; ++kk) {
            float4 av = *(const float4*)&As[kk][ty * 4];
            float4 bv = *(const float4*)&Bs[kk][tx * 4];
            float a[4] = {av.x, av.y, av.z, av.w};
            float b[4] = {bv.x, bv.y, bv.z, bv.w};
#pragma unroll
            for (int i = 0; i < 4; ++i)
#pragma unroll
                for (int j = 0; j < 4; ++j) acc[i][j] += a[i] * b[j];
        }
        __syncthreads();
    }
#pragma unroll
    for (int i = 0; i < 4; ++i) {
        int m = bm + ty * 4 + i;
        int b = m >> 7, k = m & 127;
#pragma unroll
        for (int j = 0; j < 4; ++j) {
            int n = bn + tx * 4 + j;
            float v = acc[i][j];
            if (n < DIM_) {
                unsigned short hi, lo;
                cvt_hilo(v, hi, lo);
                int h = n >> 5, d = n & 31;
                size_t o = ((size_t)(b * H_ + h) * KL_ + k) * HD_ + d;
                Kqh[o] = hi;
                Kql[o] = lo;
            } else if (n < 2 * DIM_) {
                int nn = n - DIM_, h = nn >> 5, d = nn & 31;
                Kk_bf[((size_t)(b * H_ + h) * KL_ + k) * HD_ + d] = f2bf(v);
            } else {
                int nn = n - 2 * DIM_, h = nn >> 5, d = nn & 31;
                VT_bf[((size_t)(b * H_ + h) * HD_ + d) * KL_ + k] = f2bf(v);
            }
        }
    }
}

// ===========================================================================
// K1 v11: rp16 packed rd|polar loads (unchanged)
// ===========================================================================
__global__ __launch_bounds__(256) void score_bins_mfma4(const unsigned short* __restrict__ kxh,
                                                        const unsigned short* __restrict__ kxl,
                                                        const unsigned short* __restrict__ Kqh_g,
                                                        const unsigned short* __restrict__ Kql_g,
                                                        const unsigned short* __restrict__ rp16,
                                                        const unsigned int* __restrict__ mbits,
                                                        const float* __restrict__ dis_embed,
                                                        __hip_bfloat16* __restrict__ Sg,
                                                        float* __restrict__ binspart) {
    const int b = blockIdx.z, h = blockIdx.y, xc = blockIdx.x;
    const int x0 = xc * 64;
    const int tid = threadIdx.x;
    const int w = tid >> 6, lane = tid & 63;
    const int c15 = lane & 15, q = lane >> 4;
    const size_t bh = (size_t)(b * H_ + h);

    __shared__ unsigned int mskb[64][5];
    __shared__ float de_h[NDIS_];
    __shared__ float binsL[8][4][16][PB_ + 1];
    __shared__ __align__(16) unsigned short Ss[2][16][72];

    {
        int xr = tid >> 2, kg = tid & 3;
        mskb[xr][kg] = mbits[(bh * XL_ + x0 + xr) * 4 + kg];
    }
    if (tid < NDIS_) de_h[tid] = dis_embed[tid * H_ + h];
    __syncthreads();

    v8s axh, axl;
    {
        const size_t aoff = ((size_t)b * XL_ + x0 + w * 16 + c15) * DIM_ + h * HD_ + q * 8;
        axh = *(const v8s*)&kxh[aoff];
        axl = *(const v8s*)&kxl[aoff];
    }

    v8s bqh[2], bql[2];
    uint2 rp2[2];
    auto load_nt = [&](int nt, int s) {
        const int k = nt * 16 + c15;
        const size_t kqoff = (bh * KL_ + k) * HD_ + q * 8;
        bqh[s] = *(const v8s*)&Kqh_g[kqoff];
        bql[s] = *(const v8s*)&Kql_g[kqoff];
        const size_t rowoff = ((size_t)(b * KL_ + k)) * XL_ + x0 + w * 16 + q * 4;
        rp2[s] = *(const uint2*)&rp16[rowoff];
    };
    load_nt(0, 0);

#pragma unroll
    for (int nt = 0; nt < 8; ++nt) {
        const int s = nt & 1;
        if (nt < 7) load_nt(nt + 1, s ^ 1);

        const int k = nt * 16 + c15;
        v4f D = {0.f, 0.f, 0.f, 0.f};
        D = __builtin_amdgcn_mfma_f32_16x16x32_bf16(axl, bqh[s], D, 0, 0, 0);
        D = __builtin_amdgcn_mfma_f32_16x16x32_bf16(axh, bql[s], D, 0, 0, 0);
        D = __builtin_amdgcn_mfma_f32_16x16x32_bf16(axh, bqh[s], D, 0, 0, 0);

        float bins[PB_] = {};
        {
            const unsigned short* rpv = (const unsigned short*)&rp2[s];
            ushort4 pack;
#pragma unroll
            for (int r = 0; r < 4; ++r) {
                float sc = D[r] * SCALE_;
                float a = fabsf(sc);
                int pv = (rpv[r] >> 8) & 7;
#pragma unroll
                for (int pb = 0; pb < PB_; ++pb) bins[pb] += (pv == pb) ? a : 0.0f;
                int xloc = w * 16 + q * 4 + r;
                int mbit = (mskb[xloc][k >> 5] >> (k & 31)) & 1;
                float sp = (mbit ? -1e6f : sc) + de_h[rpv[r] & 0x7F];
                ((unsigned short*)&pack)[r] = f2bf(sp);
            }
            *(ushort4*)&Ss[s][c15][w * 16 + q * 4] = pack;
        }

#pragma unroll
        for (int pb = 0; pb < PB_; ++pb) {
            bins[pb] += __shfl_xor(bins[pb], 16);
            bins[pb] += __shfl_xor(bins[pb], 32);
        }
        if (q == 0) {
#pragma unroll
            for (int pb = 0; pb < PB_; ++pb) binsL[nt][w][c15][pb] = bins[pb];
        }

        __syncthreads();
        {
            int row = tid >> 4, seg = tid & 15;
            unsigned short* dst = (unsigned short*)Sg +
                (bh * KL_ + nt * 16 + row) * XL_ + x0 + seg * 4;
            *(uint2*)dst = *(const uint2*)&Ss[s][row][seg * 4];
        }
    }
    __syncthreads();
    {
        int k = tid >> 1, half = tid & 1;
        int nt = k >> 4, c = k & 15;
        float4 s = {0.f, 0.f, 0.f, 0.f};
#pragma unroll
        for (int w4 = 0; w4 < 4; ++w4) {
            const float* bp = &binsL[nt][w4][c][half * 4];
            s.x += bp[0]; s.y += bp[1]; s.z += bp[2]; s.w += bp[3];
        }
        *(float4*)&binspart[(bh * KL_ + k) * (NCH2_ * PB_) + xc * PB_ + half * 4] = s;
    }
}

// K2: argmax (unchanged)
__global__ __launch_bounds__(256) void bins_argmax(const float* __restrict__ binspart,
                                                   int* __restrict__ main_ori) {
    const int w = threadIdx.x >> 6, lane = threadIdx.x & 63;
    const int row = blockIdx.x * 4 + w;
    float s[PB_];
#pragma unroll
    for (int pb = 0; pb < PB_; ++pb) s[pb] = 0.0f;
    if (lane < NCH2_) {
        const float* bp = &binspart[(size_t)row * (NCH2_ * PB_) + lane * PB_];
#pragma unroll
        for (int pb = 0; pb < PB_; ++pb) s[pb] = bp[pb];
    }
#pragma unroll
    for (int m = 1; m < 64; m <<= 1)
#pragma unroll
        for (int pb = 0; pb < PB_; ++pb) s[pb] += __shfl_xor(s[pb], m);
    if (lane == 0) {
        float best = s[0];
        int bi = 0;
#pragma unroll
        for (int pb = 1; pb < PB_; ++pb)
            if (s[pb] > best) { best = s[pb]; bi = pb; }
        main_ori[row] = bi;
    }
}

// ===========================================================================
// K3 v4: flash_mfma (unchanged)
// ===========================================================================
__global__ __launch_bounds__(256) void flash_mfma(const __hip_bfloat16* __restrict__ Sg,
                                                  const unsigned int* __restrict__ pp4,
                                                  const unsigned short* __restrict__ VTx,
                                                  const float* __restrict__ polar_emb,
                                                  const int* __restrict__ main_ori,
                                                  float* __restrict__ part) {
    const int b = blockIdx.z, h = blockIdx.y, xc = blockIdx.x;
    const int tid = threadIdx.x;
    const int w = tid >> 6, lane = tid & 63;
    const int c = lane & 15, q = lane >> 4;
    const size_t bh = (size_t)(b * H_ + h);
    const int xbeg = xc * XC2_;

    __shared__ int mo_s[KL_];
    __shared__ float pe_s[PB_];
    if (tid < KL_) mo_s[tid] = main_ori[bh * KL_ + tid];
    if (tid < PB_) pe_s[tid] = polar_emb[tid];
    __syncthreads();

    const int wk0 = w * 32;
    const int mo[2] = {mo_s[wk0 + c], mo_s[wk0 + 16 + c]};
    const unsigned short* SgU = (const unsigned short*)Sg;

    v4f acc[2][2] = {};
    float lsum[2] = {0.f, 0.f};

    for (int s = 0; s < XC2_ / 32; ++s) {
        const int xs = xbeg + s * 32;
        v8s pa[2];
#pragma unroll
        for (int kt = 0; kt < 2; ++kt) {
            const int k = wk0 + kt * 16 + c;
            v8s sv = *(const v8s*)&SgU[(bh * KL_ + k) * XL_ + xs + q * 8];
            unsigned pw = pp4[((size_t)(b * KL_ + k)) * (XL_ / 8) + (xs >> 3) + q];
            unsigned short pk[8];
#pragma unroll
            for (int j = 0; j < 8; ++j) {
                float sp = bf2f((unsigned short)sv[j]);
                int np = (((int)(pw >> (j * 4)) & 7) - mo[kt]) & 7;
                float p = __expf(sp + pe_s[np]);
                unsigned short pb = f2bf(p);
                pk[j] = pb;
                lsum[kt] += bf2f(pb);
            }
            pa[kt] = *(v8s*)pk;
        }
#pragma unroll
        for (int dt = 0; dt < 2; ++dt) {
            v8s bv = *(const v8s*)&VTx[((size_t)bh * HD_ + dt * 16 + c) * XL_ + xs + q * 8];
            acc[0][dt] = __builtin_amdgcn_mfma_f32_16x16x32_bf16(pa[0], bv, acc[0][dt], 0, 0, 0);
            acc[1][dt] = __builtin_amdgcn_mfma_f32_16x16x32_bf16(pa[1], bv, acc[1][dt], 0, 0, 0);
        }
    }

#pragma unroll
    for (int kt = 0; kt < 2; ++kt) {
        lsum[kt] += __shfl_xor(lsum[kt], 16);
        lsum[kt] += __shfl_xor(lsum[kt], 32);
    }
#pragma unroll
    for (int kt = 0; kt < 2; ++kt) {
#pragma unroll
        for (int dt = 0; dt < 2; ++dt) {
#pragma unroll
            for (int r = 0; r < 4; ++r) {
                int krow = wk0 + kt * 16 + q * 4 + r;
                part[((size_t)(bh * KL_ + krow) * NS2_ + xc) * 36 + dt * 16 + c] = acc[kt][dt][r];
            }
        }
        if (q == 0) {
            int krow = wk0 + kt * 16 + c;
            part[((size_t)(bh * KL_ + krow) * NS2_ + xc) * 36 + 32] = lsum[kt];
        }
    }
}

// K4: merge over NS2_ chunks
__global__ __launch_bounds__(256) void merge_cached(const float* __restrict__ part,
                                                    float* __restrict__ kout_pre) {
    const int tid = threadIdx.x;
    const int ri = tid >> 5, d = tid & 31;
    const int row = blockIdx.x * 8 + ri;
    float l = 0.f, a = 0.f;
#pragma unroll 4
    for (int c = 0; c < NS2_; ++c) {
        const float* p = &part[((size_t)row * NS2_ + c) * 36];
        l += p[32];
        a += p[d];
    }
    int k = row & (KL_ - 1);
    int bh = row >> 7;
    int h = bh & (H_ - 1), b = bh >> 3;
    kout_pre[(size_t)(b * KL_ + k) * DIM_ + h * HD_ + d] = a / l;
}

// ===========================================================================
// attn_x_mfma v5 (unchanged)
// ===========================================================================
__global__ __launch_bounds__(256) void attn_x_mfma(const unsigned short* __restrict__ qxh,
                                                   const unsigned short* __restrict__ Kk_bf,
                                                   const unsigned short* __restrict__ VT_bf,
                                                   const unsigned short* __restrict__ rp16,
                                                   const unsigned int* __restrict__ mbits,
                                                   const float* __restrict__ dis_embed,
                                                   const float* __restrict__ polar_emb,
                                                   const int* __restrict__ main_ori,
                                                   unsigned short* __restrict__ oh,
                                                   unsigned short* __restrict__ ol) {
    const int b = blockIdx.z, h = blockIdx.y;
    const int x0 = blockIdx.x * 64;
    const int tid = threadIdx.x;
    const int wave = tid >> 6, lane = tid & 63;
    const int c = lane & 15, q = lane >> 4;

    __shared__ __align__(16) unsigned short P_s[4][16][136];
    __shared__ unsigned short rp_s[KL_][72];
    __shared__ unsigned int msk_s[64][5];
    __shared__ float de_h[NDIS_];
    __shared__ float pe[PB_];
    __shared__ int mo_s[KL_];

    const size_t bh = (size_t)(b * H_ + h);
    if (tid < NDIS_) de_h[tid] = dis_embed[tid * H_ + h];
    if (tid < PB_) pe[tid] = polar_emb[tid];
    if (tid < KL_) mo_s[tid] = main_ori[bh * KL_ + tid];
    {
        int xr = tid >> 2, kg = tid & 3;
        msk_s[xr][kg] = mbits[(bh * XL_ + x0 + xr) * 4 + kg];
    }
    __syncthreads();

#pragma unroll
    for (int i = 0; i < 8; ++i) {
        int id = tid + 256 * i;          // 2048 chunks of 4 u16
        int k = id >> 4, ch = id & 15;
        uint2 v = *(const uint2*)&rp16[((size_t)(b * KL_ + k)) * XL_ + x0 + ch * 4];
        int mo = mo_s[k];
        const unsigned short* pv = (const unsigned short*)&v;
        unsigned short outv[4];
#pragma unroll
        for (int j = 0; j < 4; ++j) {
            int np = (((pv[j] >> 8) & 7) - mo) & 7;
            outv[j] = (unsigned short)((pv[j] & 0x7F) | (np << 8));
        }
        *(uint2*)&rp_s[k][ch * 4] = *(uint2*)&outv[0];
    }
    __syncthreads();

    v8s aq = *(const v8s*)&qxh[(size_t)(b * XL_ + x0 + wave * 16 + c) * DIM_ + h * HD_ + q * 8];

    const unsigned short* KkB = &Kk_bf[(size_t)bh * KL_ * HD_];
    v4f S[8];
#pragma unroll
    for (int t = 0; t < 8; ++t) {
        v8s bk = *(const v8s*)&KkB[(size_t)(t * 16 + c) * HD_ + q * 8];
        S[t] = __builtin_amdgcn_mfma_f32_16x16x32_bf16(aq, bk, (v4f){0.f, 0.f, 0.f, 0.f}, 0, 0, 0);
    }

    const int xloc = wave * 16;
    float lr[4] = {0.f, 0.f, 0.f, 0.f};
#pragma unroll
    for (int t = 0; t < 8; ++t) {
#pragma unroll
        for (int r = 0; r < 4; ++r) {
            int krow = t * 16 + c;
            int xrow = q * 4 + r;
            unsigned short rp = rp_s[krow][xloc + xrow];
            int mbit = (msk_s[xloc + xrow][krow >> 5] >> (krow & 31)) & 1;
            float sval = S[t][r] * SCALE_;
            float tval = (mbit ? -25.0f : sval) + de_h[rp & 0x7f] + pe[(rp >> 8) & 7];
            float p = __expf(tval);
            unsigned short pb = f2bf(p);
            P_s[wave][xrow][krow] = pb;
            lr[r] += bf2f(pb);
        }
    }
#pragma unroll
    for (int r = 0; r < 4; ++r) {
#pragma unroll
        for (int m = 1; m < 16; m <<= 1) lr[r] += __shfl_xor(lr[r], m);
    }
    __syncthreads();

    const unsigned short* VTB = &VT_bf[(size_t)bh * HD_ * KL_];
    v4f O0 = {0.f, 0.f, 0.f, 0.f}, O1 = {0.f, 0.f, 0.f, 0.f};
#pragma unroll
    for (int kc = 0; kc < 4; ++kc) {
        v8s ap = *(v8s*)&P_s[wave][c][kc * 32 + q * 8];
        v8s bv0 = *(const v8s*)&VTB[(size_t)c * KL_ + kc * 32 + q * 8];
        v8s bv1 = *(const v8s*)&VTB[(size_t)(16 + c) * KL_ + kc * 32 + q * 8];
        O0 = __builtin_amdgcn_mfma_f32_16x16x32_bf16(ap, bv0, O0, 0, 0, 0);
        O1 = __builtin_amdgcn_mfma_f32_16x16x32_bf16(ap, bv1, O1, 0, 0, 0);
    }

#pragma unroll
    for (int r = 0; r < 4; ++r) {
        int xg = x0 + wave * 16 + q * 4 + r;
        float inv = 1.0f / lr[r];
        size_t obase = (size_t)(b * XL_ + xg) * DIM_ + h * HD_;
        float v0 = O0[r] * inv;
        float v1 = O1[r] * inv;
        unsigned short h0, l0, h1, l1;
        cvt_hilo(v0, h0, l0);
        cvt_hilo(v1, h1, l1);
        oh[obase + c] = h0;
        ol[obase + c] = l0;
        oh[obase + 16 + c] = h1;
        ol[obase + 16 + c] = l1;
    }
}

// ---------------------------------------------------------------------------
extern "C" void kernel_launch(void* const* d_in, const int* in_sizes, int n_in,
                              void* d_out, int out_size, void* d_ws, size_t ws_size,
                              hipStream_t stream) {
    const float* x         = (const float*)d_in[0];
    const float* kernal    = (const float*)d_in[1];
    const int* rd          = (const int*)d_in[2];
    const int* polar_pos   = (const int*)d_in[3];
    const int* att_mask    = (const int*)d_in[4];
    const float* W_qkv     = (const float*)d_in[5];
    const float* dis_embed = (const float*)d_in[6];
    const float* polar_emb = (const float*)d_in[7];
    const float* W_proj    = (const float*)d_in[8];
    const float* b_proj    = (const float*)d_in[9];
    float* out             = (float*)d_out;

    char* base = (char*)d_ws;
    size_t off = 0;
    auto alloc = [&](size_t bytes) { void* p = base + off; off = (off + bytes + 255) & ~255ULL; return p; };
    const size_t MX = (size_t)B_ * XL_;

    unsigned short* VTx = (unsigned short*)alloc((size_t)B_ * H_ * HD_ * XL_ * 2);
    unsigned short* qxh = (unsigned short*)alloc(MX * DIM_ * 2);
    unsigned short* kxh = (unsigned short*)alloc(MX * DIM_ * 2);
    unsigned short* kxl = (unsigned short*)alloc(MX * DIM_ * 2);
    float* binspart  = (float*)alloc((size_t)B_ * H_ * KL_ * NCH2_ * PB_ * 4);
    float* kout_pre  = (float*)alloc((size_t)B_ * KL_ * DIM_ * 4);
    int* main_ori    = (int*)alloc(B_ * H_ * KL_ * 4);
    float* part      = (float*)alloc((size_t)B_ * H_ * KL_ * NS2_ * 36 * 4);
    __hip_bfloat16* Sg = (__hip_bfloat16*)alloc((size_t)B_ * H_ * KL_ * XL_ * 2);
    unsigned short* wph = (unsigned short*)alloc((size_t)DIM_ * DIM_ * 2);
    unsigned short* wpl = (unsigned short*)alloc((size_t)DIM_ * DIM_ * 2);
    unsigned short* wqh = (unsigned short*)alloc((size_t)TDIM_ * DIM_ * 2);
    unsigned short* wql = (unsigned short*)alloc((size_t)TDIM_ * DIM_ * 2);
    unsigned int* mbits = (unsigned int*)alloc((size_t)B_ * H_ * XL_ * (KL_ / 32) * 4);
    unsigned int* pp4   = (unsigned int*)alloc((size_t)B_ * KL_ * (XL_ / 8) * 4);
    unsigned short* rp16 = (unsigned short*)alloc((size_t)B_ * KL_ * XL_ * 2);
    unsigned short* Kqh_g = (unsigned short*)alloc((size_t)B_ * H_ * KL_ * HD_ * 2);
    unsigned short* Kql_g = (unsigned short*)alloc((size_t)B_ * H_ * KL_ * HD_ * 2);
    unsigned short* Kk_bf = (unsigned short*)alloc((size_t)B_ * H_ * KL_ * HD_ * 2);
    unsigned short* VT_bf = (unsigned short*)alloc((size_t)B_ * H_ * HD_ * KL_ * 2);

    // aliases into Sg region (xh/xl consumed by qkv gemm before Sg written;
    // oh/ol written by attn_x after flash has consumed Sg)
    unsigned short* xh = (unsigned short*)Sg;
    unsigned short* xl_ = xh + MX * DIM_;
    unsigned short* oh = (unsigned short*)Sg;
    unsigned short* ol = oh + MX * DIM_;

    // --- fused preamble (1 launch) ---
    preamble<<<dim3(NB_CVT_ + NB_PACK_ + NB_WQ_ + NB_WP_ + NB_PP_), 256, 0, stream>>>(
        x, att_mask, W_qkv, W_proj, polar_pos, rd, xh, xl_, mbits, wqh, wql, wph, wpl, pp4, rp16);

    // --- qkv projections ---
    gemm_qkv<<<dim3((TDIM_ / 128) * (MX / 128)), 256, 0, stream>>>(
        xh, xl_, wqh, wql, MX, TDIM_, DIM_, qxh, kxh, kxl, VTx);
    gemm64_qkv<<<dim3(TDIM_ / 64, (B_ * KL_) / 64), 256, 0, stream>>>(
        kernal, W_qkv, Kqh_g, Kql_g, Kk_bf, VT_bf, B_ * KL_, TDIM_, DIM_);

    // --- k-direction ---
    score_bins_mfma4<<<dim3(NCH2_, H_, B_), 256, 0, stream>>>(
        kxh, kxl, Kqh_g, Kql_g, rp16, mbits, dis_embed, Sg, binspart);
    bins_argmax<<<dim3(B_ * H_ * KL_ / 4), 256, 0, stream>>>(binspart, main_ori);
    flash_mfma<<<dim3(NS2_, H_, B_), 256, 0, stream>>>(
        Sg, pp4, VTx, polar_emb, main_ori, part);
    merge_cached<<<dim3(B_ * H_ * KL_ / 8), 256, 0, stream>>>(part, kout_pre);

    // --- x-direction ---
    attn_x_mfma<<<dim3(XL_ / 64, H_, B_), 256, 0, stream>>>(
        qxh, Kk_bf, VT_bf, rp16, mbits, dis_embed, polar_emb, main_ori, oh, ol);

    // --- output projections ---
    gemm_out<<<dim3((DIM_ / 128) * (MX / 128)), 256, 0, stream>>>(
        oh, ol, wph, wpl, out, b_proj, MX, DIM_, DIM_);
    gemm64<<<dim3(DIM_ / 64, (B_ * KL_) / 64), 256, 0, stream>>>(
        kout_pre, W_proj, out + (size_t)B_ * XL_ * DIM_, b_proj, B_ * KL_, DIM_, DIM_);
}

// Round 12
// 313.309 us; speedup vs baseline: 1.0004x; 1.0004x over previous
//
#include <hip/hip_runtime.h>
#include <hip/hip_bf16.h>

#define B_    4
#define KL_   128
#define XL_   4096
#define DIM_  256
#define H_    8
#define HD_   32
#define PB_   8
#define NDIS_ 66
#define TDIM_ 768
#define SCALE_ 0.17677669529663687f
#define NCH2_ 64
#define KC2_  16
#define NS2_  32               // flash x-chunks
#define XC2_  (XL_ / NS2_)     // 128 x per chunk
#define GM_PITCH_ 133

// preamble grid partition (cvt partition removed: x converted inside gemm_qkv)
#define NB_PACK_ 2048
#define NB_WQ_   768
#define NB_WP_   256
#define NB_PP_   1024          // polar 4-bit pack + rp16 pack: B*KL*XL/8/256

typedef float v4f __attribute__((ext_vector_type(4)));
typedef short v8s __attribute__((ext_vector_type(8)));

__device__ __forceinline__ unsigned short f2bf(float f) {
    __hip_bfloat16 h = __float2bfloat16(f);
    return __builtin_bit_cast(unsigned short, h);
}
__device__ __forceinline__ float bf2f(unsigned short u) {
    return __bfloat162float(__builtin_bit_cast(__hip_bfloat16, u));
}
__device__ __forceinline__ void cvt_hilo(float v, unsigned short& hi, unsigned short& lo) {
    hi = f2bf(v);
    lo = f2bf(v - bf2f(hi));
}

// ---------------------------------------------------------------------------
// preamble: pack_mask (ballot) + cvt_wT(W_qkv/W_proj) + {pp4 + rp16}
// ---------------------------------------------------------------------------
__global__ __launch_bounds__(256) void preamble(const int* __restrict__ att_mask,
                                                const float* __restrict__ W_qkv,
                                                const float* __restrict__ W_proj,
                                                const int* __restrict__ polar_pos,
                                                const int* __restrict__ rd,
                                                unsigned int* __restrict__ mbits,
                                                unsigned short* __restrict__ wqh,
                                                unsigned short* __restrict__ wql,
                                                unsigned short* __restrict__ wph,
                                                unsigned short* __restrict__ wpl,
                                                unsigned int* __restrict__ pp4,
                                                unsigned short* __restrict__ rp16) {
    const int bid = blockIdx.x, tid = threadIdx.x;
    if (bid < NB_PACK_) {
        // ballot pack: lane l loads att_mask[base + i*64 + l] (coalesced);
        // ballot bit l == mask bit; bit order identical to per-thread pack.
        const int w = tid >> 6, lane = tid & 63;
        const size_t ibase = (((size_t)bid * 4 + w) * 32) * 64;
#pragma unroll
        for (int u = 0; u < 4; ++u) {
            int vals[8];
#pragma unroll
            for (int i = 0; i < 8; ++i)
                vals[i] = att_mask[ibase + (size_t)(u * 8 + i) * 64 + lane];
            unsigned long long bm0 = __ballot(vals[0] != 0);
            unsigned long long bm1 = __ballot(vals[1] != 0);
            unsigned long long bm2 = __ballot(vals[2] != 0);
            unsigned long long bm3 = __ballot(vals[3] != 0);
            unsigned long long bm4 = __ballot(vals[4] != 0);
            unsigned long long bm5 = __ballot(vals[5] != 0);
            unsigned long long bm6 = __ballot(vals[6] != 0);
            unsigned long long bm7 = __ballot(vals[7] != 0);
            if (lane == 0) {
                size_t wb = ibase / 32 + (size_t)u * 16;
                *(uint2*)&mbits[wb + 0]  = make_uint2((unsigned)bm0, (unsigned)(bm0 >> 32));
                *(uint2*)&mbits[wb + 2]  = make_uint2((unsigned)bm1, (unsigned)(bm1 >> 32));
                *(uint2*)&mbits[wb + 4]  = make_uint2((unsigned)bm2, (unsigned)(bm2 >> 32));
                *(uint2*)&mbits[wb + 6]  = make_uint2((unsigned)bm3, (unsigned)(bm3 >> 32));
                *(uint2*)&mbits[wb + 8]  = make_uint2((unsigned)bm4, (unsigned)(bm4 >> 32));
                *(uint2*)&mbits[wb + 10] = make_uint2((unsigned)bm5, (unsigned)(bm5 >> 32));
                *(uint2*)&mbits[wb + 12] = make_uint2((unsigned)bm6, (unsigned)(bm6 >> 32));
                *(uint2*)&mbits[wb + 14] = make_uint2((unsigned)bm7, (unsigned)(bm7 >> 32));
            }
        }
    } else if (bid < NB_PACK_ + NB_WQ_) {
        int n = bid - NB_PACK_, k = tid;
        float v = W_qkv[(size_t)k * TDIM_ + n];
        unsigned short h, l;
        cvt_hilo(v, h, l);
        wqh[(size_t)n * DIM_ + k] = h;
        wql[(size_t)n * DIM_ + k] = l;
    } else if (bid < NB_PACK_ + NB_WQ_ + NB_WP_) {
        int n = bid - (NB_PACK_ + NB_WQ_), k = tid;
        float v = W_proj[(size_t)k * DIM_ + n];
        unsigned short h, l;
        cvt_hilo(v, h, l);
        wph[(size_t)n * DIM_ + k] = h;
        wpl[(size_t)n * DIM_ + k] = l;
    } else {
        // pp4: 8 polar values -> one u32; rp16: rd | polar<<8 per element
        size_t wid = (size_t)(bid - (NB_PACK_ + NB_WQ_ + NB_WP_)) * 256 + tid;
        const int* srcp = &polar_pos[wid * 8];
        const int* srcr = &rd[wid * 8];
        int4 a = *(const int4*)&srcp[0];
        int4 b4 = *(const int4*)&srcp[4];
        int4 ra = *(const int4*)&srcr[0];
        int4 rb = *(const int4*)&srcr[4];
        unsigned pk = (unsigned)(a.x & 7) | ((unsigned)(a.y & 7) << 4) |
                      ((unsigned)(a.z & 7) << 8) | ((unsigned)(a.w & 7) << 12) |
                      ((unsigned)(b4.x & 7) << 16) | ((unsigned)(b4.y & 7) << 20) |
                      ((unsigned)(b4.z & 7) << 24) | ((unsigned)(b4.w & 7) << 28);
        pp4[wid] = pk;
        unsigned short rp[8];
        rp[0] = (unsigned short)(ra.x | ((a.x & 7) << 8));
        rp[1] = (unsigned short)(ra.y | ((a.y & 7) << 8));
        rp[2] = (unsigned short)(ra.z | ((a.z & 7) << 8));
        rp[3] = (unsigned short)(ra.w | ((a.w & 7) << 8));
        rp[4] = (unsigned short)(rb.x | ((b4.x & 7) << 8));
        rp[5] = (unsigned short)(rb.y | ((b4.y & 7) << 8));
        rp[6] = (unsigned short)(rb.z | ((b4.z & 7) << 8));
        rp[7] = (unsigned short)(rb.w | ((b4.w & 7) << 8));
        *(uint4*)&rp16[wid * 8] = *(uint4*)&rp[0];
    }
}

// ---------------------------------------------------------------------------
// gemm_out: split-bf16 MFMA GEMM -> f32 C (+bias), XCD-swizzled linear grid.
// ---------------------------------------------------------------------------
__global__ __launch_bounds__(256) void gemm_out(const unsigned short* __restrict__ Ah,
                                                const unsigned short* __restrict__ Al,
                                                const unsigned short* __restrict__ Bh,
                                                const unsigned short* __restrict__ Bl,
                                                float* __restrict__ C,
                                                const float* __restrict__ bias,
                                                int M, int N, int K) {
    __shared__ __align__(16) unsigned short Ah_s[128 * 32];
    __shared__ __align__(16) unsigned short Al_s[128 * 32];
    __shared__ __align__(16) unsigned short Bh_s[128 * 32];
    __shared__ __align__(16) unsigned short Bl_s[128 * 32];
    const int tid = threadIdx.x;
    const int w = tid >> 6, lane = tid & 63;
    const int c = lane & 15, q = lane >> 4;

    const int NBX = N >> 7;
    const int id = blockIdx.x;
    const int xcd = id & 7, grp = id >> 3;
    const int bm = ((grp / NBX) * 8 + xcd) * 128;
    const int bn = (grp % NBX) * 128;

    const int lrow = lane >> 2;
    const int lcol = (lane & 3) * 8;

    v4f acc[2][8] = {};
    for (int k0 = 0; k0 < K; k0 += 32) {
        __syncthreads();
#pragma unroll
        for (int i = 0; i < 2; ++i) {
            const int chunk = w * 2 + i;
            const int row = chunk * 16 + lrow;
            const size_t ga = (size_t)(bm + row) * K + k0 + lcol;
            const size_t gb = (size_t)(bn + row) * K + k0 + lcol;
            const int lo = chunk * 512;
            __builtin_amdgcn_global_load_lds(
                (const __attribute__((address_space(1))) unsigned int*)&Ah[ga],
                (__attribute__((address_space(3))) unsigned int*)&Ah_s[lo], 16, 0, 0);
            __builtin_amdgcn_global_load_lds(
                (const __attribute__((address_space(1))) unsigned int*)&Al[ga],
                (__attribute__((address_space(3))) unsigned int*)&Al_s[lo], 16, 0, 0);
            __builtin_amdgcn_global_load_lds(
                (const __attribute__((address_space(1))) unsigned int*)&Bh[gb],
                (__attribute__((address_space(3))) unsigned int*)&Bh_s[lo], 16, 0, 0);
            __builtin_amdgcn_global_load_lds(
                (const __attribute__((address_space(1))) unsigned int*)&Bl[gb],
                (__attribute__((address_space(3))) unsigned int*)&Bl_s[lo], 16, 0, 0);
        }
        asm volatile("s_waitcnt vmcnt(0)" ::: "memory");
        __syncthreads();
        v8s afh[2], afl[2];
#pragma unroll
        for (int mt = 0; mt < 2; ++mt) {
            afh[mt] = *(v8s*)&Ah_s[(w * 32 + mt * 16 + c) * 32 + q * 8];
            afl[mt] = *(v8s*)&Al_s[(w * 32 + mt * 16 + c) * 32 + q * 8];
        }
#pragma unroll
        for (int nt = 0; nt < 8; ++nt) {
            v8s bfh = *(v8s*)&Bh_s[(nt * 16 + c) * 32 + q * 8];
            v8s bfl = *(v8s*)&Bl_s[(nt * 16 + c) * 32 + q * 8];
#pragma unroll
            for (int mt = 0; mt < 2; ++mt) {
                acc[mt][nt] = __builtin_amdgcn_mfma_f32_16x16x32_bf16(afl[mt], bfh, acc[mt][nt], 0, 0, 0);
                acc[mt][nt] = __builtin_amdgcn_mfma_f32_16x16x32_bf16(afh[mt], bfl, acc[mt][nt], 0, 0, 0);
                acc[mt][nt] = __builtin_amdgcn_mfma_f32_16x16x32_bf16(afh[mt], bfh, acc[mt][nt], 0, 0, 0);
            }
        }
    }
#pragma unroll
    for (int mt = 0; mt < 2; ++mt) {
#pragma unroll
        for (int nt = 0; nt < 8; ++nt) {
            int col = bn + nt * 16 + c;
            float bv = bias ? bias[col] : 0.0f;
#pragma unroll
            for (int r = 0; r < 4; ++r) {
                int row = bm + w * 32 + mt * 16 + q * 4 + r;
                C[(size_t)row * N + col] = acc[mt][nt][r] + bv;
            }
        }
    }
}

// ---------------------------------------------------------------------------
// gemm_qkv v2: A staged as f32 DIRECTLY from x (global_load_lds, 16KB tile);
// hi/lo conversion at fragment-build time (bit-identical to the old xh/xl
// path). Epilogue unchanged: q->qh bf16, k->kh/kl hi/lo (LDS-staged,
// pitch-133), v->VTx bf16 transposed.
// ---------------------------------------------------------------------------
__global__ __launch_bounds__(256) void gemm_qkv(const float* __restrict__ X,
                                                const unsigned short* __restrict__ Bh,
                                                const unsigned short* __restrict__ Bl,
                                                int M, int N, int K,
                                                unsigned short* __restrict__ qh,
                                                unsigned short* __restrict__ kh,
                                                unsigned short* __restrict__ kl2,
                                                unsigned short* __restrict__ VTx) {
    __shared__ __align__(16) char SMEM[64 * GM_PITCH_ * 4];
    float* Ax_s = (float*)SMEM;                               // 128x32 f32 = 16KB
    unsigned short* Bh_s = (unsigned short*)(SMEM + 16384);   // 8KB
    unsigned short* Bl_s = (unsigned short*)(SMEM + 24576);   // 8KB
    float* scratch = (float*)SMEM;

    const int tid = threadIdx.x;
    const int w = tid >> 6, lane = tid & 63;
    const int c = lane & 15, q = lane >> 4;

    const int NBX = N >> 7;
    const int id = blockIdx.x;
    const int xcd = id & 7, grp = id >> 3;
    const int bm = ((grp / NBX) * 8 + xcd) * 128;
    const int bn = (grp % NBX) * 128;

    const int arow = lane >> 3;           // f32 A staging: 8 rows/issue
    const int acol = (lane & 7) * 4;
    const int lrow = lane >> 2;           // bf16 B staging: 16 rows/issue
    const int lcol = (lane & 3) * 8;

    v4f acc[2][8] = {};
    for (int k0 = 0; k0 < K; k0 += 32) {
        __syncthreads();
#pragma unroll
        for (int i = 0; i < 4; ++i) {
            const int chunk = w * 4 + i;                 // 0..15
            const int row = chunk * 8 + arow;
            const size_t ga = (size_t)(bm + row) * K + k0 + acol;
            __builtin_amdgcn_global_load_lds(
                (const __attribute__((address_space(1))) unsigned int*)&X[ga],
                (__attribute__((address_space(3))) unsigned int*)&Ax_s[chunk * 256], 16, 0, 0);
        }
#pragma unroll
        for (int i = 0; i < 2; ++i) {
            const int chunk = w * 2 + i;                 // 0..7
            const int row = chunk * 16 + lrow;
            const size_t gb = (size_t)(bn + row) * K + k0 + lcol;
            const int lo = chunk * 512;
            __builtin_amdgcn_global_load_lds(
                (const __attribute__((address_space(1))) unsigned int*)&Bh[gb],
                (__attribute__((address_space(3))) unsigned int*)&Bh_s[lo], 16, 0, 0);
            __builtin_amdgcn_global_load_lds(
                (const __attribute__((address_space(1))) unsigned int*)&Bl[gb],
                (__attribute__((address_space(3))) unsigned int*)&Bl_s[lo], 16, 0, 0);
        }
        asm volatile("s_waitcnt vmcnt(0)" ::: "memory");
        __syncthreads();
        v8s afh[2], afl[2];
#pragma unroll
        for (int mt = 0; mt < 2; ++mt) {
            const float* src = &Ax_s[(w * 32 + mt * 16 + c) * 32 + q * 8];
            float4 f0 = *(const float4*)&src[0];
            float4 f1 = *(const float4*)&src[4];
            float vv[8] = {f0.x, f0.y, f0.z, f0.w, f1.x, f1.y, f1.z, f1.w};
#pragma unroll
            for (int j = 0; j < 8; ++j) {
                unsigned short hi, lo;
                cvt_hilo(vv[j], hi, lo);
                ((short*)&afh[mt])[j] = (short)hi;
                ((short*)&afl[mt])[j] = (short)lo;
            }
        }
#pragma unroll
        for (int nt = 0; nt < 8; ++nt) {
            v8s bfh = *(v8s*)&Bh_s[(nt * 16 + c) * 32 + q * 8];
            v8s bfl = *(v8s*)&Bl_s[(nt * 16 + c) * 32 + q * 8];
#pragma unroll
            for (int mt = 0; mt < 2; ++mt) {
                acc[mt][nt] = __builtin_amdgcn_mfma_f32_16x16x32_bf16(afl[mt], bfh, acc[mt][nt], 0, 0, 0);
                acc[mt][nt] = __builtin_amdgcn_mfma_f32_16x16x32_bf16(afh[mt], bfl, acc[mt][nt], 0, 0, 0);
                acc[mt][nt] = __builtin_amdgcn_mfma_f32_16x16x32_bf16(afh[mt], bfh, acc[mt][nt], 0, 0, 0);
            }
        }
    }
    if (bn >= 2 * DIM_) {
        // v segment: transposed bf16 store VTx[bh][d][x], 8B chunks
#pragma unroll
        for (int mt = 0; mt < 2; ++mt) {
#pragma unroll
            for (int nt = 0; nt < 8; ++nt) {
                int nn = bn + nt * 16 + c - 2 * DIM_;
                int h = nn >> 5, d = nn & 31;
                int row0 = bm + w * 32 + mt * 16 + q * 4;
                int b = row0 >> 12, x = row0 & (XL_ - 1);
                unsigned short t4[4];
#pragma unroll
                for (int r = 0; r < 4; ++r) t4[r] = f2bf(acc[mt][nt][r]);
                *(ushort4*)&VTx[((size_t)(b * H_ + h) * HD_ + d) * XL_ + x] = *(ushort4*)&t4[0];
            }
        }
    } else {
        for (int mt = 0; mt < 2; ++mt) {
            __syncthreads();
#pragma unroll
            for (int nt = 0; nt < 8; ++nt)
#pragma unroll
                for (int r = 0; r < 4; ++r)
                    scratch[(w * 16 + q * 4 + r) * GM_PITCH_ + nt * 16 + c] = acc[mt][nt][r];
            __syncthreads();
            const int or_ = tid & 63, oc = (tid >> 6) * 32;
            const int grow = bm + (or_ >> 4) * 32 + mt * 16 + (or_ & 15);
            const float* src = &scratch[or_ * GM_PITCH_ + oc];
            if (bn < DIM_) {
                unsigned short* dst = &qh[(size_t)grow * DIM_ + bn + oc];
#pragma unroll
                for (int j4 = 0; j4 < 4; ++j4) {
                    unsigned short tmp[8];
#pragma unroll
                    for (int j = 0; j < 8; ++j) tmp[j] = f2bf(src[j4 * 8 + j]);
                    *(uint4*)&dst[j4 * 8] = *(uint4*)&tmp[0];
                }
            } else {
                const size_t o = (size_t)grow * DIM_ + bn - DIM_ + oc;
#pragma unroll
                for (int j4 = 0; j4 < 4; ++j4) {
                    unsigned short th[8], tl[8];
#pragma unroll
                    for (int j = 0; j < 8; ++j) cvt_hilo(src[j4 * 8 + j], th[j], tl[j]);
                    *(uint4*)&kh[o + j4 * 8] = *(uint4*)&th[0];
                    *(uint4*)&kl2[o + j4 * 8] = *(uint4*)&tl[0];
                }
            }
        }
    }
}

// ---------------------------------------------------------------------------
// 64x64 f32 GEMM (small-M) — proj path
// ---------------------------------------------------------------------------
__global__ __launch_bounds__(256) void gemm64(const float* __restrict__ A,
                                              const float* __restrict__ Bw,
                                              float* __restrict__ C,
                                              const float* __restrict__ bias,
                                              int M, int N, int K) {
    __shared__ __align__(16) float As[16][68];
    __shared__ __align__(16) float Bs[16][64];
    const int tid = threadIdx.x;
    const int tx = tid & 15, ty = tid >> 4;
    const int bn = blockIdx.x * 64, bm = blockIdx.y * 64;
    const int am = tid >> 2, ac = tid & 3;
    float acc[4][4] = {};
    for (int k0 = 0; k0 < K; k0 += 16) {
        float4 a4 = *(const float4*)&A[(size_t)(bm + am) * K + k0 + ac * 4];
        As[ac * 4 + 0][am] = a4.x;
        As[ac * 4 + 1][am] = a4.y;
        As[ac * 4 + 2][am] = a4.z;
        As[ac * 4 + 3][am] = a4.w;
        *(float4*)&Bs[ty][tx * 4] = *(const float4*)&Bw[(size_t)(k0 + ty) * N + bn + tx * 4];
        __syncthreads();
#pragma unroll
        for (int kk = 0; kk < 16; ++kk) {
            float4 av = *(const float4*)&As[kk][ty * 4];
            float4 bv = *(const float4*)&Bs[kk][tx * 4];
            float a[4] = {av.x, av.y, av.z, av.w};
            float b[4] = {bv.x, bv.y, bv.z, bv.w};
#pragma unroll
            for (int i = 0; i < 4; ++i)
#pragma unroll
                for (int j = 0; j < 4; ++j) acc[i][j] += a[i] * b[j];
        }
        __syncthreads();
    }
#pragma unroll
    for (int i = 0; i < 4; ++i) {
        int m = bm + ty * 4 + i;
#pragma unroll
        for (int j = 0; j < 4; ++j) {
            int n = bn + tx * 4 + j;
            float v = acc[i][j];
            if (bias) v += bias[n];
            C[(size_t)m * N + n] = v;
        }
    }
}

// ---------------------------------------------------------------------------
// gemm64_qkv: kernal @ W_qkv with typed epilogue (unchanged)
// ---------------------------------------------------------------------------
__global__ __launch_bounds__(256) void gemm64_qkv(const float* __restrict__ A,
                                                  const float* __restrict__ Bw,
                                                  unsigned short* __restrict__ Kqh,
                                                  unsigned short* __restrict__ Kql,
                                                  unsigned short* __restrict__ Kk_bf,
                                                  unsigned short* __restrict__ VT_bf,
                                                  int M, int N, int K) {
    __shared__ __align__(16) float As[16][68];
    __shared__ __align__(16) float Bs[16][64];
    const int tid = threadIdx.x;
    const int tx = tid & 15, ty = tid >> 4;
    const int bn = blockIdx.x * 64, bm = blockIdx.y * 64;
    const int am = tid >> 2, ac = tid & 3;
    float acc[4][4] = {};
    for (int k0 = 0; k0 < K; k0 += 16) {
        float4 a4 = *(const float4*)&A[(size_t)(bm + am) * K + k0 + ac * 4];
        As[ac * 4 + 0][am] = a4.x;
        As[ac * 4 + 1][am] = a4.y;
        As[ac * 4 + 2][am] = a4.z;
        As[ac * 4 + 3][am] = a4.w;
        *(float4*)&Bs[ty][tx * 4] = *(const float4*)&Bw[(size_t)(k0 + ty) * N + bn + tx * 4];
        __syncthreads();
#pragma unroll
        for (int kk = 0; kk < 16; ++kk) {
            float4 av = *(const float4*)&As[kk][ty * 4];
            float4 bv = *(const float4*)&Bs[kk][tx * 4];
            float a[4] = {av.x, av.y, av.z, av.w};
            float b[4] = {bv.x, bv.y, bv.z, bv.w};
#pragma unroll
            for (int i = 0; i < 4; ++i)
#pragma unroll
                for (int j = 0; j < 4; ++j) acc[i][j] += a[i] * b[j];
        }
        __syncthreads();
    }
#pragma unroll
    for (int i = 0; i < 4; ++i) {
        int m = bm + ty * 4 + i;
        int b = m >> 7, k = m & 127;
#pragma unroll
        for (int j = 0; j < 4; ++j) {
            int n = bn + tx * 4 + j;
            float v = acc[i][j];
            if (n < DIM_) {
                unsigned short hi, lo;
                cvt_hilo(v, hi, lo);
                int h = n >> 5, d = n & 31;
                size_t o = ((size_t)(b * H_ + h) * KL_ + k) * HD_ + d;
                Kqh[o] = hi;
                Kql[o] = lo;
            } else if (n < 2 * DIM_) {
                int nn = n - DIM_, h = nn >> 5, d = nn & 31;
                Kk_bf[((size_t)(b * H_ + h) * KL_ + k) * HD_ + d] = f2bf(v);
            } else {
                int nn = n - 2 * DIM_, h = nn >> 5, d = nn & 31;
                VT_bf[((size_t)(b * H_ + h) * HD_ + d) * KL_ + k] = f2bf(v);
            }
        }
    }
}

// ===========================================================================
// K1 v11: rp16 packed rd|polar loads (unchanged)
// ===========================================================================
__global__ __launch_bounds__(256) void score_bins_mfma4(const unsigned short* __restrict__ kxh,
                                                        const unsigned short* __restrict__ kxl,
                                                        const unsigned short* __restrict__ Kqh_g,
                                                        const unsigned short* __restrict__ Kql_g,
                                                        const unsigned short* __restrict__ rp16,
                                                        const unsigned int* __restrict__ mbits,
                                                        const float* __restrict__ dis_embed,
                                                        __hip_bfloat16* __restrict__ Sg,
                                                        float* __restrict__ binspart) {
    const int b = blockIdx.z, h = blockIdx.y, xc = blockIdx.x;
    const int x0 = xc * 64;
    const int tid = threadIdx.x;
    const int w = tid >> 6, lane = tid & 63;
    const int c15 = lane & 15, q = lane >> 4;
    const size_t bh = (size_t)(b * H_ + h);

    __shared__ unsigned int mskb[64][5];
    __shared__ float de_h[NDIS_];
    __shared__ float binsL[8][4][16][PB_ + 1];
    __shared__ __align__(16) unsigned short Ss[2][16][72];

    {
        int xr = tid >> 2, kg = tid & 3;
        mskb[xr][kg] = mbits[(bh * XL_ + x0 + xr) * 4 + kg];
    }
    if (tid < NDIS_) de_h[tid] = dis_embed[tid * H_ + h];
    __syncthreads();

    v8s axh, axl;
    {
        const size_t aoff = ((size_t)b * XL_ + x0 + w * 16 + c15) * DIM_ + h * HD_ + q * 8;
        axh = *(const v8s*)&kxh[aoff];
        axl = *(const v8s*)&kxl[aoff];
    }

    v8s bqh[2], bql[2];
    uint2 rp2[2];
    auto load_nt = [&](int nt, int s) {
        const int k = nt * 16 + c15;
        const size_t kqoff = (bh * KL_ + k) * HD_ + q * 8;
        bqh[s] = *(const v8s*)&Kqh_g[kqoff];
        bql[s] = *(const v8s*)&Kql_g[kqoff];
        const size_t rowoff = ((size_t)(b * KL_ + k)) * XL_ + x0 + w * 16 + q * 4;
        rp2[s] = *(const uint2*)&rp16[rowoff];
    };
    load_nt(0, 0);

#pragma unroll
    for (int nt = 0; nt < 8; ++nt) {
        const int s = nt & 1;
        if (nt < 7) load_nt(nt + 1, s ^ 1);

        const int k = nt * 16 + c15;
        v4f D = {0.f, 0.f, 0.f, 0.f};
        D = __builtin_amdgcn_mfma_f32_16x16x32_bf16(axl, bqh[s], D, 0, 0, 0);
        D = __builtin_amdgcn_mfma_f32_16x16x32_bf16(axh, bql[s], D, 0, 0, 0);
        D = __builtin_amdgcn_mfma_f32_16x16x32_bf16(axh, bqh[s], D, 0, 0, 0);

        float bins[PB_] = {};
        {
            const unsigned short* rpv = (const unsigned short*)&rp2[s];
            ushort4 pack;
#pragma unroll
            for (int r = 0; r < 4; ++r) {
                float sc = D[r] * SCALE_;
                float a = fabsf(sc);
                int pv = (rpv[r] >> 8) & 7;
#pragma unroll
                for (int pb = 0; pb < PB_; ++pb) bins[pb] += (pv == pb) ? a : 0.0f;
                int xloc = w * 16 + q * 4 + r;
                int mbit = (mskb[xloc][k >> 5] >> (k & 31)) & 1;
                float sp = (mbit ? -1e6f : sc) + de_h[rpv[r] & 0x7F];
                ((unsigned short*)&pack)[r] = f2bf(sp);
            }
            *(ushort4*)&Ss[s][c15][w * 16 + q * 4] = pack;
        }

#pragma unroll
        for (int pb = 0; pb < PB_; ++pb) {
            bins[pb] += __shfl_xor(bins[pb], 16);
            bins[pb] += __shfl_xor(bins[pb], 32);
        }
        if (q == 0) {
#pragma unroll
            for (int pb = 0; pb < PB_; ++pb) binsL[nt][w][c15][pb] = bins[pb];
        }

        __syncthreads();
        {
            int row = tid >> 4, seg = tid & 15;
            unsigned short* dst = (unsigned short*)Sg +
                (bh * KL_ + nt * 16 + row) * XL_ + x0 + seg * 4;
            *(uint2*)dst = *(const uint2*)&Ss[s][row][seg * 4];
        }
    }
    __syncthreads();
    {
        int k = tid >> 1, half = tid & 1;
        int nt = k >> 4, c = k & 15;
        float4 s = {0.f, 0.f, 0.f, 0.f};
#pragma unroll
        for (int w4 = 0; w4 < 4; ++w4) {
            const float* bp = &binsL[nt][w4][c][half * 4];
            s.x += bp[0]; s.y += bp[1]; s.z += bp[2]; s.w += bp[3];
        }
        *(float4*)&binspart[(bh * KL_ + k) * (NCH2_ * PB_) + xc * PB_ + half * 4] = s;
    }
}

// K2: argmax (unchanged)
__global__ __launch_bounds__(256) void bins_argmax(const float* __restrict__ binspart,
                                                   int* __restrict__ main_ori) {
    const int w = threadIdx.x >> 6, lane = threadIdx.x & 63;
    const int row = blockIdx.x * 4 + w;
    float s[PB_];
#pragma unroll
    for (int pb = 0; pb < PB_; ++pb) s[pb] = 0.0f;
    if (lane < NCH2_) {
        const float* bp = &binspart[(size_t)row * (NCH2_ * PB_) + lane * PB_];
#pragma unroll
        for (int pb = 0; pb < PB_; ++pb) s[pb] = bp[pb];
    }
#pragma unroll
    for (int m = 1; m < 64; m <<= 1)
#pragma unroll
        for (int pb = 0; pb < PB_; ++pb) s[pb] += __shfl_xor(s[pb], m);
    if (lane == 0) {
        float best = s[0];
        int bi = 0;
#pragma unroll
        for (int pb = 1; pb < PB_; ++pb)
            if (s[pb] > best) { best = s[pb]; bi = pb; }
        main_ori[row] = bi;
    }
}

// ===========================================================================
// K3 v4: flash_mfma (unchanged)
// ===========================================================================
__global__ __launch_bounds__(256) void flash_mfma(const __hip_bfloat16* __restrict__ Sg,
                                                  const unsigned int* __restrict__ pp4,
                                                  const unsigned short* __restrict__ VTx,
                                                  const float* __restrict__ polar_emb,
                                                  const int* __restrict__ main_ori,
                                                  float* __restrict__ part) {
    const int b = blockIdx.z, h = blockIdx.y, xc = blockIdx.x;
    const int tid = threadIdx.x;
    const int w = tid >> 6, lane = tid & 63;
    const int c = lane & 15, q = lane >> 4;
    const size_t bh = (size_t)(b * H_ + h);
    const int xbeg = xc * XC2_;

    __shared__ int mo_s[KL_];
    __shared__ float pe_s[PB_];
    if (tid < KL_) mo_s[tid] = main_ori[bh * KL_ + tid];
    if (tid < PB_) pe_s[tid] = polar_emb[tid];
    __syncthreads();

    const int wk0 = w * 32;
    const int mo[2] = {mo_s[wk0 + c], mo_s[wk0 + 16 + c]};
    const unsigned short* SgU = (const unsigned short*)Sg;

    v4f acc[2][2] = {};
    float lsum[2] = {0.f, 0.f};

    for (int s = 0; s < XC2_ / 32; ++s) {
        const int xs = xbeg + s * 32;
        v8s pa[2];
#pragma unroll
        for (int kt = 0; kt < 2; ++kt) {
            const int k = wk0 + kt * 16 + c;
            v8s sv = *(const v8s*)&SgU[(bh * KL_ + k) * XL_ + xs + q * 8];
            unsigned pw = pp4[((size_t)(b * KL_ + k)) * (XL_ / 8) + (xs >> 3) + q];
            unsigned short pk[8];
#pragma unroll
            for (int j = 0; j < 8; ++j) {
                float sp = bf2f((unsigned short)sv[j]);
                int np = (((int)(pw >> (j * 4)) & 7) - mo[kt]) & 7;
                float p = __expf(sp + pe_s[np]);
                unsigned short pb = f2bf(p);
                pk[j] = pb;
                lsum[kt] += bf2f(pb);
            }
            pa[kt] = *(v8s*)pk;
        }
#pragma unroll
        for (int dt = 0; dt < 2; ++dt) {
            v8s bv = *(const v8s*)&VTx[((size_t)bh * HD_ + dt * 16 + c) * XL_ + xs + q * 8];
            acc[0][dt] = __builtin_amdgcn_mfma_f32_16x16x32_bf16(pa[0], bv, acc[0][dt], 0, 0, 0);
            acc[1][dt] = __builtin_amdgcn_mfma_f32_16x16x32_bf16(pa[1], bv, acc[1][dt], 0, 0, 0);
        }
    }

#pragma unroll
    for (int kt = 0; kt < 2; ++kt) {
        lsum[kt] += __shfl_xor(lsum[kt], 16);
        lsum[kt] += __shfl_xor(lsum[kt], 32);
    }
#pragma unroll
    for (int kt = 0; kt < 2; ++kt) {
#pragma unroll
        for (int dt = 0; dt < 2; ++dt) {
#pragma unroll
            for (int r = 0; r < 4; ++r) {
                int krow = wk0 + kt * 16 + q * 4 + r;
                part[((size_t)(bh * KL_ + krow) * NS2_ + xc) * 36 + dt * 16 + c] = acc[kt][dt][r];
            }
        }
        if (q == 0) {
            int krow = wk0 + kt * 16 + c;
            part[((size_t)(bh * KL_ + krow) * NS2_ + xc) * 36 + 32] = lsum[kt];
        }
    }
}

// K4: merge over NS2_ chunks
__global__ __launch_bounds__(256) void merge_cached(const float* __restrict__ part,
                                                    float* __restrict__ kout_pre) {
    const int tid = threadIdx.x;
    const int ri = tid >> 5, d = tid & 31;
    const int row = blockIdx.x * 8 + ri;
    float l = 0.f, a = 0.f;
#pragma unroll 4
    for (int c = 0; c < NS2_; ++c) {
        const float* p = &part[((size_t)row * NS2_ + c) * 36];
        l += p[32];
        a += p[d];
    }
    int k = row & (KL_ - 1);
    int bh = row >> 7;
    int h = bh & (H_ - 1), b = bh >> 3;
    kout_pre[(size_t)(b * KL_ + k) * DIM_ + h * HD_ + d] = a / l;
}

// ===========================================================================
// attn_x_mfma v5 (unchanged)
// ===========================================================================
__global__ __launch_bounds__(256) void attn_x_mfma(const unsigned short* __restrict__ qxh,
                                                   const unsigned short* __restrict__ Kk_bf,
                                                   const unsigned short* __restrict__ VT_bf,
                                                   const unsigned short* __restrict__ rp16,
                                                   const unsigned int* __restrict__ mbits,
                                                   const float* __restrict__ dis_embed,
                                                   const float* __restrict__ polar_emb,
                                                   const int* __restrict__ main_ori,
                                                   unsigned short* __restrict__ oh,
                                                   unsigned short* __restrict__ ol) {
    const int b = blockIdx.z, h = blockIdx.y;
    const int x0 = blockIdx.x * 64;
    const int tid = threadIdx.x;
    const int wave = tid >> 6, lane = tid & 63;
    const int c = lane & 15, q = lane >> 4;

    __shared__ __align__(16) unsigned short P_s[4][16][136];
    __shared__ unsigned short rp_s[KL_][72];
    __shared__ unsigned int msk_s[64][5];
    __shared__ float de_h[NDIS_];
    __shared__ float pe[PB_];
    __shared__ int mo_s[KL_];

    const size_t bh = (size_t)(b * H_ + h);
    if (tid < NDIS_) de_h[tid] = dis_embed[tid * H_ + h];
    if (tid < PB_) pe[tid] = polar_emb[tid];
    if (tid < KL_) mo_s[tid] = main_ori[bh * KL_ + tid];
    {
        int xr = tid >> 2, kg = tid & 3;
        msk_s[xr][kg] = mbits[(bh * XL_ + x0 + xr) * 4 + kg];
    }
    __syncthreads();

#pragma unroll
    for (int i = 0; i < 8; ++i) {
        int id = tid + 256 * i;          // 2048 chunks of 4 u16
        int k = id >> 4, ch = id & 15;
        uint2 v = *(const uint2*)&rp16[((size_t)(b * KL_ + k)) * XL_ + x0 + ch * 4];
        int mo = mo_s[k];
        const unsigned short* pv = (const unsigned short*)&v;
        unsigned short outv[4];
#pragma unroll
        for (int j = 0; j < 4; ++j) {
            int np = (((pv[j] >> 8) & 7) - mo) & 7;
            outv[j] = (unsigned short)((pv[j] & 0x7F) | (np << 8));
        }
        *(uint2*)&rp_s[k][ch * 4] = *(uint2*)&outv[0];
    }
    __syncthreads();

    v8s aq = *(const v8s*)&qxh[(size_t)(b * XL_ + x0 + wave * 16 + c) * DIM_ + h * HD_ + q * 8];

    const unsigned short* KkB = &Kk_bf[(size_t)bh * KL_ * HD_];
    v4f S[8];
#pragma unroll
    for (int t = 0; t < 8; ++t) {
        v8s bk = *(const v8s*)&KkB[(size_t)(t * 16 + c) * HD_ + q * 8];
        S[t] = __builtin_amdgcn_mfma_f32_16x16x32_bf16(aq, bk, (v4f){0.f, 0.f, 0.f, 0.f}, 0, 0, 0);
    }

    const int xloc = wave * 16;
    float lr[4] = {0.f, 0.f, 0.f, 0.f};
#pragma unroll
    for (int t = 0; t < 8; ++t) {
#pragma unroll
        for (int r = 0; r < 4; ++r) {
            int krow = t * 16 + c;
            int xrow = q * 4 + r;
            unsigned short rp = rp_s[krow][xloc + xrow];
            int mbit = (msk_s[xloc + xrow][krow >> 5] >> (krow & 31)) & 1;
            float sval = S[t][r] * SCALE_;
            float tval = (mbit ? -25.0f : sval) + de_h[rp & 0x7f] + pe[(rp >> 8) & 7];
            float p = __expf(tval);
            unsigned short pb = f2bf(p);
            P_s[wave][xrow][krow] = pb;
            lr[r] += bf2f(pb);
        }
    }
#pragma unroll
    for (int r = 0; r < 4; ++r) {
#pragma unroll
        for (int m = 1; m < 16; m <<= 1) lr[r] += __shfl_xor(lr[r], m);
    }
    __syncthreads();

    const unsigned short* VTB = &VT_bf[(size_t)bh * HD_ * KL_];
    v4f O0 = {0.f, 0.f, 0.f, 0.f}, O1 = {0.f, 0.f, 0.f, 0.f};
#pragma unroll
    for (int kc = 0; kc < 4; ++kc) {
        v8s ap = *(v8s*)&P_s[wave][c][kc * 32 + q * 8];
        v8s bv0 = *(const v8s*)&VTB[(size_t)c * KL_ + kc * 32 + q * 8];
        v8s bv1 = *(const v8s*)&VTB[(size_t)(16 + c) * KL_ + kc * 32 + q * 8];
        O0 = __builtin_amdgcn_mfma_f32_16x16x32_bf16(ap, bv0, O0, 0, 0, 0);
        O1 = __builtin_amdgcn_mfma_f32_16x16x32_bf16(ap, bv1, O1, 0, 0, 0);
    }

#pragma unroll
    for (int r = 0; r < 4; ++r) {
        int xg = x0 + wave * 16 + q * 4 + r;
        float inv = 1.0f / lr[r];
        size_t obase = (size_t)(b * XL_ + xg) * DIM_ + h * HD_;
        float v0 = O0[r] * inv;
        float v1 = O1[r] * inv;
        unsigned short h0, l0, h1, l1;
        cvt_hilo(v0, h0, l0);
        cvt_hilo(v1, h1, l1);
        oh[obase + c] = h0;
        ol[obase + c] = l0;
        oh[obase + 16 + c] = h1;
        ol[obase + 16 + c] = l1;
    }
}

// ---------------------------------------------------------------------------
extern "C" void kernel_launch(void* const* d_in, const int* in_sizes, int n_in,
                              void* d_out, int out_size, void* d_ws, size_t ws_size,
                              hipStream_t stream) {
    const float* x         = (const float*)d_in[0];
    const float* kernal    = (const float*)d_in[1];
    const int* rd          = (const int*)d_in[2];
    const int* polar_pos   = (const int*)d_in[3];
    const int* att_mask    = (const int*)d_in[4];
    const float* W_qkv     = (const float*)d_in[5];
    const float* dis_embed = (const float*)d_in[6];
    const float* polar_emb = (const float*)d_in[7];
    const float* W_proj    = (const float*)d_in[8];
    const float* b_proj    = (const float*)d_in[9];
    float* out             = (float*)d_out;

    char* base = (char*)d_ws;
    size_t off = 0;
    auto alloc = [&](size_t bytes) { void* p = base + off; off = (off + bytes + 255) & ~255ULL; return p; };
    const size_t MX = (size_t)B_ * XL_;

    unsigned short* VTx = (unsigned short*)alloc((size_t)B_ * H_ * HD_ * XL_ * 2);
    unsigned short* qxh = (unsigned short*)alloc(MX * DIM_ * 2);
    unsigned short* kxh = (unsigned short*)alloc(MX * DIM_ * 2);
    unsigned short* kxl = (unsigned short*)alloc(MX * DIM_ * 2);
    float* binspart  = (float*)alloc((size_t)B_ * H_ * KL_ * NCH2_ * PB_ * 4);
    float* kout_pre  = (float*)alloc((size_t)B_ * KL_ * DIM_ * 4);
    int* main_ori    = (int*)alloc(B_ * H_ * KL_ * 4);
    float* part      = (float*)alloc((size_t)B_ * H_ * KL_ * NS2_ * 36 * 4);
    __hip_bfloat16* Sg = (__hip_bfloat16*)alloc((size_t)B_ * H_ * KL_ * XL_ * 2);
    unsigned short* wph = (unsigned short*)alloc((size_t)DIM_ * DIM_ * 2);
    unsigned short* wpl = (unsigned short*)alloc((size_t)DIM_ * DIM_ * 2);
    unsigned short* wqh = (unsigned short*)alloc((size_t)TDIM_ * DIM_ * 2);
    unsigned short* wql = (unsigned short*)alloc((size_t)TDIM_ * DIM_ * 2);
    unsigned int* mbits = (unsigned int*)alloc((size_t)B_ * H_ * XL_ * (KL_ / 32) * 4);
    unsigned int* pp4   = (unsigned int*)alloc((size_t)B_ * KL_ * (XL_ / 8) * 4);
    unsigned short* rp16 = (unsigned short*)alloc((size_t)B_ * KL_ * XL_ * 2);
    unsigned short* Kqh_g = (unsigned short*)alloc((size_t)B_ * H_ * KL_ * HD_ * 2);
    unsigned short* Kql_g = (unsigned short*)alloc((size_t)B_ * H_ * KL_ * HD_ * 2);
    unsigned short* Kk_bf = (unsigned short*)alloc((size_t)B_ * H_ * KL_ * HD_ * 2);
    unsigned short* VT_bf = (unsigned short*)alloc((size_t)B_ * H_ * HD_ * KL_ * 2);

    // oh/ol alias into Sg region (written by attn_x after flash consumed Sg)
    unsigned short* oh = (unsigned short*)Sg;
    unsigned short* ol = oh + MX * DIM_;

    // --- fused preamble (1 launch; x conversion now inside gemm_qkv) ---
    preamble<<<dim3(NB_PACK_ + NB_WQ_ + NB_WP_ + NB_PP_), 256, 0, stream>>>(
        att_mask, W_qkv, W_proj, polar_pos, rd, mbits, wqh, wql, wph, wpl, pp4, rp16);

    // --- qkv projections ---
    gemm_qkv<<<dim3((TDIM_ / 128) * (MX / 128)), 256, 0, stream>>>(
        x, wqh, wql, MX, TDIM_, DIM_, qxh, kxh, kxl, VTx);
    gemm64_qkv<<<dim3(TDIM_ / 64, (B_ * KL_) / 64), 256, 0, stream>>>(
        kernal, W_qkv, Kqh_g, Kql_g, Kk_bf, VT_bf, B_ * KL_, TDIM_, DIM_);

    // --- k-direction ---
    score_bins_mfma4<<<dim3(NCH2_, H_, B_), 256, 0, stream>>>(
        kxh, kxl, Kqh_g, Kql_g, rp16, mbits, dis_embed, Sg, binspart);
    bins_argmax<<<dim3(B_ * H_ * KL_ / 4), 256, 0, stream>>>(binspart, main_ori);
    flash_mfma<<<dim3(NS2_, H_, B_), 256, 0, stream>>>(
        Sg, pp4, VTx, polar_emb, main_ori, part);
    merge_cached<<<dim3(B_ * H_ * KL_ / 8), 256, 0, stream>>>(part, kout_pre);

    // --- x-direction ---
    attn_x_mfma<<<dim3(XL_ / 64, H_, B_), 256, 0, stream>>>(
        qxh, Kk_bf, VT_bf, rp16, mbits, dis_embed, polar_emb, main_ori, oh, ol);

    // --- output projections ---
    gemm_out<<<dim3((DIM_ / 128) * (MX / 128)), 256, 0, stream>>>(
        oh, ol, wph, wpl, out, b_proj, MX, DIM_, DIM_);
    gemm64<<<dim3(DIM_ / 64, (B_ * KL_) / 64), 256, 0, stream>>>(
        kout_pre, W_proj, out + (size_t)B_ * XL_ * DIM_, b_proj, B_ * KL_, DIM_, DIM_);
}

// Round 13
// 312.956 us; speedup vs baseline: 1.0016x; 1.0011x over previous
//
#include <hip/hip_runtime.h>
#include <hip/hip_bf16.h>

#define B_    4
#define KL_   128
#define XL_   4096
#define DIM_  256
#define H_    8
#define HD_   32
#define PB_   8
#define NDIS_ 66
#define TDIM_ 768
#define SCALE_ 0.17677669529663687f
#define NCH2_ 64
#define KC2_  16
#define NS2_  32               // flash x-chunks
#define XC2_  (XL_ / NS2_)     // 128 x per chunk
#define GM_PITCH_ 133

// preamble grid partition (cvt partition removed: x converted inside gemm_qkv)
#define NB_PACK_ 2048
#define NB_WQ_   768
#define NB_WP_   256
#define NB_PP_   1024          // polar 4-bit pack + rp16 pack: B*KL*XL/8/256

typedef float v4f __attribute__((ext_vector_type(4)));
typedef short v8s __attribute__((ext_vector_type(8)));

__device__ __forceinline__ unsigned short f2bf(float f) {
    __hip_bfloat16 h = __float2bfloat16(f);
    return __builtin_bit_cast(unsigned short, h);
}
__device__ __forceinline__ float bf2f(unsigned short u) {
    return __bfloat162float(__builtin_bit_cast(__hip_bfloat16, u));
}
__device__ __forceinline__ void cvt_hilo(float v, unsigned short& hi, unsigned short& lo) {
    hi = f2bf(v);
    lo = f2bf(v - bf2f(hi));
}

// ---------------------------------------------------------------------------
// preamble: pack_mask (ballot) + cvt_wT(W_qkv/W_proj) + {pp4 + rp16}
// ---------------------------------------------------------------------------
__global__ __launch_bounds__(256) void preamble(const int* __restrict__ att_mask,
                                                const float* __restrict__ W_qkv,
                                                const float* __restrict__ W_proj,
                                                const int* __restrict__ polar_pos,
                                                const int* __restrict__ rd,
                                                unsigned int* __restrict__ mbits,
                                                unsigned short* __restrict__ wqh,
                                                unsigned short* __restrict__ wql,
                                                unsigned short* __restrict__ wph,
                                                unsigned short* __restrict__ wpl,
                                                unsigned int* __restrict__ pp4,
                                                unsigned short* __restrict__ rp16) {
    const int bid = blockIdx.x, tid = threadIdx.x;
    if (bid < NB_PACK_) {
        const int w = tid >> 6, lane = tid & 63;
        const size_t ibase = (((size_t)bid * 4 + w) * 32) * 64;
#pragma unroll
        for (int u = 0; u < 4; ++u) {
            int vals[8];
#pragma unroll
            for (int i = 0; i < 8; ++i)
                vals[i] = att_mask[ibase + (size_t)(u * 8 + i) * 64 + lane];
            unsigned long long bm0 = __ballot(vals[0] != 0);
            unsigned long long bm1 = __ballot(vals[1] != 0);
            unsigned long long bm2 = __ballot(vals[2] != 0);
            unsigned long long bm3 = __ballot(vals[3] != 0);
            unsigned long long bm4 = __ballot(vals[4] != 0);
            unsigned long long bm5 = __ballot(vals[5] != 0);
            unsigned long long bm6 = __ballot(vals[6] != 0);
            unsigned long long bm7 = __ballot(vals[7] != 0);
            if (lane == 0) {
                size_t wb = ibase / 32 + (size_t)u * 16;
                *(uint2*)&mbits[wb + 0]  = make_uint2((unsigned)bm0, (unsigned)(bm0 >> 32));
                *(uint2*)&mbits[wb + 2]  = make_uint2((unsigned)bm1, (unsigned)(bm1 >> 32));
                *(uint2*)&mbits[wb + 4]  = make_uint2((unsigned)bm2, (unsigned)(bm2 >> 32));
                *(uint2*)&mbits[wb + 6]  = make_uint2((unsigned)bm3, (unsigned)(bm3 >> 32));
                *(uint2*)&mbits[wb + 8]  = make_uint2((unsigned)bm4, (unsigned)(bm4 >> 32));
                *(uint2*)&mbits[wb + 10] = make_uint2((unsigned)bm5, (unsigned)(bm5 >> 32));
                *(uint2*)&mbits[wb + 12] = make_uint2((unsigned)bm6, (unsigned)(bm6 >> 32));
                *(uint2*)&mbits[wb + 14] = make_uint2((unsigned)bm7, (unsigned)(bm7 >> 32));
            }
        }
    } else if (bid < NB_PACK_ + NB_WQ_) {
        int n = bid - NB_PACK_, k = tid;
        float v = W_qkv[(size_t)k * TDIM_ + n];
        unsigned short h, l;
        cvt_hilo(v, h, l);
        wqh[(size_t)n * DIM_ + k] = h;
        wql[(size_t)n * DIM_ + k] = l;
    } else if (bid < NB_PACK_ + NB_WQ_ + NB_WP_) {
        int n = bid - (NB_PACK_ + NB_WQ_), k = tid;
        float v = W_proj[(size_t)k * DIM_ + n];
        unsigned short h, l;
        cvt_hilo(v, h, l);
        wph[(size_t)n * DIM_ + k] = h;
        wpl[(size_t)n * DIM_ + k] = l;
    } else {
        size_t wid = (size_t)(bid - (NB_PACK_ + NB_WQ_ + NB_WP_)) * 256 + tid;
        const int* srcp = &polar_pos[wid * 8];
        const int* srcr = &rd[wid * 8];
        int4 a = *(const int4*)&srcp[0];
        int4 b4 = *(const int4*)&srcp[4];
        int4 ra = *(const int4*)&srcr[0];
        int4 rb = *(const int4*)&srcr[4];
        unsigned pk = (unsigned)(a.x & 7) | ((unsigned)(a.y & 7) << 4) |
                      ((unsigned)(a.z & 7) << 8) | ((unsigned)(a.w & 7) << 12) |
                      ((unsigned)(b4.x & 7) << 16) | ((unsigned)(b4.y & 7) << 20) |
                      ((unsigned)(b4.z & 7) << 24) | ((unsigned)(b4.w & 7) << 28);
        pp4[wid] = pk;
        unsigned short rp[8];
        rp[0] = (unsigned short)(ra.x | ((a.x & 7) << 8));
        rp[1] = (unsigned short)(ra.y | ((a.y & 7) << 8));
        rp[2] = (unsigned short)(ra.z | ((a.z & 7) << 8));
        rp[3] = (unsigned short)(ra.w | ((a.w & 7) << 8));
        rp[4] = (unsigned short)(rb.x | ((b4.x & 7) << 8));
        rp[5] = (unsigned short)(rb.y | ((b4.y & 7) << 8));
        rp[6] = (unsigned short)(rb.z | ((b4.z & 7) << 8));
        rp[7] = (unsigned short)(rb.w | ((b4.w & 7) << 8));
        *(uint4*)&rp16[wid * 8] = *(uint4*)&rp[0];
    }
}

// ---------------------------------------------------------------------------
// gemm_out: split-bf16 MFMA GEMM -> f32 C (+bias), XCD-swizzled linear grid.
// bf16 tiles unit-swizzled: 16B unit u of row r stored at u^(r&3)
// (source-side permutation; reads use matching XOR). 8-way -> 4-way conflicts.
// ---------------------------------------------------------------------------
__global__ __launch_bounds__(256) void gemm_out(const unsigned short* __restrict__ Ah,
                                                const unsigned short* __restrict__ Al,
                                                const unsigned short* __restrict__ Bh,
                                                const unsigned short* __restrict__ Bl,
                                                float* __restrict__ C,
                                                const float* __restrict__ bias,
                                                int M, int N, int K) {
    __shared__ __align__(16) unsigned short Ah_s[128 * 32];
    __shared__ __align__(16) unsigned short Al_s[128 * 32];
    __shared__ __align__(16) unsigned short Bh_s[128 * 32];
    __shared__ __align__(16) unsigned short Bl_s[128 * 32];
    const int tid = threadIdx.x;
    const int w = tid >> 6, lane = tid & 63;
    const int c = lane & 15, q = lane >> 4;

    const int NBX = N >> 7;
    const int id = blockIdx.x;
    const int xcd = id & 7, grp = id >> 3;
    const int bm = ((grp / NBX) * 8 + xcd) * 128;
    const int bn = (grp % NBX) * 128;

    const int lrow = lane >> 2;
    // source-side unit swizzle: logical unit (l&3)^(row&3), row&3 = (l>>2)&3
    const int lcol = (((lane & 3) ^ ((lane >> 2) & 3)) * 8);

    v4f acc[2][8] = {};
    for (int k0 = 0; k0 < K; k0 += 32) {
        __syncthreads();
#pragma unroll
        for (int i = 0; i < 2; ++i) {
            const int chunk = w * 2 + i;
            const int row = chunk * 16 + lrow;
            const size_t ga = (size_t)(bm + row) * K + k0 + lcol;
            const size_t gb = (size_t)(bn + row) * K + k0 + lcol;
            const int lo = chunk * 512;
            __builtin_amdgcn_global_load_lds(
                (const __attribute__((address_space(1))) unsigned int*)&Ah[ga],
                (__attribute__((address_space(3))) unsigned int*)&Ah_s[lo], 16, 0, 0);
            __builtin_amdgcn_global_load_lds(
                (const __attribute__((address_space(1))) unsigned int*)&Al[ga],
                (__attribute__((address_space(3))) unsigned int*)&Al_s[lo], 16, 0, 0);
            __builtin_amdgcn_global_load_lds(
                (const __attribute__((address_space(1))) unsigned int*)&Bh[gb],
                (__attribute__((address_space(3))) unsigned int*)&Bh_s[lo], 16, 0, 0);
            __builtin_amdgcn_global_load_lds(
                (const __attribute__((address_space(1))) unsigned int*)&Bl[gb],
                (__attribute__((address_space(3))) unsigned int*)&Bl_s[lo], 16, 0, 0);
        }
        asm volatile("s_waitcnt vmcnt(0)" ::: "memory");
        __syncthreads();
        const int uA = (q ^ (c & 3)) * 8;     // physical unit for logical col q*8
        v8s afh[2], afl[2];
#pragma unroll
        for (int mt = 0; mt < 2; ++mt) {
            afh[mt] = *(v8s*)&Ah_s[(w * 32 + mt * 16 + c) * 32 + uA];
            afl[mt] = *(v8s*)&Al_s[(w * 32 + mt * 16 + c) * 32 + uA];
        }
#pragma unroll
        for (int nt = 0; nt < 8; ++nt) {
            v8s bfh = *(v8s*)&Bh_s[(nt * 16 + c) * 32 + uA];
            v8s bfl = *(v8s*)&Bl_s[(nt * 16 + c) * 32 + uA];
#pragma unroll
            for (int mt = 0; mt < 2; ++mt) {
                acc[mt][nt] = __builtin_amdgcn_mfma_f32_16x16x32_bf16(afl[mt], bfh, acc[mt][nt], 0, 0, 0);
                acc[mt][nt] = __builtin_amdgcn_mfma_f32_16x16x32_bf16(afh[mt], bfl, acc[mt][nt], 0, 0, 0);
                acc[mt][nt] = __builtin_amdgcn_mfma_f32_16x16x32_bf16(afh[mt], bfh, acc[mt][nt], 0, 0, 0);
            }
        }
    }
#pragma unroll
    for (int mt = 0; mt < 2; ++mt) {
#pragma unroll
        for (int nt = 0; nt < 8; ++nt) {
            int col = bn + nt * 16 + c;
            float bv = bias ? bias[col] : 0.0f;
#pragma unroll
            for (int r = 0; r < 4; ++r) {
                int row = bm + w * 32 + mt * 16 + q * 4 + r;
                C[(size_t)row * N + col] = acc[mt][nt][r] + bv;
            }
        }
    }
}

// ---------------------------------------------------------------------------
// gemm_qkv v3: A staged f32 with 8-unit XOR swizzle (16-way -> 2-way bank
// conflicts); B bf16 with 4-unit swizzle. hi/lo conversion at fragment build
// (bit-identical values). Epilogue unchanged.
// ---------------------------------------------------------------------------
__global__ __launch_bounds__(256) void gemm_qkv(const float* __restrict__ X,
                                                const unsigned short* __restrict__ Bh,
                                                const unsigned short* __restrict__ Bl,
                                                int M, int N, int K,
                                                unsigned short* __restrict__ qh,
                                                unsigned short* __restrict__ kh,
                                                unsigned short* __restrict__ kl2,
                                                unsigned short* __restrict__ VTx) {
    __shared__ __align__(16) char SMEM[64 * GM_PITCH_ * 4];
    float* Ax_s = (float*)SMEM;                               // 128x32 f32 = 16KB
    unsigned short* Bh_s = (unsigned short*)(SMEM + 16384);   // 8KB
    unsigned short* Bl_s = (unsigned short*)(SMEM + 24576);   // 8KB
    float* scratch = (float*)SMEM;

    const int tid = threadIdx.x;
    const int w = tid >> 6, lane = tid & 63;
    const int c = lane & 15, q = lane >> 4;

    const int NBX = N >> 7;
    const int id = blockIdx.x;
    const int xcd = id & 7, grp = id >> 3;
    const int bm = ((grp / NBX) * 8 + xcd) * 128;
    const int bn = (grp % NBX) * 128;

    // A f32: 8 rows/issue; logical unit = (l&7)^(row&7), row&7 = l>>3
    const int arow = lane >> 3;
    const int acol = (((lane & 7) ^ (lane >> 3)) * 4);
    // B bf16: 16 rows/issue; logical unit = (l&3)^(row&3), row&3 = (l>>2)&3
    const int lrow = lane >> 2;
    const int lcol = (((lane & 3) ^ ((lane >> 2) & 3)) * 8);

    v4f acc[2][8] = {};
    for (int k0 = 0; k0 < K; k0 += 32) {
        __syncthreads();
#pragma unroll
        for (int i = 0; i < 4; ++i) {
            const int chunk = w * 4 + i;                 // 0..15
            const int row = chunk * 8 + arow;
            const size_t ga = (size_t)(bm + row) * K + k0 + acol;
            __builtin_amdgcn_global_load_lds(
                (const __attribute__((address_space(1))) unsigned int*)&X[ga],
                (__attribute__((address_space(3))) unsigned int*)&Ax_s[chunk * 256], 16, 0, 0);
        }
#pragma unroll
        for (int i = 0; i < 2; ++i) {
            const int chunk = w * 2 + i;                 // 0..7
            const int row = chunk * 16 + lrow;
            const size_t gb = (size_t)(bn + row) * K + k0 + lcol;
            const int lo = chunk * 512;
            __builtin_amdgcn_global_load_lds(
                (const __attribute__((address_space(1))) unsigned int*)&Bh[gb],
                (__attribute__((address_space(3))) unsigned int*)&Bh_s[lo], 16, 0, 0);
            __builtin_amdgcn_global_load_lds(
                (const __attribute__((address_space(1))) unsigned int*)&Bl[gb],
                (__attribute__((address_space(3))) unsigned int*)&Bl_s[lo], 16, 0, 0);
        }
        asm volatile("s_waitcnt vmcnt(0)" ::: "memory");
        __syncthreads();
        const int r7 = c & 7;
        const int uB = (q ^ (c & 3)) * 8;
        v8s afh[2], afl[2];
#pragma unroll
        for (int mt = 0; mt < 2; ++mt) {
            const float* sA = &Ax_s[(w * 32 + mt * 16 + c) * 32];
            float4 f0 = *(const float4*)&sA[((2 * q) ^ r7) * 4];
            float4 f1 = *(const float4*)&sA[((2 * q + 1) ^ r7) * 4];
            float vv[8] = {f0.x, f0.y, f0.z, f0.w, f1.x, f1.y, f1.z, f1.w};
#pragma unroll
            for (int j = 0; j < 8; ++j) {
                unsigned short hi, lo;
                cvt_hilo(vv[j], hi, lo);
                ((short*)&afh[mt])[j] = (short)hi;
                ((short*)&afl[mt])[j] = (short)lo;
            }
        }
#pragma unroll
        for (int nt = 0; nt < 8; ++nt) {
            v8s bfh = *(v8s*)&Bh_s[(nt * 16 + c) * 32 + uB];
            v8s bfl = *(v8s*)&Bl_s[(nt * 16 + c) * 32 + uB];
#pragma unroll
            for (int mt = 0; mt < 2; ++mt) {
                acc[mt][nt] = __builtin_amdgcn_mfma_f32_16x16x32_bf16(afl[mt], bfh, acc[mt][nt], 0, 0, 0);
                acc[mt][nt] = __builtin_amdgcn_mfma_f32_16x16x32_bf16(afh[mt], bfl, acc[mt][nt], 0, 0, 0);
                acc[mt][nt] = __builtin_amdgcn_mfma_f32_16x16x32_bf16(afh[mt], bfh, acc[mt][nt], 0, 0, 0);
            }
        }
    }
    if (bn >= 2 * DIM_) {
        // v segment: transposed bf16 store VTx[bh][d][x], 8B chunks
#pragma unroll
        for (int mt = 0; mt < 2; ++mt) {
#pragma unroll
            for (int nt = 0; nt < 8; ++nt) {
                int nn = bn + nt * 16 + c - 2 * DIM_;
                int h = nn >> 5, d = nn & 31;
                int row0 = bm + w * 32 + mt * 16 + q * 4;
                int b = row0 >> 12, x = row0 & (XL_ - 1);
                unsigned short t4[4];
#pragma unroll
                for (int r = 0; r < 4; ++r) t4[r] = f2bf(acc[mt][nt][r]);
                *(ushort4*)&VTx[((size_t)(b * H_ + h) * HD_ + d) * XL_ + x] = *(ushort4*)&t4[0];
            }
        }
    } else {
        for (int mt = 0; mt < 2; ++mt) {
            __syncthreads();
#pragma unroll
            for (int nt = 0; nt < 8; ++nt)
#pragma unroll
                for (int r = 0; r < 4; ++r)
                    scratch[(w * 16 + q * 4 + r) * GM_PITCH_ + nt * 16 + c] = acc[mt][nt][r];
            __syncthreads();
            const int or_ = tid & 63, oc = (tid >> 6) * 32;
            const int grow = bm + (or_ >> 4) * 32 + mt * 16 + (or_ & 15);
            const float* src = &scratch[or_ * GM_PITCH_ + oc];
            if (bn < DIM_) {
                unsigned short* dst = &qh[(size_t)grow * DIM_ + bn + oc];
#pragma unroll
                for (int j4 = 0; j4 < 4; ++j4) {
                    unsigned short tmp[8];
#pragma unroll
                    for (int j = 0; j < 8; ++j) tmp[j] = f2bf(src[j4 * 8 + j]);
                    *(uint4*)&dst[j4 * 8] = *(uint4*)&tmp[0];
                }
            } else {
                const size_t o = (size_t)grow * DIM_ + bn - DIM_ + oc;
#pragma unroll
                for (int j4 = 0; j4 < 4; ++j4) {
                    unsigned short th[8], tl[8];
#pragma unroll
                    for (int j = 0; j < 8; ++j) cvt_hilo(src[j4 * 8 + j], th[j], tl[j]);
                    *(uint4*)&kh[o + j4 * 8] = *(uint4*)&th[0];
                    *(uint4*)&kl2[o + j4 * 8] = *(uint4*)&tl[0];
                }
            }
        }
    }
}

// ---------------------------------------------------------------------------
// 64x64 f32 GEMM (small-M) — proj path
// ---------------------------------------------------------------------------
__global__ __launch_bounds__(256) void gemm64(const float* __restrict__ A,
                                              const float* __restrict__ Bw,
                                              float* __restrict__ C,
                                              const float* __restrict__ bias,
                                              int M, int N, int K) {
    __shared__ __align__(16) float As[16][68];
    __shared__ __align__(16) float Bs[16][64];
    const int tid = threadIdx.x;
    const int tx = tid & 15, ty = tid >> 4;
    const int bn = blockIdx.x * 64, bm = blockIdx.y * 64;
    const int am = tid >> 2, ac = tid & 3;
    float acc[4][4] = {};
    for (int k0 = 0; k0 < K; k0 += 16) {
        float4 a4 = *(const float4*)&A[(size_t)(bm + am) * K + k0 + ac * 4];
        As[ac * 4 + 0][am] = a4.x;
        As[ac * 4 + 1][am] = a4.y;
        As[ac * 4 + 2][am] = a4.z;
        As[ac * 4 + 3][am] = a4.w;
        *(float4*)&Bs[ty][tx * 4] = *(const float4*)&Bw[(size_t)(k0 + ty) * N + bn + tx * 4];
        __syncthreads();
#pragma unroll
        for (int kk = 0; kk < 16; ++kk) {
            float4 av = *(const float4*)&As[kk][ty * 4];
            float4 bv = *(const float4*)&Bs[kk][tx * 4];
            float a[4] = {av.x, av.y, av.z, av.w};
            float b[4] = {bv.x, bv.y, bv.z, bv.w};
#pragma unroll
            for (int i = 0; i < 4; ++i)
#pragma unroll
                for (int j = 0; j < 4; ++j) acc[i][j] += a[i] * b[j];
        }
        __syncthreads();
    }
#pragma unroll
    for (int i = 0; i < 4; ++i) {
        int m = bm + ty * 4 + i;
#pragma unroll
        for (int j = 0; j < 4; ++j) {
            int n = bn + tx * 4 + j;
            float v = acc[i][j];
            if (bias) v += bias[n];
            C[(size_t)m * N + n] = v;
        }
    }
}

// ---------------------------------------------------------------------------
// gemm64_qkv: kernal @ W_qkv with typed epilogue (unchanged)
// ---------------------------------------------------------------------------
__global__ __launch_bounds__(256) void gemm64_qkv(const float* __restrict__ A,
                                                  const float* __restrict__ Bw,
                                                  unsigned short* __restrict__ Kqh,
                                                  unsigned short* __restrict__ Kql,
                                                  unsigned short* __restrict__ Kk_bf,
                                                  unsigned short* __restrict__ VT_bf,
                                                  int M, int N, int K) {
    __shared__ __align__(16) float As[16][68];
    __shared__ __align__(16) float Bs[16][64];
    const int tid = threadIdx.x;
    const int tx = tid & 15, ty = tid >> 4;
    const int bn = blockIdx.x * 64, bm = blockIdx.y * 64;
    const int am = tid >> 2, ac = tid & 3;
    float acc[4][4] = {};
    for (int k0 = 0; k0 < K; k0 += 16) {
        float4 a4 = *(const float4*)&A[(size_t)(bm + am) * K + k0 + ac * 4];
        As[ac * 4 + 0][am] = a4.x;
        As[ac * 4 + 1][am] = a4.y;
        As[ac * 4 + 2][am] = a4.z;
        As[ac * 4 + 3][am] = a4.w;
        *(float4*)&Bs[ty][tx * 4] = *(const float4*)&Bw[(size_t)(k0 + ty) * N + bn + tx * 4];
        __syncthreads();
#pragma unroll
        for (int kk = 0; kk < 16; ++kk) {
            float4 av = *(const float4*)&As[kk][ty * 4];
            float4 bv = *(const float4*)&Bs[kk][tx * 4];
            float a[4] = {av.x, av.y, av.z, av.w};
            float b[4] = {bv.x, bv.y, bv.z, bv.w};
#pragma unroll
            for (int i = 0; i < 4; ++i)
#pragma unroll
                for (int j = 0; j < 4; ++j) acc[i][j] += a[i] * b[j];
        }
        __syncthreads();
    }
#pragma unroll
    for (int i = 0; i < 4; ++i) {
        int m = bm + ty * 4 + i;
        int b = m >> 7, k = m & 127;
#pragma unroll
        for (int j = 0; j < 4; ++j) {
            int n = bn + tx * 4 + j;
            float v = acc[i][j];
            if (n < DIM_) {
                unsigned short hi, lo;
                cvt_hilo(v, hi, lo);
                int h = n >> 5, d = n & 31;
                size_t o = ((size_t)(b * H_ + h) * KL_ + k) * HD_ + d;
                Kqh[o] = hi;
                Kql[o] = lo;
            } else if (n < 2 * DIM_) {
                int nn = n - DIM_, h = nn >> 5, d = nn & 31;
                Kk_bf[((size_t)(b * H_ + h) * KL_ + k) * HD_ + d] = f2bf(v);
            } else {
                int nn = n - 2 * DIM_, h = nn >> 5, d = nn & 31;
                VT_bf[((size_t)(b * H_ + h) * HD_ + d) * KL_ + k] = f2bf(v);
            }
        }
    }
}

// ===========================================================================
// K1 v11: rp16 packed rd|polar loads (unchanged)
// ===========================================================================
__global__ __launch_bounds__(256) void score_bins_mfma4(const unsigned short* __restrict__ kxh,
                                                        const unsigned short* __restrict__ kxl,
                                                        const unsigned short* __restrict__ Kqh_g,
                                                        const unsigned short* __restrict__ Kql_g,
                                                        const unsigned short* __restrict__ rp16,
                                                        const unsigned int* __restrict__ mbits,
                                                        const float* __restrict__ dis_embed,
                                                        __hip_bfloat16* __restrict__ Sg,
                                                        float* __restrict__ binspart) {
    const int b = blockIdx.z, h = blockIdx.y, xc = blockIdx.x;
    const int x0 = xc * 64;
    const int tid = threadIdx.x;
    const int w = tid >> 6, lane = tid & 63;
    const int c15 = lane & 15, q = lane >> 4;
    const size_t bh = (size_t)(b * H_ + h);

    __shared__ unsigned int mskb[64][5];
    __shared__ float de_h[NDIS_];
    __shared__ float binsL[8][4][16][PB_ + 1];
    __shared__ __align__(16) unsigned short Ss[2][16][72];

    {
        int xr = tid >> 2, kg = tid & 3;
        mskb[xr][kg] = mbits[(bh * XL_ + x0 + xr) * 4 + kg];
    }
    if (tid < NDIS_) de_h[tid] = dis_embed[tid * H_ + h];
    __syncthreads();

    v8s axh, axl;
    {
        const size_t aoff = ((size_t)b * XL_ + x0 + w * 16 + c15) * DIM_ + h * HD_ + q * 8;
        axh = *(const v8s*)&kxh[aoff];
        axl = *(const v8s*)&kxl[aoff];
    }

    v8s bqh[2], bql[2];
    uint2 rp2[2];
    auto load_nt = [&](int nt, int s) {
        const int k = nt * 16 + c15;
        const size_t kqoff = (bh * KL_ + k) * HD_ + q * 8;
        bqh[s] = *(const v8s*)&Kqh_g[kqoff];
        bql[s] = *(const v8s*)&Kql_g[kqoff];
        const size_t rowoff = ((size_t)(b * KL_ + k)) * XL_ + x0 + w * 16 + q * 4;
        rp2[s] = *(const uint2*)&rp16[rowoff];
    };
    load_nt(0, 0);

#pragma unroll
    for (int nt = 0; nt < 8; ++nt) {
        const int s = nt & 1;
        if (nt < 7) load_nt(nt + 1, s ^ 1);

        const int k = nt * 16 + c15;
        v4f D = {0.f, 0.f, 0.f, 0.f};
        D = __builtin_amdgcn_mfma_f32_16x16x32_bf16(axl, bqh[s], D, 0, 0, 0);
        D = __builtin_amdgcn_mfma_f32_16x16x32_bf16(axh, bql[s], D, 0, 0, 0);
        D = __builtin_amdgcn_mfma_f32_16x16x32_bf16(axh, bqh[s], D, 0, 0, 0);

        float bins[PB_] = {};
        {
            const unsigned short* rpv = (const unsigned short*)&rp2[s];
            ushort4 pack;
#pragma unroll
            for (int r = 0; r < 4; ++r) {
                float sc = D[r] * SCALE_;
                float a = fabsf(sc);
                int pv = (rpv[r] >> 8) & 7;
#pragma unroll
                for (int pb = 0; pb < PB_; ++pb) bins[pb] += (pv == pb) ? a : 0.0f;
                int xloc = w * 16 + q * 4 + r;
                int mbit = (mskb[xloc][k >> 5] >> (k & 31)) & 1;
                float sp = (mbit ? -1e6f : sc) + de_h[rpv[r] & 0x7F];
                ((unsigned short*)&pack)[r] = f2bf(sp);
            }
            *(ushort4*)&Ss[s][c15][w * 16 + q * 4] = pack;
        }

#pragma unroll
        for (int pb = 0; pb < PB_; ++pb) {
            bins[pb] += __shfl_xor(bins[pb], 16);
            bins[pb] += __shfl_xor(bins[pb], 32);
        }
        if (q == 0) {
#pragma unroll
            for (int pb = 0; pb < PB_; ++pb) binsL[nt][w][c15][pb] = bins[pb];
        }

        __syncthreads();
        {
            int row = tid >> 4, seg = tid & 15;
            unsigned short* dst = (unsigned short*)Sg +
                (bh * KL_ + nt * 16 + row) * XL_ + x0 + seg * 4;
            *(uint2*)dst = *(const uint2*)&Ss[s][row][seg * 4];
        }
    }
    __syncthreads();
    {
        int k = tid >> 1, half = tid & 1;
        int nt = k >> 4, c = k & 15;
        float4 s = {0.f, 0.f, 0.f, 0.f};
#pragma unroll
        for (int w4 = 0; w4 < 4; ++w4) {
            const float* bp = &binsL[nt][w4][c][half * 4];
            s.x += bp[0]; s.y += bp[1]; s.z += bp[2]; s.w += bp[3];
        }
        *(float4*)&binspart[(bh * KL_ + k) * (NCH2_ * PB_) + xc * PB_ + half * 4] = s;
    }
}

// K2: argmax (unchanged)
__global__ __launch_bounds__(256) void bins_argmax(const float* __restrict__ binspart,
                                                   int* __restrict__ main_ori) {
    const int w = threadIdx.x >> 6, lane = threadIdx.x & 63;
    const int row = blockIdx.x * 4 + w;
    float s[PB_];
#pragma unroll
    for (int pb = 0; pb < PB_; ++pb) s[pb] = 0.0f;
    if (lane < NCH2_) {
        const float* bp = &binspart[(size_t)row * (NCH2_ * PB_) + lane * PB_];
#pragma unroll
        for (int pb = 0; pb < PB_; ++pb) s[pb] = bp[pb];
    }
#pragma unroll
    for (int m = 1; m < 64; m <<= 1)
#pragma unroll
        for (int pb = 0; pb < PB_; ++pb) s[pb] += __shfl_xor(s[pb], m);
    if (lane == 0) {
        float best = s[0];
        int bi = 0;
#pragma unroll
        for (int pb = 1; pb < PB_; ++pb)
            if (s[pb] > best) { best = s[pb]; bi = pb; }
        main_ori[row] = bi;
    }
}

// ===========================================================================
// K3 v4: flash_mfma (unchanged)
// ===========================================================================
__global__ __launch_bounds__(256) void flash_mfma(const __hip_bfloat16* __restrict__ Sg,
                                                  const unsigned int* __restrict__ pp4,
                                                  const unsigned short* __restrict__ VTx,
                                                  const float* __restrict__ polar_emb,
                                                  const int* __restrict__ main_ori,
                                                  float* __restrict__ part) {
    const int b = blockIdx.z, h = blockIdx.y, xc = blockIdx.x;
    const int tid = threadIdx.x;
    const int w = tid >> 6, lane = tid & 63;
    const int c = lane & 15, q = lane >> 4;
    const size_t bh = (size_t)(b * H_ + h);
    const int xbeg = xc * XC2_;

    __shared__ int mo_s[KL_];
    __shared__ float pe_s[PB_];
    if (tid < KL_) mo_s[tid] = main_ori[bh * KL_ + tid];
    if (tid < PB_) pe_s[tid] = polar_emb[tid];
    __syncthreads();

    const int wk0 = w * 32;
    const int mo[2] = {mo_s[wk0 + c], mo_s[wk0 + 16 + c]};
    const unsigned short* SgU = (const unsigned short*)Sg;

    v4f acc[2][2] = {};
    float lsum[2] = {0.f, 0.f};

    for (int s = 0; s < XC2_ / 32; ++s) {
        const int xs = xbeg + s * 32;
        v8s pa[2];
#pragma unroll
        for (int kt = 0; kt < 2; ++kt) {
            const int k = wk0 + kt * 16 + c;
            v8s sv = *(const v8s*)&SgU[(bh * KL_ + k) * XL_ + xs + q * 8];
            unsigned pw = pp4[((size_t)(b * KL_ + k)) * (XL_ / 8) + (xs >> 3) + q];
            unsigned short pk[8];
#pragma unroll
            for (int j = 0; j < 8; ++j) {
                float sp = bf2f((unsigned short)sv[j]);
                int np = (((int)(pw >> (j * 4)) & 7) - mo[kt]) & 7;
                float p = __expf(sp + pe_s[np]);
                unsigned short pb = f2bf(p);
                pk[j] = pb;
                lsum[kt] += bf2f(pb);
            }
            pa[kt] = *(v8s*)pk;
        }
#pragma unroll
        for (int dt = 0; dt < 2; ++dt) {
            v8s bv = *(const v8s*)&VTx[((size_t)bh * HD_ + dt * 16 + c) * XL_ + xs + q * 8];
            acc[0][dt] = __builtin_amdgcn_mfma_f32_16x16x32_bf16(pa[0], bv, acc[0][dt], 0, 0, 0);
            acc[1][dt] = __builtin_amdgcn_mfma_f32_16x16x32_bf16(pa[1], bv, acc[1][dt], 0, 0, 0);
        }
    }

#pragma unroll
    for (int kt = 0; kt < 2; ++kt) {
        lsum[kt] += __shfl_xor(lsum[kt], 16);
        lsum[kt] += __shfl_xor(lsum[kt], 32);
    }
#pragma unroll
    for (int kt = 0; kt < 2; ++kt) {
#pragma unroll
        for (int dt = 0; dt < 2; ++dt) {
#pragma unroll
            for (int r = 0; r < 4; ++r) {
                int krow = wk0 + kt * 16 + q * 4 + r;
                part[((size_t)(bh * KL_ + krow) * NS2_ + xc) * 36 + dt * 16 + c] = acc[kt][dt][r];
            }
        }
        if (q == 0) {
            int krow = wk0 + kt * 16 + c;
            part[((size_t)(bh * KL_ + krow) * NS2_ + xc) * 36 + 32] = lsum[kt];
        }
    }
}

// K4: merge over NS2_ chunks
__global__ __launch_bounds__(256) void merge_cached(const float* __restrict__ part,
                                                    float* __restrict__ kout_pre) {
    const int tid = threadIdx.x;
    const int ri = tid >> 5, d = tid & 31;
    const int row = blockIdx.x * 8 + ri;
    float l = 0.f, a = 0.f;
#pragma unroll 4
    for (int c = 0; c < NS2_; ++c) {
        const float* p = &part[((size_t)row * NS2_ + c) * 36];
        l += p[32];
        a += p[d];
    }
    int k = row & (KL_ - 1);
    int bh = row >> 7;
    int h = bh & (H_ - 1), b = bh >> 3;
    kout_pre[(size_t)(b * KL_ + k) * DIM_ + h * HD_ + d] = a / l;
}

// ===========================================================================
// attn_x_mfma v5 (unchanged)
// ===========================================================================
__global__ __launch_bounds__(256) void attn_x_mfma(const unsigned short* __restrict__ qxh,
                                                   const unsigned short* __restrict__ Kk_bf,
                                                   const unsigned short* __restrict__ VT_bf,
                                                   const unsigned short* __restrict__ rp16,
                                                   const unsigned int* __restrict__ mbits,
                                                   const float* __restrict__ dis_embed,
                                                   const float* __restrict__ polar_emb,
                                                   const int* __restrict__ main_ori,
                                                   unsigned short* __restrict__ oh,
                                                   unsigned short* __restrict__ ol) {
    const int b = blockIdx.z, h = blockIdx.y;
    const int x0 = blockIdx.x * 64;
    const int tid = threadIdx.x;
    const int wave = tid >> 6, lane = tid & 63;
    const int c = lane & 15, q = lane >> 4;

    __shared__ __align__(16) unsigned short P_s[4][16][136];
    __shared__ unsigned short rp_s[KL_][72];
    __shared__ unsigned int msk_s[64][5];
    __shared__ float de_h[NDIS_];
    __shared__ float pe[PB_];
    __shared__ int mo_s[KL_];

    const size_t bh = (size_t)(b * H_ + h);
    if (tid < NDIS_) de_h[tid] = dis_embed[tid * H_ + h];
    if (tid < PB_) pe[tid] = polar_emb[tid];
    if (tid < KL_) mo_s[tid] = main_ori[bh * KL_ + tid];
    {
        int xr = tid >> 2, kg = tid & 3;
        msk_s[xr][kg] = mbits[(bh * XL_ + x0 + xr) * 4 + kg];
    }
    __syncthreads();

#pragma unroll
    for (int i = 0; i < 8; ++i) {
        int id = tid + 256 * i;          // 2048 chunks of 4 u16
        int k = id >> 4, ch = id & 15;
        uint2 v = *(const uint2*)&rp16[((size_t)(b * KL_ + k)) * XL_ + x0 + ch * 4];
        int mo = mo_s[k];
        const unsigned short* pv = (const unsigned short*)&v;
        unsigned short outv[4];
#pragma unroll
        for (int j = 0; j < 4; ++j) {
            int np = (((pv[j] >> 8) & 7) - mo) & 7;
            outv[j] = (unsigned short)((pv[j] & 0x7F) | (np << 8));
        }
        *(uint2*)&rp_s[k][ch * 4] = *(uint2*)&outv[0];
    }
    __syncthreads();

    v8s aq = *(const v8s*)&qxh[(size_t)(b * XL_ + x0 + wave * 16 + c) * DIM_ + h * HD_ + q * 8];

    const unsigned short* KkB = &Kk_bf[(size_t)bh * KL_ * HD_];
    v4f S[8];
#pragma unroll
    for (int t = 0; t < 8; ++t) {
        v8s bk = *(const v8s*)&KkB[(size_t)(t * 16 + c) * HD_ + q * 8];
        S[t] = __builtin_amdgcn_mfma_f32_16x16x32_bf16(aq, bk, (v4f){0.f, 0.f, 0.f, 0.f}, 0, 0, 0);
    }

    const int xloc = wave * 16;
    float lr[4] = {0.f, 0.f, 0.f, 0.f};
#pragma unroll
    for (int t = 0; t < 8; ++t) {
#pragma unroll
        for (int r = 0; r < 4; ++r) {
            int krow = t * 16 + c;
            int xrow = q * 4 + r;
            unsigned short rp = rp_s[krow][xloc + xrow];
            int mbit = (msk_s[xloc + xrow][krow >> 5] >> (krow & 31)) & 1;
            float sval = S[t][r] * SCALE_;
            float tval = (mbit ? -25.0f : sval) + de_h[rp & 0x7f] + pe[(rp >> 8) & 7];
            float p = __expf(tval);
            unsigned short pb = f2bf(p);
            P_s[wave][xrow][krow] = pb;
            lr[r] += bf2f(pb);
        }
    }
#pragma unroll
    for (int r = 0; r < 4; ++r) {
#pragma unroll
        for (int m = 1; m < 16; m <<= 1) lr[r] += __shfl_xor(lr[r], m);
    }
    __syncthreads();

    const unsigned short* VTB = &VT_bf[(size_t)bh * HD_ * KL_];
    v4f O0 = {0.f, 0.f, 0.f, 0.f}, O1 = {0.f, 0.f, 0.f, 0.f};
#pragma unroll
    for (int kc = 0; kc < 4; ++kc) {
        v8s ap = *(v8s*)&P_s[wave][c][kc * 32 + q * 8];
        v8s bv0 = *(const v8s*)&VTB[(size_t)c * KL_ + kc * 32 + q * 8];
        v8s bv1 = *(const v8s*)&VTB[(size_t)(16 + c) * KL_ + kc * 32 + q * 8];
        O0 = __builtin_amdgcn_mfma_f32_16x16x32_bf16(ap, bv0, O0, 0, 0, 0);
        O1 = __builtin_amdgcn_mfma_f32_16x16x32_bf16(ap, bv1, O1, 0, 0, 0);
    }

#pragma unroll
    for (int r = 0; r < 4; ++r) {
        int xg = x0 + wave * 16 + q * 4 + r;
        float inv = 1.0f / lr[r];
        size_t obase = (size_t)(b * XL_ + xg) * DIM_ + h * HD_;
        float v0 = O0[r] * inv;
        float v1 = O1[r] * inv;
        unsigned short h0, l0, h1, l1;
        cvt_hilo(v0, h0, l0);
        cvt_hilo(v1, h1, l1);
        oh[obase + c] = h0;
        ol[obase + c] = l0;
        oh[obase + 16 + c] = h1;
        ol[obase + 16 + c] = l1;
    }
}

// ---------------------------------------------------------------------------
extern "C" void kernel_launch(void* const* d_in, const int* in_sizes, int n_in,
                              void* d_out, int out_size, void* d_ws, size_t ws_size,
                              hipStream_t stream) {
    const float* x         = (const float*)d_in[0];
    const float* kernal    = (const float*)d_in[1];
    const int* rd          = (const int*)d_in[2];
    const int* polar_pos   = (const int*)d_in[3];
    const int* att_mask    = (const int*)d_in[4];
    const float* W_qkv     = (const float*)d_in[5];
    const float* dis_embed = (const float*)d_in[6];
    const float* polar_emb = (const float*)d_in[7];
    const float* W_proj    = (const float*)d_in[8];
    const float* b_proj    = (const float*)d_in[9];
    float* out             = (float*)d_out;

    char* base = (char*)d_ws;
    size_t off = 0;
    auto alloc = [&](size_t bytes) { void* p = base + off; off = (off + bytes + 255) & ~255ULL; return p; };
    const size_t MX = (size_t)B_ * XL_;

    unsigned short* VTx = (unsigned short*)alloc((size_t)B_ * H_ * HD_ * XL_ * 2);
    unsigned short* qxh = (unsigned short*)alloc(MX * DIM_ * 2);
    unsigned short* kxh = (unsigned short*)alloc(MX * DIM_ * 2);
    unsigned short* kxl = (unsigned short*)alloc(MX * DIM_ * 2);
    float* binspart  = (float*)alloc((size_t)B_ * H_ * KL_ * NCH2_ * PB_ * 4);
    float* kout_pre  = (float*)alloc((size_t)B_ * KL_ * DIM_ * 4);
    int* main_ori    = (int*)alloc(B_ * H_ * KL_ * 4);
    float* part      = (float*)alloc((size_t)B_ * H_ * KL_ * NS2_ * 36 * 4);
    __hip_bfloat16* Sg = (__hip_bfloat16*)alloc((size_t)B_ * H_ * KL_ * XL_ * 2);
    unsigned short* wph = (unsigned short*)alloc((size_t)DIM_ * DIM_ * 2);
    unsigned short* wpl = (unsigned short*)alloc((size_t)DIM_ * DIM_ * 2);
    unsigned short* wqh = (unsigned short*)alloc((size_t)TDIM_ * DIM_ * 2);
    unsigned short* wql = (unsigned short*)alloc((size_t)TDIM_ * DIM_ * 2);
    unsigned int* mbits = (unsigned int*)alloc((size_t)B_ * H_ * XL_ * (KL_ / 32) * 4);
    unsigned int* pp4   = (unsigned int*)alloc((size_t)B_ * KL_ * (XL_ / 8) * 4);
    unsigned short* rp16 = (unsigned short*)alloc((size_t)B_ * KL_ * XL_ * 2);
    unsigned short* Kqh_g = (unsigned short*)alloc((size_t)B_ * H_ * KL_ * HD_ * 2);
    unsigned short* Kql_g = (unsigned short*)alloc((size_t)B_ * H_ * KL_ * HD_ * 2);
    unsigned short* Kk_bf = (unsigned short*)alloc((size_t)B_ * H_ * KL_ * HD_ * 2);
    unsigned short* VT_bf = (unsigned short*)alloc((size_t)B_ * H_ * HD_ * KL_ * 2);

    // oh/ol alias into Sg region (written by attn_x after flash consumed Sg)
    unsigned short* oh = (unsigned short*)Sg;
    unsigned short* ol = oh + MX * DIM_;

    // --- fused preamble (1 launch; x conversion inside gemm_qkv) ---
    preamble<<<dim3(NB_PACK_ + NB_WQ_ + NB_WP_ + NB_PP_), 256, 0, stream>>>(
        att_mask, W_qkv, W_proj, polar_pos, rd, mbits, wqh, wql, wph, wpl, pp4, rp16);

    // --- qkv projections ---
    gemm_qkv<<<dim3((TDIM_ / 128) * (MX / 128)), 256, 0, stream>>>(
        x, wqh, wql, MX, TDIM_, DIM_, qxh, kxh, kxl, VTx);
    gemm64_qkv<<<dim3(TDIM_ / 64, (B_ * KL_) / 64), 256, 0, stream>>>(
        kernal, W_qkv, Kqh_g, Kql_g, Kk_bf, VT_bf, B_ * KL_, TDIM_, DIM_);

    // --- k-direction ---
    score_bins_mfma4<<<dim3(NCH2_, H_, B_), 256, 0, stream>>>(
        kxh, kxl, Kqh_g, Kql_g, rp16, mbits, dis_embed, Sg, binspart);
    bins_argmax<<<dim3(B_ * H_ * KL_ / 4), 256, 0, stream>>>(binspart, main_ori);
    flash_mfma<<<dim3(NS2_, H_, B_), 256, 0, stream>>>(
        Sg, pp4, VTx, polar_emb, main_ori, part);
    merge_cached<<<dim3(B_ * H_ * KL_ / 8), 256, 0, stream>>>(part, kout_pre);

    // --- x-direction ---
    attn_x_mfma<<<dim3(XL_ / 64, H_, B_), 256, 0, stream>>>(
        qxh, Kk_bf, VT_bf, rp16, mbits, dis_embed, polar_emb, main_ori, oh, ol);

    // --- output projections ---
    gemm_out<<<dim3((DIM_ / 128) * (MX / 128)), 256, 0, stream>>>(
        oh, ol, wph, wpl, out, b_proj, MX, DIM_, DIM_);
    gemm64<<<dim3(DIM_ / 64, (B_ * KL_) / 64), 256, 0, stream>>>(
        kout_pre, W_proj, out + (size_t)B_ * XL_ * DIM_, b_proj, B_ * KL_, DIM_, DIM_);
}

// Round 14
// 305.871 us; speedup vs baseline: 1.0248x; 1.0232x over previous
//
#include <hip/hip_runtime.h>
#include <hip/hip_bf16.h>

#define B_    4
#define KL_   128
#define XL_   4096
#define DIM_  256
#define H_    8
#define HD_   32
#define PB_   8
#define NDIS_ 66
#define TDIM_ 768
#define SCALE_ 0.17677669529663687f
#define NCH2_ 64
#define NS2_  32               // flash x-chunks
#define XC2_  (XL_ / NS2_)     // 128 x per chunk
#define SC_PITCH_ 69           // epilogue scratch pitch (69%32=5, gcd=1 -> 2-way)

// preamble grid partition
#define NB_PACK_ 2048
#define NB_WQ_   768
#define NB_WP_   256
#define NB_PP_   1024

typedef float v4f __attribute__((ext_vector_type(4)));
typedef short v8s __attribute__((ext_vector_type(8)));

__device__ __forceinline__ unsigned short f2bf(float f) {
    __hip_bfloat16 h = __float2bfloat16(f);
    return __builtin_bit_cast(unsigned short, h);
}
__device__ __forceinline__ float bf2f(unsigned short u) {
    return __bfloat162float(__builtin_bit_cast(__hip_bfloat16, u));
}
__device__ __forceinline__ void cvt_hilo(float v, unsigned short& hi, unsigned short& lo) {
    hi = f2bf(v);
    lo = f2bf(v - bf2f(hi));
}

// ---------------------------------------------------------------------------
// preamble: pack_mask (ballot) + cvt_wT(W_qkv/W_proj) + {pp4 + rp16}
// ---------------------------------------------------------------------------
__global__ __launch_bounds__(256) void preamble(const int* __restrict__ att_mask,
                                                const float* __restrict__ W_qkv,
                                                const float* __restrict__ W_proj,
                                                const int* __restrict__ polar_pos,
                                                const int* __restrict__ rd,
                                                unsigned int* __restrict__ mbits,
                                                unsigned short* __restrict__ wqh,
                                                unsigned short* __restrict__ wql,
                                                unsigned short* __restrict__ wph,
                                                unsigned short* __restrict__ wpl,
                                                unsigned int* __restrict__ pp4,
                                                unsigned short* __restrict__ rp16) {
    const int bid = blockIdx.x, tid = threadIdx.x;
    if (bid < NB_PACK_) {
        const int w = tid >> 6, lane = tid & 63;
        const size_t ibase = (((size_t)bid * 4 + w) * 32) * 64;
#pragma unroll
        for (int u = 0; u < 4; ++u) {
            int vals[8];
#pragma unroll
            for (int i = 0; i < 8; ++i)
                vals[i] = att_mask[ibase + (size_t)(u * 8 + i) * 64 + lane];
            unsigned long long bm0 = __ballot(vals[0] != 0);
            unsigned long long bm1 = __ballot(vals[1] != 0);
            unsigned long long bm2 = __ballot(vals[2] != 0);
            unsigned long long bm3 = __ballot(vals[3] != 0);
            unsigned long long bm4 = __ballot(vals[4] != 0);
            unsigned long long bm5 = __ballot(vals[5] != 0);
            unsigned long long bm6 = __ballot(vals[6] != 0);
            unsigned long long bm7 = __ballot(vals[7] != 0);
            if (lane == 0) {
                size_t wb = ibase / 32 + (size_t)u * 16;
                *(uint2*)&mbits[wb + 0]  = make_uint2((unsigned)bm0, (unsigned)(bm0 >> 32));
                *(uint2*)&mbits[wb + 2]  = make_uint2((unsigned)bm1, (unsigned)(bm1 >> 32));
                *(uint2*)&mbits[wb + 4]  = make_uint2((unsigned)bm2, (unsigned)(bm2 >> 32));
                *(uint2*)&mbits[wb + 6]  = make_uint2((unsigned)bm3, (unsigned)(bm3 >> 32));
                *(uint2*)&mbits[wb + 8]  = make_uint2((unsigned)bm4, (unsigned)(bm4 >> 32));
                *(uint2*)&mbits[wb + 10] = make_uint2((unsigned)bm5, (unsigned)(bm5 >> 32));
                *(uint2*)&mbits[wb + 12] = make_uint2((unsigned)bm6, (unsigned)(bm6 >> 32));
                *(uint2*)&mbits[wb + 14] = make_uint2((unsigned)bm7, (unsigned)(bm7 >> 32));
            }
        }
    } else if (bid < NB_PACK_ + NB_WQ_) {
        int n = bid - NB_PACK_, k = tid;
        float v = W_qkv[(size_t)k * TDIM_ + n];
        unsigned short h, l;
        cvt_hilo(v, h, l);
        wqh[(size_t)n * DIM_ + k] = h;
        wql[(size_t)n * DIM_ + k] = l;
    } else if (bid < NB_PACK_ + NB_WQ_ + NB_WP_) {
        int n = bid - (NB_PACK_ + NB_WQ_), k = tid;
        float v = W_proj[(size_t)k * DIM_ + n];
        unsigned short h, l;
        cvt_hilo(v, h, l);
        wph[(size_t)n * DIM_ + k] = h;
        wpl[(size_t)n * DIM_ + k] = l;
    } else {
        size_t wid = (size_t)(bid - (NB_PACK_ + NB_WQ_ + NB_WP_)) * 256 + tid;
        const int* srcp = &polar_pos[wid * 8];
        const int* srcr = &rd[wid * 8];
        int4 a = *(const int4*)&srcp[0];
        int4 b4 = *(const int4*)&srcp[4];
        int4 ra = *(const int4*)&srcr[0];
        int4 rb = *(const int4*)&srcr[4];
        unsigned pk = (unsigned)(a.x & 7) | ((unsigned)(a.y & 7) << 4) |
                      ((unsigned)(a.z & 7) << 8) | ((unsigned)(a.w & 7) << 12) |
                      ((unsigned)(b4.x & 7) << 16) | ((unsigned)(b4.y & 7) << 20) |
                      ((unsigned)(b4.z & 7) << 24) | ((unsigned)(b4.w & 7) << 28);
        pp4[wid] = pk;
        unsigned short rp[8];
        rp[0] = (unsigned short)(ra.x | ((a.x & 7) << 8));
        rp[1] = (unsigned short)(ra.y | ((a.y & 7) << 8));
        rp[2] = (unsigned short)(ra.z | ((a.z & 7) << 8));
        rp[3] = (unsigned short)(ra.w | ((a.w & 7) << 8));
        rp[4] = (unsigned short)(rb.x | ((b4.x & 7) << 8));
        rp[5] = (unsigned short)(rb.y | ((b4.y & 7) << 8));
        rp[6] = (unsigned short)(rb.z | ((b4.z & 7) << 8));
        rp[7] = (unsigned short)(rb.w | ((b4.w & 7) << 8));
        *(uint4*)&rp16[wid * 8] = *(uint4*)&rp[0];
    }
}

// ---------------------------------------------------------------------------
// gemm_out v2: BM=64 (grid 2x blocks/CU), bf16 tiles unit-swizzled.
// Launch: (N/128)*(M/64) linear blocks; M/64 must be multiple of 8.
// ---------------------------------------------------------------------------
__global__ __launch_bounds__(256) void gemm_out(const unsigned short* __restrict__ Ah,
                                                const unsigned short* __restrict__ Al,
                                                const unsigned short* __restrict__ Bh,
                                                const unsigned short* __restrict__ Bl,
                                                float* __restrict__ C,
                                                const float* __restrict__ bias,
                                                int M, int N, int K) {
    __shared__ __align__(16) unsigned short Ah_s[64 * 32];
    __shared__ __align__(16) unsigned short Al_s[64 * 32];
    __shared__ __align__(16) unsigned short Bh_s[128 * 32];
    __shared__ __align__(16) unsigned short Bl_s[128 * 32];
    const int tid = threadIdx.x;
    const int w = tid >> 6, lane = tid & 63;
    const int c = lane & 15, q = lane >> 4;

    const int NBX = N >> 7;
    const int id = blockIdx.x;
    const int xcd = id & 7, grp = id >> 3;
    const int bm = ((grp / NBX) * 8 + xcd) * 64;
    const int bn = (grp % NBX) * 128;

    const int lrow = lane >> 2;
    const int lcol = (((lane & 3) ^ ((lane >> 2) & 3)) * 8);

    v4f acc[8] = {};
    for (int k0 = 0; k0 < K; k0 += 32) {
        __syncthreads();
        {
            // A: 4 chunks of 16 rows; wave w issues chunk w
            const int row = w * 16 + lrow;
            const size_t ga = (size_t)(bm + row) * K + k0 + lcol;
            __builtin_amdgcn_global_load_lds(
                (const __attribute__((address_space(1))) unsigned int*)&Ah[ga],
                (__attribute__((address_space(3))) unsigned int*)&Ah_s[w * 512], 16, 0, 0);
            __builtin_amdgcn_global_load_lds(
                (const __attribute__((address_space(1))) unsigned int*)&Al[ga],
                (__attribute__((address_space(3))) unsigned int*)&Al_s[w * 512], 16, 0, 0);
        }
#pragma unroll
        for (int i = 0; i < 2; ++i) {
            const int chunk = w * 2 + i;
            const int row = chunk * 16 + lrow;
            const size_t gb = (size_t)(bn + row) * K + k0 + lcol;
            __builtin_amdgcn_global_load_lds(
                (const __attribute__((address_space(1))) unsigned int*)&Bh[gb],
                (__attribute__((address_space(3))) unsigned int*)&Bh_s[chunk * 512], 16, 0, 0);
            __builtin_amdgcn_global_load_lds(
                (const __attribute__((address_space(1))) unsigned int*)&Bl[gb],
                (__attribute__((address_space(3))) unsigned int*)&Bl_s[chunk * 512], 16, 0, 0);
        }
        asm volatile("s_waitcnt vmcnt(0)" ::: "memory");
        __syncthreads();
        const int uA = (q ^ (c & 3)) * 8;
        v8s afh = *(v8s*)&Ah_s[(w * 16 + c) * 32 + uA];
        v8s afl = *(v8s*)&Al_s[(w * 16 + c) * 32 + uA];
#pragma unroll
        for (int nt = 0; nt < 8; ++nt) {
            v8s bfh = *(v8s*)&Bh_s[(nt * 16 + c) * 32 + uA];
            v8s bfl = *(v8s*)&Bl_s[(nt * 16 + c) * 32 + uA];
            acc[nt] = __builtin_amdgcn_mfma_f32_16x16x32_bf16(afl, bfh, acc[nt], 0, 0, 0);
            acc[nt] = __builtin_amdgcn_mfma_f32_16x16x32_bf16(afh, bfl, acc[nt], 0, 0, 0);
            acc[nt] = __builtin_amdgcn_mfma_f32_16x16x32_bf16(afh, bfh, acc[nt], 0, 0, 0);
        }
    }
#pragma unroll
    for (int nt = 0; nt < 8; ++nt) {
        int col = bn + nt * 16 + c;
        float bv = bias ? bias[col] : 0.0f;
#pragma unroll
        for (int r = 0; r < 4; ++r) {
            int row = bm + w * 16 + q * 4 + r;
            C[(size_t)row * N + col] = acc[nt][r] + bv;
        }
    }
}

// ---------------------------------------------------------------------------
// gemm_qkv v4: BM=64 (grid 1536 = 6 blocks/CU), LDS 24KB. A staged f32 with
// 8-unit XOR swizzle, converted to hi/lo at fragment build (bit-identical).
// q/k epilogue via scratch in TWO column halves (17.7KB <= 24KB union).
// ---------------------------------------------------------------------------
__global__ __launch_bounds__(256) void gemm_qkv(const float* __restrict__ X,
                                                const unsigned short* __restrict__ Bh,
                                                const unsigned short* __restrict__ Bl,
                                                int M, int N, int K,
                                                unsigned short* __restrict__ qh,
                                                unsigned short* __restrict__ kh,
                                                unsigned short* __restrict__ kl2,
                                                unsigned short* __restrict__ VTx) {
    __shared__ __align__(16) char SMEM[24576];
    float* Ax_s = (float*)SMEM;                               // 64x32 f32 = 8KB
    unsigned short* Bh_s = (unsigned short*)(SMEM + 8192);    // 8KB
    unsigned short* Bl_s = (unsigned short*)(SMEM + 16384);   // 8KB
    float* scratch = (float*)SMEM;                            // 64x69 f32 = 17.7KB

    const int tid = threadIdx.x;
    const int w = tid >> 6, lane = tid & 63;
    const int c = lane & 15, q = lane >> 4;

    const int NBX = N >> 7;
    const int id = blockIdx.x;
    const int xcd = id & 7, grp = id >> 3;
    const int bm = ((grp / NBX) * 8 + xcd) * 64;
    const int bn = (grp % NBX) * 128;

    // A f32: 8 rows/issue; logical unit (l&7)^(row&7), row&7 = l>>3
    const int arow = lane >> 3;
    const int acol = (((lane & 7) ^ (lane >> 3)) * 4);
    // B bf16: 16 rows/issue; logical unit (l&3)^(row&3)
    const int lrow = lane >> 2;
    const int lcol = (((lane & 3) ^ ((lane >> 2) & 3)) * 8);

    v4f acc[8] = {};
    for (int k0 = 0; k0 < K; k0 += 32) {
        __syncthreads();
#pragma unroll
        for (int i = 0; i < 2; ++i) {
            const int chunk = w * 2 + i;                 // 0..7, 8 rows each
            const int row = chunk * 8 + arow;
            const size_t ga = (size_t)(bm + row) * K + k0 + acol;
            __builtin_amdgcn_global_load_lds(
                (const __attribute__((address_space(1))) unsigned int*)&X[ga],
                (__attribute__((address_space(3))) unsigned int*)&Ax_s[chunk * 256], 16, 0, 0);
        }
#pragma unroll
        for (int i = 0; i < 2; ++i) {
            const int chunk = w * 2 + i;                 // 0..7, 16 rows each
            const int row = chunk * 16 + lrow;
            const size_t gb = (size_t)(bn + row) * K + k0 + lcol;
            __builtin_amdgcn_global_load_lds(
                (const __attribute__((address_space(1))) unsigned int*)&Bh[gb],
                (__attribute__((address_space(3))) unsigned int*)&Bh_s[chunk * 512], 16, 0, 0);
            __builtin_amdgcn_global_load_lds(
                (const __attribute__((address_space(1))) unsigned int*)&Bl[gb],
                (__attribute__((address_space(3))) unsigned int*)&Bl_s[chunk * 512], 16, 0, 0);
        }
        asm volatile("s_waitcnt vmcnt(0)" ::: "memory");
        __syncthreads();
        const int r7 = c & 7;
        const int uB = (q ^ (c & 3)) * 8;
        v8s afh, afl;
        {
            const float* sA = &Ax_s[(w * 16 + c) * 32];
            float4 f0 = *(const float4*)&sA[((2 * q) ^ r7) * 4];
            float4 f1 = *(const float4*)&sA[((2 * q + 1) ^ r7) * 4];
            float vv[8] = {f0.x, f0.y, f0.z, f0.w, f1.x, f1.y, f1.z, f1.w};
#pragma unroll
            for (int j = 0; j < 8; ++j) {
                unsigned short hi, lo;
                cvt_hilo(vv[j], hi, lo);
                ((short*)&afh)[j] = (short)hi;
                ((short*)&afl)[j] = (short)lo;
            }
        }
#pragma unroll
        for (int nt = 0; nt < 8; ++nt) {
            v8s bfh = *(v8s*)&Bh_s[(nt * 16 + c) * 32 + uB];
            v8s bfl = *(v8s*)&Bl_s[(nt * 16 + c) * 32 + uB];
            acc[nt] = __builtin_amdgcn_mfma_f32_16x16x32_bf16(afl, bfh, acc[nt], 0, 0, 0);
            acc[nt] = __builtin_amdgcn_mfma_f32_16x16x32_bf16(afh, bfl, acc[nt], 0, 0, 0);
            acc[nt] = __builtin_amdgcn_mfma_f32_16x16x32_bf16(afh, bfh, acc[nt], 0, 0, 0);
        }
    }
    if (bn >= 2 * DIM_) {
        // v segment: transposed bf16 store VTx[bh][d][x], 8B chunks
#pragma unroll
        for (int nt = 0; nt < 8; ++nt) {
            int nn = bn + nt * 16 + c - 2 * DIM_;
            int h = nn >> 5, d = nn & 31;
            int row0 = bm + w * 16 + q * 4;
            int b = row0 >> 12, x = row0 & (XL_ - 1);
            unsigned short t4[4];
#pragma unroll
            for (int r = 0; r < 4; ++r) t4[r] = f2bf(acc[nt][r]);
            *(ushort4*)&VTx[((size_t)(b * H_ + h) * HD_ + d) * XL_ + x] = *(ushort4*)&t4[0];
        }
    } else {
        // q / k segments: scratch-staged conversion, two 64-col halves
        for (int half = 0; half < 2; ++half) {
            __syncthreads();
#pragma unroll
            for (int nt = 0; nt < 4; ++nt) {
                int nt_g = half * 4 + nt;
#pragma unroll
                for (int r = 0; r < 4; ++r)
                    scratch[(w * 16 + q * 4 + r) * SC_PITCH_ + nt * 16 + c] = acc[nt_g][r];
            }
            __syncthreads();
            const int row = tid & 63, colseg = (tid >> 6) * 16;
            const int grow = bm + row;
            const float* src = &scratch[row * SC_PITCH_ + colseg];
            if (bn < DIM_) {
                unsigned short* dst = &qh[(size_t)grow * DIM_ + bn + half * 64 + colseg];
#pragma unroll
                for (int j8 = 0; j8 < 2; ++j8) {
                    unsigned short tmp[8];
#pragma unroll
                    for (int j = 0; j < 8; ++j) tmp[j] = f2bf(src[j8 * 8 + j]);
                    *(uint4*)&dst[j8 * 8] = *(uint4*)&tmp[0];
                }
            } else {
                const size_t o = (size_t)grow * DIM_ + bn - DIM_ + half * 64 + colseg;
#pragma unroll
                for (int j8 = 0; j8 < 2; ++j8) {
                    unsigned short th[8], tl[8];
#pragma unroll
                    for (int j = 0; j < 8; ++j) cvt_hilo(src[j8 * 8 + j], th[j], tl[j]);
                    *(uint4*)&kh[o + j8 * 8] = *(uint4*)&th[0];
                    *(uint4*)&kl2[o + j8 * 8] = *(uint4*)&tl[0];
                }
            }
        }
    }
}

// ---------------------------------------------------------------------------
// 64x64 f32 GEMM (small-M) — proj path
// ---------------------------------------------------------------------------
__global__ __launch_bounds__(256) void gemm64(const float* __restrict__ A,
                                              const float* __restrict__ Bw,
                                              float* __restrict__ C,
                                              const float* __restrict__ bias,
                                              int M, int N, int K) {
    __shared__ __align__(16) float As[16][68];
    __shared__ __align__(16) float Bs[16][64];
    const int tid = threadIdx.x;
    const int tx = tid & 15, ty = tid >> 4;
    const int bn = blockIdx.x * 64, bm = blockIdx.y * 64;
    const int am = tid >> 2, ac = tid & 3;
    float acc[4][4] = {};
    for (int k0 = 0; k0 < K; k0 += 16) {
        float4 a4 = *(const float4*)&A[(size_t)(bm + am) * K + k0 + ac * 4];
        As[ac * 4 + 0][am] = a4.x;
        As[ac * 4 + 1][am] = a4.y;
        As[ac * 4 + 2][am] = a4.z;
        As[ac * 4 + 3][am] = a4.w;
        *(float4*)&Bs[ty][tx * 4] = *(const float4*)&Bw[(size_t)(k0 + ty) * N + bn + tx * 4];
        __syncthreads();
#pragma unroll
        for (int kk = 0; kk < 16; ++kk) {
            float4 av = *(const float4*)&As[kk][ty * 4];
            float4 bv = *(const float4*)&Bs[kk][tx * 4];
            float a[4] = {av.x, av.y, av.z, av.w};
            float b[4] = {bv.x, bv.y, bv.z, bv.w};
#pragma unroll
            for (int i = 0; i < 4; ++i)
#pragma unroll
                for (int j = 0; j < 4; ++j) acc[i][j] += a[i] * b[j];
        }
        __syncthreads();
    }
#pragma unroll
    for (int i = 0; i < 4; ++i) {
        int m = bm + ty * 4 + i;
#pragma unroll
        for (int j = 0; j < 4; ++j) {
            int n = bn + tx * 4 + j;
            float v = acc[i][j];
            if (bias) v += bias[n];
            C[(size_t)m * N + n] = v;
        }
    }
}

// ---------------------------------------------------------------------------
// gemm64_qkv: kernal @ W_qkv with typed epilogue (unchanged)
// ---------------------------------------------------------------------------
__global__ __launch_bounds__(256) void gemm64_qkv(const float* __restrict__ A,
                                                  const float* __restrict__ Bw,
                                                  unsigned short* __restrict__ Kqh,
                                                  unsigned short* __restrict__ Kql,
                                                  unsigned short* __restrict__ Kk_bf,
                                                  unsigned short* __restrict__ VT_bf,
                                                  int M, int N, int K) {
    __shared__ __align__(16) float As[16][68];
    __shared__ __align__(16) float Bs[16][64];
    const int tid = threadIdx.x;
    const int tx = tid & 15, ty = tid >> 4;
    const int bn = blockIdx.x * 64, bm = blockIdx.y * 64;
    const int am = tid >> 2, ac = tid & 3;
    float acc[4][4] = {};
    for (int k0 = 0; k0 < K; k0 += 16) {
        float4 a4 = *(const float4*)&A[(size_t)(bm + am) * K + k0 + ac * 4];
        As[ac * 4 + 0][am] = a4.x;
        As[ac * 4 + 1][am] = a4.y;
        As[ac * 4 + 2][am] = a4.z;
        As[ac * 4 + 3][am] = a4.w;
        *(float4*)&Bs[ty][tx * 4] = *(const float4*)&Bw[(size_t)(k0 + ty) * N + bn + tx * 4];
        __syncthreads();
#pragma unroll
        for (int kk = 0; kk < 16; ++kk) {
            float4 av = *(const float4*)&As[kk][ty * 4];
            float4 bv = *(const float4*)&Bs[kk][tx * 4];
            float a[4] = {av.x, av.y, av.z, av.w};
            float b[4] = {bv.x, bv.y, bv.z, bv.w};
#pragma unroll
            for (int i = 0; i < 4; ++i)
#pragma unroll
                for (int j = 0; j < 4; ++j) acc[i][j] += a[i] * b[j];
        }
        __syncthreads();
    }
#pragma unroll
    for (int i = 0; i < 4; ++i) {
        int m = bm + ty * 4 + i;
        int b = m >> 7, k = m & 127;
#pragma unroll
        for (int j = 0; j < 4; ++j) {
            int n = bn + tx * 4 + j;
            float v = acc[i][j];
            if (n < DIM_) {
                unsigned short hi, lo;
                cvt_hilo(v, hi, lo);
                int h = n >> 5, d = n & 31;
                size_t o = ((size_t)(b * H_ + h) * KL_ + k) * HD_ + d;
                Kqh[o] = hi;
                Kql[o] = lo;
            } else if (n < 2 * DIM_) {
                int nn = n - DIM_, h = nn >> 5, d = nn & 31;
                Kk_bf[((size_t)(b * H_ + h) * KL_ + k) * HD_ + d] = f2bf(v);
            } else {
                int nn = n - 2 * DIM_, h = nn >> 5, d = nn & 31;
                VT_bf[((size_t)(b * H_ + h) * HD_ + d) * KL_ + k] = f2bf(v);
            }
        }
    }
}

// ===========================================================================
// K1 v11: rp16 packed rd|polar loads (unchanged)
// ===========================================================================
__global__ __launch_bounds__(256) void score_bins_mfma4(const unsigned short* __restrict__ kxh,
                                                        const unsigned short* __restrict__ kxl,
                                                        const unsigned short* __restrict__ Kqh_g,
                                                        const unsigned short* __restrict__ Kql_g,
                                                        const unsigned short* __restrict__ rp16,
                                                        const unsigned int* __restrict__ mbits,
                                                        const float* __restrict__ dis_embed,
                                                        __hip_bfloat16* __restrict__ Sg,
                                                        float* __restrict__ binspart) {
    const int b = blockIdx.z, h = blockIdx.y, xc = blockIdx.x;
    const int x0 = xc * 64;
    const int tid = threadIdx.x;
    const int w = tid >> 6, lane = tid & 63;
    const int c15 = lane & 15, q = lane >> 4;
    const size_t bh = (size_t)(b * H_ + h);

    __shared__ unsigned int mskb[64][5];
    __shared__ float de_h[NDIS_];
    __shared__ float binsL[8][4][16][PB_ + 1];
    __shared__ __align__(16) unsigned short Ss[2][16][72];

    {
        int xr = tid >> 2, kg = tid & 3;
        mskb[xr][kg] = mbits[(bh * XL_ + x0 + xr) * 4 + kg];
    }
    if (tid < NDIS_) de_h[tid] = dis_embed[tid * H_ + h];
    __syncthreads();

    v8s axh, axl;
    {
        const size_t aoff = ((size_t)b * XL_ + x0 + w * 16 + c15) * DIM_ + h * HD_ + q * 8;
        axh = *(const v8s*)&kxh[aoff];
        axl = *(const v8s*)&kxl[aoff];
    }

    v8s bqh[2], bql[2];
    uint2 rp2[2];
    auto load_nt = [&](int nt, int s) {
        const int k = nt * 16 + c15;
        const size_t kqoff = (bh * KL_ + k) * HD_ + q * 8;
        bqh[s] = *(const v8s*)&Kqh_g[kqoff];
        bql[s] = *(const v8s*)&Kql_g[kqoff];
        const size_t rowoff = ((size_t)(b * KL_ + k)) * XL_ + x0 + w * 16 + q * 4;
        rp2[s] = *(const uint2*)&rp16[rowoff];
    };
    load_nt(0, 0);

#pragma unroll
    for (int nt = 0; nt < 8; ++nt) {
        const int s = nt & 1;
        if (nt < 7) load_nt(nt + 1, s ^ 1);

        const int k = nt * 16 + c15;
        v4f D = {0.f, 0.f, 0.f, 0.f};
        D = __builtin_amdgcn_mfma_f32_16x16x32_bf16(axl, bqh[s], D, 0, 0, 0);
        D = __builtin_amdgcn_mfma_f32_16x16x32_bf16(axh, bql[s], D, 0, 0, 0);
        D = __builtin_amdgcn_mfma_f32_16x16x32_bf16(axh, bqh[s], D, 0, 0, 0);

        float bins[PB_] = {};
        {
            const unsigned short* rpv = (const unsigned short*)&rp2[s];
            ushort4 pack;
#pragma unroll
            for (int r = 0; r < 4; ++r) {
                float sc = D[r] * SCALE_;
                float a = fabsf(sc);
                int pv = (rpv[r] >> 8) & 7;
#pragma unroll
                for (int pb = 0; pb < PB_; ++pb) bins[pb] += (pv == pb) ? a : 0.0f;
                int xloc = w * 16 + q * 4 + r;
                int mbit = (mskb[xloc][k >> 5] >> (k & 31)) & 1;
                float sp = (mbit ? -1e6f : sc) + de_h[rpv[r] & 0x7F];
                ((unsigned short*)&pack)[r] = f2bf(sp);
            }
            *(ushort4*)&Ss[s][c15][w * 16 + q * 4] = pack;
        }

#pragma unroll
        for (int pb = 0; pb < PB_; ++pb) {
            bins[pb] += __shfl_xor(bins[pb], 16);
            bins[pb] += __shfl_xor(bins[pb], 32);
        }
        if (q == 0) {
#pragma unroll
            for (int pb = 0; pb < PB_; ++pb) binsL[nt][w][c15][pb] = bins[pb];
        }

        __syncthreads();
        {
            int row = tid >> 4, seg = tid & 15;
            unsigned short* dst = (unsigned short*)Sg +
                (bh * KL_ + nt * 16 + row) * XL_ + x0 + seg * 4;
            *(uint2*)dst = *(const uint2*)&Ss[s][row][seg * 4];
        }
    }
    __syncthreads();
    {
        int k = tid >> 1, half = tid & 1;
        int nt = k >> 4, c = k & 15;
        float4 s = {0.f, 0.f, 0.f, 0.f};
#pragma unroll
        for (int w4 = 0; w4 < 4; ++w4) {
            const float* bp = &binsL[nt][w4][c][half * 4];
            s.x += bp[0]; s.y += bp[1]; s.z += bp[2]; s.w += bp[3];
        }
        *(float4*)&binspart[(bh * KL_ + k) * (NCH2_ * PB_) + xc * PB_ + half * 4] = s;
    }
}

// K2: argmax (unchanged)
__global__ __launch_bounds__(256) void bins_argmax(const float* __restrict__ binspart,
                                                   int* __restrict__ main_ori) {
    const int w = threadIdx.x >> 6, lane = threadIdx.x & 63;
    const int row = blockIdx.x * 4 + w;
    float s[PB_];
#pragma unroll
    for (int pb = 0; pb < PB_; ++pb) s[pb] = 0.0f;
    if (lane < NCH2_) {
        const float* bp = &binspart[(size_t)row * (NCH2_ * PB_) + lane * PB_];
#pragma unroll
        for (int pb = 0; pb < PB_; ++pb) s[pb] = bp[pb];
    }
#pragma unroll
    for (int m = 1; m < 64; m <<= 1)
#pragma unroll
        for (int pb = 0; pb < PB_; ++pb) s[pb] += __shfl_xor(s[pb], m);
    if (lane == 0) {
        float best = s[0];
        int bi = 0;
#pragma unroll
        for (int pb = 1; pb < PB_; ++pb)
            if (s[pb] > best) { best = s[pb]; bi = pb; }
        main_ori[row] = bi;
    }
}

// ===========================================================================
// K3 v4: flash_mfma (unchanged)
// ===========================================================================
__global__ __launch_bounds__(256) void flash_mfma(const __hip_bfloat16* __restrict__ Sg,
                                                  const unsigned int* __restrict__ pp4,
                                                  const unsigned short* __restrict__ VTx,
                                                  const float* __restrict__ polar_emb,
                                                  const int* __restrict__ main_ori,
                                                  float* __restrict__ part) {
    const int b = blockIdx.z, h = blockIdx.y, xc = blockIdx.x;
    const int tid = threadIdx.x;
    const int w = tid >> 6, lane = tid & 63;
    const int c = lane & 15, q = lane >> 4;
    const size_t bh = (size_t)(b * H_ + h);
    const int xbeg = xc * XC2_;

    __shared__ int mo_s[KL_];
    __shared__ float pe_s[PB_];
    if (tid < KL_) mo_s[tid] = main_ori[bh * KL_ + tid];
    if (tid < PB_) pe_s[tid] = polar_emb[tid];
    __syncthreads();

    const int wk0 = w * 32;
    const int mo[2] = {mo_s[wk0 + c], mo_s[wk0 + 16 + c]};
    const unsigned short* SgU = (const unsigned short*)Sg;

    v4f acc[2][2] = {};
    float lsum[2] = {0.f, 0.f};

    for (int s = 0; s < XC2_ / 32; ++s) {
        const int xs = xbeg + s * 32;
        v8s pa[2];
#pragma unroll
        for (int kt = 0; kt < 2; ++kt) {
            const int k = wk0 + kt * 16 + c;
            v8s sv = *(const v8s*)&SgU[(bh * KL_ + k) * XL_ + xs + q * 8];
            unsigned pw = pp4[((size_t)(b * KL_ + k)) * (XL_ / 8) + (xs >> 3) + q];
            unsigned short pk[8];
#pragma unroll
            for (int j = 0; j < 8; ++j) {
                float sp = bf2f((unsigned short)sv[j]);
                int np = (((int)(pw >> (j * 4)) & 7) - mo[kt]) & 7;
                float p = __expf(sp + pe_s[np]);
                unsigned short pb = f2bf(p);
                pk[j] = pb;
                lsum[kt] += bf2f(pb);
            }
            pa[kt] = *(v8s*)pk;
        }
#pragma unroll
        for (int dt = 0; dt < 2; ++dt) {
            v8s bv = *(const v8s*)&VTx[((size_t)bh * HD_ + dt * 16 + c) * XL_ + xs + q * 8];
            acc[0][dt] = __builtin_amdgcn_mfma_f32_16x16x32_bf16(pa[0], bv, acc[0][dt], 0, 0, 0);
            acc[1][dt] = __builtin_amdgcn_mfma_f32_16x16x32_bf16(pa[1], bv, acc[1][dt], 0, 0, 0);
        }
    }

#pragma unroll
    for (int kt = 0; kt < 2; ++kt) {
        lsum[kt] += __shfl_xor(lsum[kt], 16);
        lsum[kt] += __shfl_xor(lsum[kt], 32);
    }
#pragma unroll
    for (int kt = 0; kt < 2; ++kt) {
#pragma unroll
        for (int dt = 0; dt < 2; ++dt) {
#pragma unroll
            for (int r = 0; r < 4; ++r) {
                int krow = wk0 + kt * 16 + q * 4 + r;
                part[((size_t)(bh * KL_ + krow) * NS2_ + xc) * 36 + dt * 16 + c] = acc[kt][dt][r];
            }
        }
        if (q == 0) {
            int krow = wk0 + kt * 16 + c;
            part[((size_t)(bh * KL_ + krow) * NS2_ + xc) * 36 + 32] = lsum[kt];
        }
    }
}

// K4: merge over NS2_ chunks
__global__ __launch_bounds__(256) void merge_cached(const float* __restrict__ part,
                                                    float* __restrict__ kout_pre) {
    const int tid = threadIdx.x;
    const int ri = tid >> 5, d = tid & 31;
    const int row = blockIdx.x * 8 + ri;
    float l = 0.f, a = 0.f;
#pragma unroll 4
    for (int c = 0; c < NS2_; ++c) {
        const float* p = &part[((size_t)row * NS2_ + c) * 36];
        l += p[32];
        a += p[d];
    }
    int k = row & (KL_ - 1);
    int bh = row >> 7;
    int h = bh & (H_ - 1), b = bh >> 3;
    kout_pre[(size_t)(b * KL_ + k) * DIM_ + h * HD_ + d] = a / l;
}

// ===========================================================================
// attn_x_mfma v5 (unchanged)
// ===========================================================================
__global__ __launch_bounds__(256) void attn_x_mfma(const unsigned short* __restrict__ qxh,
                                                   const unsigned short* __restrict__ Kk_bf,
                                                   const unsigned short* __restrict__ VT_bf,
                                                   const unsigned short* __restrict__ rp16,
                                                   const unsigned int* __restrict__ mbits,
                                                   const float* __restrict__ dis_embed,
                                                   const float* __restrict__ polar_emb,
                                                   const int* __restrict__ main_ori,
                                                   unsigned short* __restrict__ oh,
                                                   unsigned short* __restrict__ ol) {
    const int b = blockIdx.z, h = blockIdx.y;
    const int x0 = blockIdx.x * 64;
    const int tid = threadIdx.x;
    const int wave = tid >> 6, lane = tid & 63;
    const int c = lane & 15, q = lane >> 4;

    __shared__ __align__(16) unsigned short P_s[4][16][136];
    __shared__ unsigned short rp_s[KL_][72];
    __shared__ unsigned int msk_s[64][5];
    __shared__ float de_h[NDIS_];
    __shared__ float pe[PB_];
    __shared__ int mo_s[KL_];

    const size_t bh = (size_t)(b * H_ + h);
    if (tid < NDIS_) de_h[tid] = dis_embed[tid * H_ + h];
    if (tid < PB_) pe[tid] = polar_emb[tid];
    if (tid < KL_) mo_s[tid] = main_ori[bh * KL_ + tid];
    {
        int xr = tid >> 2, kg = tid & 3;
        msk_s[xr][kg] = mbits[(bh * XL_ + x0 + xr) * 4 + kg];
    }
    __syncthreads();

#pragma unroll
    for (int i = 0; i < 8; ++i) {
        int id = tid + 256 * i;          // 2048 chunks of 4 u16
        int k = id >> 4, ch = id & 15;
        uint2 v = *(const uint2*)&rp16[((size_t)(b * KL_ + k)) * XL_ + x0 + ch * 4];
        int mo = mo_s[k];
        const unsigned short* pv = (const unsigned short*)&v;
        unsigned short outv[4];
#pragma unroll
        for (int j = 0; j < 4; ++j) {
            int np = (((pv[j] >> 8) & 7) - mo) & 7;
            outv[j] = (unsigned short)((pv[j] & 0x7F) | (np << 8));
        }
        *(uint2*)&rp_s[k][ch * 4] = *(uint2*)&outv[0];
    }
    __syncthreads();

    v8s aq = *(const v8s*)&qxh[(size_t)(b * XL_ + x0 + wave * 16 + c) * DIM_ + h * HD_ + q * 8];

    const unsigned short* KkB = &Kk_bf[(size_t)bh * KL_ * HD_];
    v4f S[8];
#pragma unroll
    for (int t = 0; t < 8; ++t) {
        v8s bk = *(const v8s*)&KkB[(size_t)(t * 16 + c) * HD_ + q * 8];
        S[t] = __builtin_amdgcn_mfma_f32_16x16x32_bf16(aq, bk, (v4f){0.f, 0.f, 0.f, 0.f}, 0, 0, 0);
    }

    const int xloc = wave * 16;
    float lr[4] = {0.f, 0.f, 0.f, 0.f};
#pragma unroll
    for (int t = 0; t < 8; ++t) {
#pragma unroll
        for (int r = 0; r < 4; ++r) {
            int krow = t * 16 + c;
            int xrow = q * 4 + r;
            unsigned short rp = rp_s[krow][xloc + xrow];
            int mbit = (msk_s[xloc + xrow][krow >> 5] >> (krow & 31)) & 1;
            float sval = S[t][r] * SCALE_;
            float tval = (mbit ? -25.0f : sval) + de_h[rp & 0x7f] + pe[(rp >> 8) & 7];
            float p = __expf(tval);
            unsigned short pb = f2bf(p);
            P_s[wave][xrow][krow] = pb;
            lr[r] += bf2f(pb);
        }
    }
#pragma unroll
    for (int r = 0; r < 4; ++r) {
#pragma unroll
        for (int m = 1; m < 16; m <<= 1) lr[r] += __shfl_xor(lr[r], m);
    }
    __syncthreads();

    const unsigned short* VTB = &VT_bf[(size_t)bh * HD_ * KL_];
    v4f O0 = {0.f, 0.f, 0.f, 0.f}, O1 = {0.f, 0.f, 0.f, 0.f};
#pragma unroll
    for (int kc = 0; kc < 4; ++kc) {
        v8s ap = *(v8s*)&P_s[wave][c][kc * 32 + q * 8];
        v8s bv0 = *(const v8s*)&VTB[(size_t)c * KL_ + kc * 32 + q * 8];
        v8s bv1 = *(const v8s*)&VTB[(size_t)(16 + c) * KL_ + kc * 32 + q * 8];
        O0 = __builtin_amdgcn_mfma_f32_16x16x32_bf16(ap, bv0, O0, 0, 0, 0);
        O1 = __builtin_amdgcn_mfma_f32_16x16x32_bf16(ap, bv1, O1, 0, 0, 0);
    }

#pragma unroll
    for (int r = 0; r < 4; ++r) {
        int xg = x0 + wave * 16 + q * 4 + r;
        float inv = 1.0f / lr[r];
        size_t obase = (size_t)(b * XL_ + xg) * DIM_ + h * HD_;
        float v0 = O0[r] * inv;
        float v1 = O1[r] * inv;
        unsigned short h0, l0, h1, l1;
        cvt_hilo(v0, h0, l0);
        cvt_hilo(v1, h1, l1);
        oh[obase + c] = h0;
        ol[obase + c] = l0;
        oh[obase + 16 + c] = h1;
        ol[obase + 16 + c] = l1;
    }
}

// ---------------------------------------------------------------------------
extern "C" void kernel_launch(void* const* d_in, const int* in_sizes, int n_in,
                              void* d_out, int out_size, void* d_ws, size_t ws_size,
                              hipStream_t stream) {
    const float* x         = (const float*)d_in[0];
    const float* kernal    = (const float*)d_in[1];
    const int* rd          = (const int*)d_in[2];
    const int* polar_pos   = (const int*)d_in[3];
    const int* att_mask    = (const int*)d_in[4];
    const float* W_qkv     = (const float*)d_in[5];
    const float* dis_embed = (const float*)d_in[6];
    const float* polar_emb = (const float*)d_in[7];
    const float* W_proj    = (const float*)d_in[8];
    const float* b_proj    = (const float*)d_in[9];
    float* out             = (float*)d_out;

    char* base = (char*)d_ws;
    size_t off = 0;
    auto alloc = [&](size_t bytes) { void* p = base + off; off = (off + bytes + 255) & ~255ULL; return p; };
    const size_t MX = (size_t)B_ * XL_;

    unsigned short* VTx = (unsigned short*)alloc((size_t)B_ * H_ * HD_ * XL_ * 2);
    unsigned short* qxh = (unsigned short*)alloc(MX * DIM_ * 2);
    unsigned short* kxh = (unsigned short*)alloc(MX * DIM_ * 2);
    unsigned short* kxl = (unsigned short*)alloc(MX * DIM_ * 2);
    float* binspart  = (float*)alloc((size_t)B_ * H_ * KL_ * NCH2_ * PB_ * 4);
    float* kout_pre  = (float*)alloc((size_t)B_ * KL_ * DIM_ * 4);
    int* main_ori    = (int*)alloc(B_ * H_ * KL_ * 4);
    float* part      = (float*)alloc((size_t)B_ * H_ * KL_ * NS2_ * 36 * 4);
    __hip_bfloat16* Sg = (__hip_bfloat16*)alloc((size_t)B_ * H_ * KL_ * XL_ * 2);
    unsigned short* wph = (unsigned short*)alloc((size_t)DIM_ * DIM_ * 2);
    unsigned short* wpl = (unsigned short*)alloc((size_t)DIM_ * DIM_ * 2);
    unsigned short* wqh = (unsigned short*)alloc((size_t)TDIM_ * DIM_ * 2);
    unsigned short* wql = (unsigned short*)alloc((size_t)TDIM_ * DIM_ * 2);
    unsigned int* mbits = (unsigned int*)alloc((size_t)B_ * H_ * XL_ * (KL_ / 32) * 4);
    unsigned int* pp4   = (unsigned int*)alloc((size_t)B_ * KL_ * (XL_ / 8) * 4);
    unsigned short* rp16 = (unsigned short*)alloc((size_t)B_ * KL_ * XL_ * 2);
    unsigned short* Kqh_g = (unsigned short*)alloc((size_t)B_ * H_ * KL_ * HD_ * 2);
    unsigned short* Kql_g = (unsigned short*)alloc((size_t)B_ * H_ * KL_ * HD_ * 2);
    unsigned short* Kk_bf = (unsigned short*)alloc((size_t)B_ * H_ * KL_ * HD_ * 2);
    unsigned short* VT_bf = (unsigned short*)alloc((size_t)B_ * H_ * HD_ * KL_ * 2);

    // oh/ol alias into Sg region (written by attn_x after flash consumed Sg)
    unsigned short* oh = (unsigned short*)Sg;
    unsigned short* ol = oh + MX * DIM_;

    // --- fused preamble (1 launch; x conversion inside gemm_qkv) ---
    preamble<<<dim3(NB_PACK_ + NB_WQ_ + NB_WP_ + NB_PP_), 256, 0, stream>>>(
        att_mask, W_qkv, W_proj, polar_pos, rd, mbits, wqh, wql, wph, wpl, pp4, rp16);

    // --- qkv projections (BM=64: 1536 blocks = 6/CU) ---
    gemm_qkv<<<dim3((TDIM_ / 128) * (MX / 64)), 256, 0, stream>>>(
        x, wqh, wql, MX, TDIM_, DIM_, qxh, kxh, kxl, VTx);
    gemm64_qkv<<<dim3(TDIM_ / 64, (B_ * KL_) / 64), 256, 0, stream>>>(
        kernal, W_qkv, Kqh_g, Kql_g, Kk_bf, VT_bf, B_ * KL_, TDIM_, DIM_);

    // --- k-direction ---
    score_bins_mfma4<<<dim3(NCH2_, H_, B_), 256, 0, stream>>>(
        kxh, kxl, Kqh_g, Kql_g, rp16, mbits, dis_embed, Sg, binspart);
    bins_argmax<<<dim3(B_ * H_ * KL_ / 4), 256, 0, stream>>>(binspart, main_ori);
    flash_mfma<<<dim3(NS2_, H_, B_), 256, 0, stream>>>(
        Sg, pp4, VTx, polar_emb, main_ori, part);
    merge_cached<<<dim3(B_ * H_ * KL_ / 8), 256, 0, stream>>>(part, kout_pre);

    // --- x-direction ---
    attn_x_mfma<<<dim3(XL_ / 64, H_, B_), 256, 0, stream>>>(
        qxh, Kk_bf, VT_bf, rp16, mbits, dis_embed, polar_emb, main_ori, oh, ol);

    // --- output projections (BM=64: 512 blocks = 2/CU) ---
    gemm_out<<<dim3((DIM_ / 128) * (MX / 64)), 256, 0, stream>>>(
        oh, ol, wph, wpl, out, b_proj, MX, DIM_, DIM_);
    gemm64<<<dim3(DIM_ / 64, (B_ * KL_) / 64), 256, 0, stream>>>(
        kout_pre, W_proj, out + (size_t)B_ * XL_ * DIM_, b_proj, B_ * KL_, DIM_, DIM_);
}

// Round 15
// 305.749 us; speedup vs baseline: 1.0252x; 1.0004x over previous
//
#include <hip/hip_runtime.h>
#include <hip/hip_bf16.h>

#define B_    4
#define KL_   128
#define XL_   4096
#define DIM_  256
#define H_    8
#define HD_   32
#define PB_   8
#define NDIS_ 66
#define TDIM_ 768
#define SCALE_ 0.17677669529663687f
#define NCH2_ 64
#define NS2_  32               // flash x-chunks
#define XC2_  (XL_ / NS2_)     // 128 x per chunk
#define SC_PITCH_ 68           // 272B rows: 16B-aligned float4 reads, 2-way banks

// preamble grid partition
#define NB_PACK_ 2048
#define NB_WQ_   768
#define NB_WP_   256
#define NB_PP_   1024

typedef float v4f __attribute__((ext_vector_type(4)));
typedef short v8s __attribute__((ext_vector_type(8)));

__device__ __forceinline__ unsigned short f2bf(float f) {
    __hip_bfloat16 h = __float2bfloat16(f);
    return __builtin_bit_cast(unsigned short, h);
}
__device__ __forceinline__ float bf2f(unsigned short u) {
    return __bfloat162float(__builtin_bit_cast(__hip_bfloat16, u));
}
__device__ __forceinline__ void cvt_hilo(float v, unsigned short& hi, unsigned short& lo) {
    hi = f2bf(v);
    lo = f2bf(v - bf2f(hi));
}

// ---------------------------------------------------------------------------
// preamble: pack_mask (ballot) + cvt_wT(W_qkv/W_proj) + {pp4 + rp16}
// ---------------------------------------------------------------------------
__global__ __launch_bounds__(256) void preamble(const int* __restrict__ att_mask,
                                                const float* __restrict__ W_qkv,
                                                const float* __restrict__ W_proj,
                                                const int* __restrict__ polar_pos,
                                                const int* __restrict__ rd,
                                                unsigned int* __restrict__ mbits,
                                                unsigned short* __restrict__ wqh,
                                                unsigned short* __restrict__ wql,
                                                unsigned short* __restrict__ wph,
                                                unsigned short* __restrict__ wpl,
                                                unsigned int* __restrict__ pp4,
                                                unsigned short* __restrict__ rp16) {
    const int bid = blockIdx.x, tid = threadIdx.x;
    if (bid < NB_PACK_) {
        const int w = tid >> 6, lane = tid & 63;
        const size_t ibase = (((size_t)bid * 4 + w) * 32) * 64;
#pragma unroll
        for (int u = 0; u < 4; ++u) {
            int vals[8];
#pragma unroll
            for (int i = 0; i < 8; ++i)
                vals[i] = att_mask[ibase + (size_t)(u * 8 + i) * 64 + lane];
            unsigned long long bm0 = __ballot(vals[0] != 0);
            unsigned long long bm1 = __ballot(vals[1] != 0);
            unsigned long long bm2 = __ballot(vals[2] != 0);
            unsigned long long bm3 = __ballot(vals[3] != 0);
            unsigned long long bm4 = __ballot(vals[4] != 0);
            unsigned long long bm5 = __ballot(vals[5] != 0);
            unsigned long long bm6 = __ballot(vals[6] != 0);
            unsigned long long bm7 = __ballot(vals[7] != 0);
            if (lane == 0) {
                size_t wb = ibase / 32 + (size_t)u * 16;
                *(uint2*)&mbits[wb + 0]  = make_uint2((unsigned)bm0, (unsigned)(bm0 >> 32));
                *(uint2*)&mbits[wb + 2]  = make_uint2((unsigned)bm1, (unsigned)(bm1 >> 32));
                *(uint2*)&mbits[wb + 4]  = make_uint2((unsigned)bm2, (unsigned)(bm2 >> 32));
                *(uint2*)&mbits[wb + 6]  = make_uint2((unsigned)bm3, (unsigned)(bm3 >> 32));
                *(uint2*)&mbits[wb + 8]  = make_uint2((unsigned)bm4, (unsigned)(bm4 >> 32));
                *(uint2*)&mbits[wb + 10] = make_uint2((unsigned)bm5, (unsigned)(bm5 >> 32));
                *(uint2*)&mbits[wb + 12] = make_uint2((unsigned)bm6, (unsigned)(bm6 >> 32));
                *(uint2*)&mbits[wb + 14] = make_uint2((unsigned)bm7, (unsigned)(bm7 >> 32));
            }
        }
    } else if (bid < NB_PACK_ + NB_WQ_) {
        int n = bid - NB_PACK_, k = tid;
        float v = W_qkv[(size_t)k * TDIM_ + n];
        unsigned short h, l;
        cvt_hilo(v, h, l);
        wqh[(size_t)n * DIM_ + k] = h;
        wql[(size_t)n * DIM_ + k] = l;
    } else if (bid < NB_PACK_ + NB_WQ_ + NB_WP_) {
        int n = bid - (NB_PACK_ + NB_WQ_), k = tid;
        float v = W_proj[(size_t)k * DIM_ + n];
        unsigned short h, l;
        cvt_hilo(v, h, l);
        wph[(size_t)n * DIM_ + k] = h;
        wpl[(size_t)n * DIM_ + k] = l;
    } else {
        size_t wid = (size_t)(bid - (NB_PACK_ + NB_WQ_ + NB_WP_)) * 256 + tid;
        const int* srcp = &polar_pos[wid * 8];
        const int* srcr = &rd[wid * 8];
        int4 a = *(const int4*)&srcp[0];
        int4 b4 = *(const int4*)&srcp[4];
        int4 ra = *(const int4*)&srcr[0];
        int4 rb = *(const int4*)&srcr[4];
        unsigned pk = (unsigned)(a.x & 7) | ((unsigned)(a.y & 7) << 4) |
                      ((unsigned)(a.z & 7) << 8) | ((unsigned)(a.w & 7) << 12) |
                      ((unsigned)(b4.x & 7) << 16) | ((unsigned)(b4.y & 7) << 20) |
                      ((unsigned)(b4.z & 7) << 24) | ((unsigned)(b4.w & 7) << 28);
        pp4[wid] = pk;
        unsigned short rp[8];
        rp[0] = (unsigned short)(ra.x | ((a.x & 7) << 8));
        rp[1] = (unsigned short)(ra.y | ((a.y & 7) << 8));
        rp[2] = (unsigned short)(ra.z | ((a.z & 7) << 8));
        rp[3] = (unsigned short)(ra.w | ((a.w & 7) << 8));
        rp[4] = (unsigned short)(rb.x | ((b4.x & 7) << 8));
        rp[5] = (unsigned short)(rb.y | ((b4.y & 7) << 8));
        rp[6] = (unsigned short)(rb.z | ((b4.z & 7) << 8));
        rp[7] = (unsigned short)(rb.w | ((b4.w & 7) << 8));
        *(uint4*)&rp16[wid * 8] = *(uint4*)&rp[0];
    }
}

// ---------------------------------------------------------------------------
// gemm_out v2: BM=64, bf16 tiles unit-swizzled, XCD-swizzled linear grid.
// ---------------------------------------------------------------------------
__global__ __launch_bounds__(256) void gemm_out(const unsigned short* __restrict__ Ah,
                                                const unsigned short* __restrict__ Al,
                                                const unsigned short* __restrict__ Bh,
                                                const unsigned short* __restrict__ Bl,
                                                float* __restrict__ C,
                                                const float* __restrict__ bias,
                                                int M, int N, int K) {
    __shared__ __align__(16) unsigned short Ah_s[64 * 32];
    __shared__ __align__(16) unsigned short Al_s[64 * 32];
    __shared__ __align__(16) unsigned short Bh_s[128 * 32];
    __shared__ __align__(16) unsigned short Bl_s[128 * 32];
    const int tid = threadIdx.x;
    const int w = tid >> 6, lane = tid & 63;
    const int c = lane & 15, q = lane >> 4;

    const int NBX = N >> 7;
    const int id = blockIdx.x;
    const int xcd = id & 7, grp = id >> 3;
    const int bm = ((grp / NBX) * 8 + xcd) * 64;
    const int bn = (grp % NBX) * 128;

    const int lrow = lane >> 2;
    const int lcol = (((lane & 3) ^ ((lane >> 2) & 3)) * 8);

    v4f acc[8] = {};
    for (int k0 = 0; k0 < K; k0 += 32) {
        __syncthreads();
        {
            const int row = w * 16 + lrow;
            const size_t ga = (size_t)(bm + row) * K + k0 + lcol;
            __builtin_amdgcn_global_load_lds(
                (const __attribute__((address_space(1))) unsigned int*)&Ah[ga],
                (__attribute__((address_space(3))) unsigned int*)&Ah_s[w * 512], 16, 0, 0);
            __builtin_amdgcn_global_load_lds(
                (const __attribute__((address_space(1))) unsigned int*)&Al[ga],
                (__attribute__((address_space(3))) unsigned int*)&Al_s[w * 512], 16, 0, 0);
        }
#pragma unroll
        for (int i = 0; i < 2; ++i) {
            const int chunk = w * 2 + i;
            const int row = chunk * 16 + lrow;
            const size_t gb = (size_t)(bn + row) * K + k0 + lcol;
            __builtin_amdgcn_global_load_lds(
                (const __attribute__((address_space(1))) unsigned int*)&Bh[gb],
                (__attribute__((address_space(3))) unsigned int*)&Bh_s[chunk * 512], 16, 0, 0);
            __builtin_amdgcn_global_load_lds(
                (const __attribute__((address_space(1))) unsigned int*)&Bl[gb],
                (__attribute__((address_space(3))) unsigned int*)&Bl_s[chunk * 512], 16, 0, 0);
        }
        asm volatile("s_waitcnt vmcnt(0)" ::: "memory");
        __syncthreads();
        const int uA = (q ^ (c & 3)) * 8;
        v8s afh = *(v8s*)&Ah_s[(w * 16 + c) * 32 + uA];
        v8s afl = *(v8s*)&Al_s[(w * 16 + c) * 32 + uA];
#pragma unroll
        for (int nt = 0; nt < 8; ++nt) {
            v8s bfh = *(v8s*)&Bh_s[(nt * 16 + c) * 32 + uA];
            v8s bfl = *(v8s*)&Bl_s[(nt * 16 + c) * 32 + uA];
            acc[nt] = __builtin_amdgcn_mfma_f32_16x16x32_bf16(afl, bfh, acc[nt], 0, 0, 0);
            acc[nt] = __builtin_amdgcn_mfma_f32_16x16x32_bf16(afh, bfl, acc[nt], 0, 0, 0);
            acc[nt] = __builtin_amdgcn_mfma_f32_16x16x32_bf16(afh, bfh, acc[nt], 0, 0, 0);
        }
    }
#pragma unroll
    for (int nt = 0; nt < 8; ++nt) {
        int col = bn + nt * 16 + c;
        float bv = bias ? bias[col] : 0.0f;
#pragma unroll
        for (int r = 0; r < 4; ++r) {
            int row = bm + w * 16 + q * 4 + r;
            C[(size_t)row * N + col] = acc[nt][r] + bv;
        }
    }
}

// ---------------------------------------------------------------------------
// gemm_qkv v5: BM=64, LDS 24KB. A staged f32 with 8-unit XOR swizzle; q/k
// epilogue scratch pitch 68 (16B-aligned rows -> float4 ds_read_b128, 2-way).
// ---------------------------------------------------------------------------
__global__ __launch_bounds__(256) void gemm_qkv(const float* __restrict__ X,
                                                const unsigned short* __restrict__ Bh,
                                                const unsigned short* __restrict__ Bl,
                                                int M, int N, int K,
                                                unsigned short* __restrict__ qh,
                                                unsigned short* __restrict__ kh,
                                                unsigned short* __restrict__ kl2,
                                                unsigned short* __restrict__ VTx) {
    __shared__ __align__(16) char SMEM[24576];
    float* Ax_s = (float*)SMEM;                               // 64x32 f32 = 8KB
    unsigned short* Bh_s = (unsigned short*)(SMEM + 8192);    // 8KB
    unsigned short* Bl_s = (unsigned short*)(SMEM + 16384);   // 8KB
    float* scratch = (float*)SMEM;                            // 64x68 f32 = 17.4KB

    const int tid = threadIdx.x;
    const int w = tid >> 6, lane = tid & 63;
    const int c = lane & 15, q = lane >> 4;

    const int NBX = N >> 7;
    const int id = blockIdx.x;
    const int xcd = id & 7, grp = id >> 3;
    const int bm = ((grp / NBX) * 8 + xcd) * 64;
    const int bn = (grp % NBX) * 128;

    const int arow = lane >> 3;
    const int acol = (((lane & 7) ^ (lane >> 3)) * 4);
    const int lrow = lane >> 2;
    const int lcol = (((lane & 3) ^ ((lane >> 2) & 3)) * 8);

    v4f acc[8] = {};
    for (int k0 = 0; k0 < K; k0 += 32) {
        __syncthreads();
#pragma unroll
        for (int i = 0; i < 2; ++i) {
            const int chunk = w * 2 + i;
            const int row = chunk * 8 + arow;
            const size_t ga = (size_t)(bm + row) * K + k0 + acol;
            __builtin_amdgcn_global_load_lds(
                (const __attribute__((address_space(1))) unsigned int*)&X[ga],
                (__attribute__((address_space(3))) unsigned int*)&Ax_s[chunk * 256], 16, 0, 0);
        }
#pragma unroll
        for (int i = 0; i < 2; ++i) {
            const int chunk = w * 2 + i;
            const int row = chunk * 16 + lrow;
            const size_t gb = (size_t)(bn + row) * K + k0 + lcol;
            __builtin_amdgcn_global_load_lds(
                (const __attribute__((address_space(1))) unsigned int*)&Bh[gb],
                (__attribute__((address_space(3))) unsigned int*)&Bh_s[chunk * 512], 16, 0, 0);
            __builtin_amdgcn_global_load_lds(
                (const __attribute__((address_space(1))) unsigned int*)&Bl[gb],
                (__attribute__((address_space(3))) unsigned int*)&Bl_s[chunk * 512], 16, 0, 0);
        }
        asm volatile("s_waitcnt vmcnt(0)" ::: "memory");
        __syncthreads();
        const int r7 = c & 7;
        const int uB = (q ^ (c & 3)) * 8;
        v8s afh, afl;
        {
            const float* sA = &Ax_s[(w * 16 + c) * 32];
            float4 f0 = *(const float4*)&sA[((2 * q) ^ r7) * 4];
            float4 f1 = *(const float4*)&sA[((2 * q + 1) ^ r7) * 4];
            float vv[8] = {f0.x, f0.y, f0.z, f0.w, f1.x, f1.y, f1.z, f1.w};
#pragma unroll
            for (int j = 0; j < 8; ++j) {
                unsigned short hi, lo;
                cvt_hilo(vv[j], hi, lo);
                ((short*)&afh)[j] = (short)hi;
                ((short*)&afl)[j] = (short)lo;
            }
        }
#pragma unroll
        for (int nt = 0; nt < 8; ++nt) {
            v8s bfh = *(v8s*)&Bh_s[(nt * 16 + c) * 32 + uB];
            v8s bfl = *(v8s*)&Bl_s[(nt * 16 + c) * 32 + uB];
            acc[nt] = __builtin_amdgcn_mfma_f32_16x16x32_bf16(afl, bfh, acc[nt], 0, 0, 0);
            acc[nt] = __builtin_amdgcn_mfma_f32_16x16x32_bf16(afh, bfl, acc[nt], 0, 0, 0);
            acc[nt] = __builtin_amdgcn_mfma_f32_16x16x32_bf16(afh, bfh, acc[nt], 0, 0, 0);
        }
    }
    if (bn >= 2 * DIM_) {
#pragma unroll
        for (int nt = 0; nt < 8; ++nt) {
            int nn = bn + nt * 16 + c - 2 * DIM_;
            int h = nn >> 5, d = nn & 31;
            int row0 = bm + w * 16 + q * 4;
            int b = row0 >> 12, x = row0 & (XL_ - 1);
            unsigned short t4[4];
#pragma unroll
            for (int r = 0; r < 4; ++r) t4[r] = f2bf(acc[nt][r]);
            *(ushort4*)&VTx[((size_t)(b * H_ + h) * HD_ + d) * XL_ + x] = *(ushort4*)&t4[0];
        }
    } else {
        for (int half = 0; half < 2; ++half) {
            __syncthreads();
#pragma unroll
            for (int nt = 0; nt < 4; ++nt) {
                int nt_g = half * 4 + nt;
#pragma unroll
                for (int r = 0; r < 4; ++r)
                    scratch[(w * 16 + q * 4 + r) * SC_PITCH_ + nt * 16 + c] = acc[nt_g][r];
            }
            __syncthreads();
            const int row = tid & 63, colseg = (tid >> 6) * 16;
            const int grow = bm + row;
            const float* src = &scratch[row * SC_PITCH_ + colseg];
            float4 f0 = *(const float4*)&src[0];
            float4 f1 = *(const float4*)&src[4];
            float4 f2 = *(const float4*)&src[8];
            float4 f3 = *(const float4*)&src[12];
            float vv[16] = {f0.x, f0.y, f0.z, f0.w, f1.x, f1.y, f1.z, f1.w,
                            f2.x, f2.y, f2.z, f2.w, f3.x, f3.y, f3.z, f3.w};
            if (bn < DIM_) {
                unsigned short* dst = &qh[(size_t)grow * DIM_ + bn + half * 64 + colseg];
#pragma unroll
                for (int j8 = 0; j8 < 2; ++j8) {
                    unsigned short tmp[8];
#pragma unroll
                    for (int j = 0; j < 8; ++j) tmp[j] = f2bf(vv[j8 * 8 + j]);
                    *(uint4*)&dst[j8 * 8] = *(uint4*)&tmp[0];
                }
            } else {
                const size_t o = (size_t)grow * DIM_ + bn - DIM_ + half * 64 + colseg;
#pragma unroll
                for (int j8 = 0; j8 < 2; ++j8) {
                    unsigned short th[8], tl[8];
#pragma unroll
                    for (int j = 0; j < 8; ++j) cvt_hilo(vv[j8 * 8 + j], th[j], tl[j]);
                    *(uint4*)&kh[o + j8 * 8] = *(uint4*)&th[0];
                    *(uint4*)&kl2[o + j8 * 8] = *(uint4*)&tl[0];
                }
            }
        }
    }
}

// ---------------------------------------------------------------------------
// 64x64 f32 GEMM (small-M) — proj path
// ---------------------------------------------------------------------------
__global__ __launch_bounds__(256) void gemm64(const float* __restrict__ A,
                                              const float* __restrict__ Bw,
                                              float* __restrict__ C,
                                              const float* __restrict__ bias,
                                              int M, int N, int K) {
    __shared__ __align__(16) float As[16][68];
    __shared__ __align__(16) float Bs[16][64];
    const int tid = threadIdx.x;
    const int tx = tid & 15, ty = tid >> 4;
    const int bn = blockIdx.x * 64, bm = blockIdx.y * 64;
    const int am = tid >> 2, ac = tid & 3;
    float acc[4][4] = {};
    for (int k0 = 0; k0 < K; k0 += 16) {
        float4 a4 = *(const float4*)&A[(size_t)(bm + am) * K + k0 + ac * 4];
        As[ac * 4 + 0][am] = a4.x;
        As[ac * 4 + 1][am] = a4.y;
        As[ac * 4 + 2][am] = a4.z;
        As[ac * 4 + 3][am] = a4.w;
        *(float4*)&Bs[ty][tx * 4] = *(const float4*)&Bw[(size_t)(k0 + ty) * N + bn + tx * 4];
        __syncthreads();
#pragma unroll
        for (int kk = 0; kk < 16; ++kk) {
            float4 av = *(const float4*)&As[kk][ty * 4];
            float4 bv = *(const float4*)&Bs[kk][tx * 4];
            float a[4] = {av.x, av.y, av.z, av.w};
            float b[4] = {bv.x, bv.y, bv.z, bv.w};
#pragma unroll
            for (int i = 0; i < 4; ++i)
#pragma unroll
                for (int j = 0; j < 4; ++j) acc[i][j] += a[i] * b[j];
        }
        __syncthreads();
    }
#pragma unroll
    for (int i = 0; i < 4; ++i) {
        int m = bm + ty * 4 + i;
#pragma unroll
        for (int j = 0; j < 4; ++j) {
            int n = bn + tx * 4 + j;
            float v = acc[i][j];
            if (bias) v += bias[n];
            C[(size_t)m * N + n] = v;
        }
    }
}

// ---------------------------------------------------------------------------
// gemm64_qkv: kernal @ W_qkv with typed epilogue (unchanged)
// ---------------------------------------------------------------------------
__global__ __launch_bounds__(256) void gemm64_qkv(const float* __restrict__ A,
                                                  const float* __restrict__ Bw,
                                                  unsigned short* __restrict__ Kqh,
                                                  unsigned short* __restrict__ Kql,
                                                  unsigned short* __restrict__ Kk_bf,
                                                  unsigned short* __restrict__ VT_bf,
                                                  int M, int N, int K) {
    __shared__ __align__(16) float As[16][68];
    __shared__ __align__(16) float Bs[16][64];
    const int tid = threadIdx.x;
    const int tx = tid & 15, ty = tid >> 4;
    const int bn = blockIdx.x * 64, bm = blockIdx.y * 64;
    const int am = tid >> 2, ac = tid & 3;
    float acc[4][4] = {};
    for (int k0 = 0; k0 < K; k0 += 16) {
        float4 a4 = *(const float4*)&A[(size_t)(bm + am) * K + k0 + ac * 4];
        As[ac * 4 + 0][am] = a4.x;
        As[ac * 4 + 1][am] = a4.y;
        As[ac * 4 + 2][am] = a4.z;
        As[ac * 4 + 3][am] = a4.w;
        *(float4*)&Bs[ty][tx * 4] = *(const float4*)&Bw[(size_t)(k0 + ty) * N + bn + tx * 4];
        __syncthreads();
#pragma unroll
        for (int kk = 0; kk < 16; ++kk) {
            float4 av = *(const float4*)&As[kk][ty * 4];
            float4 bv = *(const float4*)&Bs[kk][tx * 4];
            float a[4] = {av.x, av.y, av.z, av.w};
            float b[4] = {bv.x, bv.y, bv.z, bv.w};
#pragma unroll
            for (int i = 0; i < 4; ++i)
#pragma unroll
                for (int j = 0; j < 4; ++j) acc[i][j] += a[i] * b[j];
        }
        __syncthreads();
    }
#pragma unroll
    for (int i = 0; i < 4; ++i) {
        int m = bm + ty * 4 + i;
        int b = m >> 7, k = m & 127;
#pragma unroll
        for (int j = 0; j < 4; ++j) {
            int n = bn + tx * 4 + j;
            float v = acc[i][j];
            if (n < DIM_) {
                unsigned short hi, lo;
                cvt_hilo(v, hi, lo);
                int h = n >> 5, d = n & 31;
                size_t o = ((size_t)(b * H_ + h) * KL_ + k) * HD_ + d;
                Kqh[o] = hi;
                Kql[o] = lo;
            } else if (n < 2 * DIM_) {
                int nn = n - DIM_, h = nn >> 5, d = nn & 31;
                Kk_bf[((size_t)(b * H_ + h) * KL_ + k) * HD_ + d] = f2bf(v);
            } else {
                int nn = n - 2 * DIM_, h = nn >> 5, d = nn & 31;
                VT_bf[((size_t)(b * H_ + h) * HD_ + d) * KL_ + k] = f2bf(v);
            }
        }
    }
}

// ===========================================================================
// K1 v11: rp16 packed rd|polar loads (unchanged)
// ===========================================================================
__global__ __launch_bounds__(256) void score_bins_mfma4(const unsigned short* __restrict__ kxh,
                                                        const unsigned short* __restrict__ kxl,
                                                        const unsigned short* __restrict__ Kqh_g,
                                                        const unsigned short* __restrict__ Kql_g,
                                                        const unsigned short* __restrict__ rp16,
                                                        const unsigned int* __restrict__ mbits,
                                                        const float* __restrict__ dis_embed,
                                                        __hip_bfloat16* __restrict__ Sg,
                                                        float* __restrict__ binspart) {
    const int b = blockIdx.z, h = blockIdx.y, xc = blockIdx.x;
    const int x0 = xc * 64;
    const int tid = threadIdx.x;
    const int w = tid >> 6, lane = tid & 63;
    const int c15 = lane & 15, q = lane >> 4;
    const size_t bh = (size_t)(b * H_ + h);

    __shared__ unsigned int mskb[64][5];
    __shared__ float de_h[NDIS_];
    __shared__ float binsL[8][4][16][PB_ + 1];
    __shared__ __align__(16) unsigned short Ss[2][16][72];

    {
        int xr = tid >> 2, kg = tid & 3;
        mskb[xr][kg] = mbits[(bh * XL_ + x0 + xr) * 4 + kg];
    }
    if (tid < NDIS_) de_h[tid] = dis_embed[tid * H_ + h];
    __syncthreads();

    v8s axh, axl;
    {
        const size_t aoff = ((size_t)b * XL_ + x0 + w * 16 + c15) * DIM_ + h * HD_ + q * 8;
        axh = *(const v8s*)&kxh[aoff];
        axl = *(const v8s*)&kxl[aoff];
    }

    v8s bqh[2], bql[2];
    uint2 rp2[2];
    auto load_nt = [&](int nt, int s) {
        const int k = nt * 16 + c15;
        const size_t kqoff = (bh * KL_ + k) * HD_ + q * 8;
        bqh[s] = *(const v8s*)&Kqh_g[kqoff];
        bql[s] = *(const v8s*)&Kql_g[kqoff];
        const size_t rowoff = ((size_t)(b * KL_ + k)) * XL_ + x0 + w * 16 + q * 4;
        rp2[s] = *(const uint2*)&rp16[rowoff];
    };
    load_nt(0, 0);

#pragma unroll
    for (int nt = 0; nt < 8; ++nt) {
        const int s = nt & 1;
        if (nt < 7) load_nt(nt + 1, s ^ 1);

        const int k = nt * 16 + c15;
        v4f D = {0.f, 0.f, 0.f, 0.f};
        D = __builtin_amdgcn_mfma_f32_16x16x32_bf16(axl, bqh[s], D, 0, 0, 0);
        D = __builtin_amdgcn_mfma_f32_16x16x32_bf16(axh, bql[s], D, 0, 0, 0);
        D = __builtin_amdgcn_mfma_f32_16x16x32_bf16(axh, bqh[s], D, 0, 0, 0);

        float bins[PB_] = {};
        {
            const unsigned short* rpv = (const unsigned short*)&rp2[s];
            ushort4 pack;
#pragma unroll
            for (int r = 0; r < 4; ++r) {
                float sc = D[r] * SCALE_;
                float a = fabsf(sc);
                int pv = (rpv[r] >> 8) & 7;
#pragma unroll
                for (int pb = 0; pb < PB_; ++pb) bins[pb] += (pv == pb) ? a : 0.0f;
                int xloc = w * 16 + q * 4 + r;
                int mbit = (mskb[xloc][k >> 5] >> (k & 31)) & 1;
                float sp = (mbit ? -1e6f : sc) + de_h[rpv[r] & 0x7F];
                ((unsigned short*)&pack)[r] = f2bf(sp);
            }
            *(ushort4*)&Ss[s][c15][w * 16 + q * 4] = pack;
        }

#pragma unroll
        for (int pb = 0; pb < PB_; ++pb) {
            bins[pb] += __shfl_xor(bins[pb], 16);
            bins[pb] += __shfl_xor(bins[pb], 32);
        }
        if (q == 0) {
#pragma unroll
            for (int pb = 0; pb < PB_; ++pb) binsL[nt][w][c15][pb] = bins[pb];
        }

        __syncthreads();
        {
            int row = tid >> 4, seg = tid & 15;
            unsigned short* dst = (unsigned short*)Sg +
                (bh * KL_ + nt * 16 + row) * XL_ + x0 + seg * 4;
            *(uint2*)dst = *(const uint2*)&Ss[s][row][seg * 4];
        }
    }
    __syncthreads();
    {
        int k = tid >> 1, half = tid & 1;
        int nt = k >> 4, c = k & 15;
        float4 s = {0.f, 0.f, 0.f, 0.f};
#pragma unroll
        for (int w4 = 0; w4 < 4; ++w4) {
            const float* bp = &binsL[nt][w4][c][half * 4];
            s.x += bp[0]; s.y += bp[1]; s.z += bp[2]; s.w += bp[3];
        }
        *(float4*)&binspart[(bh * KL_ + k) * (NCH2_ * PB_) + xc * PB_ + half * 4] = s;
    }
}

// K2: argmax (unchanged)
__global__ __launch_bounds__(256) void bins_argmax(const float* __restrict__ binspart,
                                                   int* __restrict__ main_ori) {
    const int w = threadIdx.x >> 6, lane = threadIdx.x & 63;
    const int row = blockIdx.x * 4 + w;
    float s[PB_];
#pragma unroll
    for (int pb = 0; pb < PB_; ++pb) s[pb] = 0.0f;
    if (lane < NCH2_) {
        const float* bp = &binspart[(size_t)row * (NCH2_ * PB_) + lane * PB_];
#pragma unroll
        for (int pb = 0; pb < PB_; ++pb) s[pb] = bp[pb];
    }
#pragma unroll
    for (int m = 1; m < 64; m <<= 1)
#pragma unroll
        for (int pb = 0; pb < PB_; ++pb) s[pb] += __shfl_xor(s[pb], m);
    if (lane == 0) {
        float best = s[0];
        int bi = 0;
#pragma unroll
        for (int pb = 1; pb < PB_; ++pb)
            if (s[pb] > best) { best = s[pb]; bi = pb; }
        main_ori[row] = bi;
    }
}

// ===========================================================================
// K3 v4: flash_mfma (unchanged)
// ===========================================================================
__global__ __launch_bounds__(256) void flash_mfma(const __hip_bfloat16* __restrict__ Sg,
                                                  const unsigned int* __restrict__ pp4,
                                                  const unsigned short* __restrict__ VTx,
                                                  const float* __restrict__ polar_emb,
                                                  const int* __restrict__ main_ori,
                                                  float* __restrict__ part) {
    const int b = blockIdx.z, h = blockIdx.y, xc = blockIdx.x;
    const int tid = threadIdx.x;
    const int w = tid >> 6, lane = tid & 63;
    const int c = lane & 15, q = lane >> 4;
    const size_t bh = (size_t)(b * H_ + h);
    const int xbeg = xc * XC2_;

    __shared__ int mo_s[KL_];
    __shared__ float pe_s[PB_];
    if (tid < KL_) mo_s[tid] = main_ori[bh * KL_ + tid];
    if (tid < PB_) pe_s[tid] = polar_emb[tid];
    __syncthreads();

    const int wk0 = w * 32;
    const int mo[2] = {mo_s[wk0 + c], mo_s[wk0 + 16 + c]};
    const unsigned short* SgU = (const unsigned short*)Sg;

    v4f acc[2][2] = {};
    float lsum[2] = {0.f, 0.f};

    for (int s = 0; s < XC2_ / 32; ++s) {
        const int xs = xbeg + s * 32;
        v8s pa[2];
#pragma unroll
        for (int kt = 0; kt < 2; ++kt) {
            const int k = wk0 + kt * 16 + c;
            v8s sv = *(const v8s*)&SgU[(bh * KL_ + k) * XL_ + xs + q * 8];
            unsigned pw = pp4[((size_t)(b * KL_ + k)) * (XL_ / 8) + (xs >> 3) + q];
            unsigned short pk[8];
#pragma unroll
            for (int j = 0; j < 8; ++j) {
                float sp = bf2f((unsigned short)sv[j]);
                int np = (((int)(pw >> (j * 4)) & 7) - mo[kt]) & 7;
                float p = __expf(sp + pe_s[np]);
                unsigned short pb = f2bf(p);
                pk[j] = pb;
                lsum[kt] += bf2f(pb);
            }
            pa[kt] = *(v8s*)pk;
        }
#pragma unroll
        for (int dt = 0; dt < 2; ++dt) {
            v8s bv = *(const v8s*)&VTx[((size_t)bh * HD_ + dt * 16 + c) * XL_ + xs + q * 8];
            acc[0][dt] = __builtin_amdgcn_mfma_f32_16x16x32_bf16(pa[0], bv, acc[0][dt], 0, 0, 0);
            acc[1][dt] = __builtin_amdgcn_mfma_f32_16x16x32_bf16(pa[1], bv, acc[1][dt], 0, 0, 0);
        }
    }

#pragma unroll
    for (int kt = 0; kt < 2; ++kt) {
        lsum[kt] += __shfl_xor(lsum[kt], 16);
        lsum[kt] += __shfl_xor(lsum[kt], 32);
    }
#pragma unroll
    for (int kt = 0; kt < 2; ++kt) {
#pragma unroll
        for (int dt = 0; dt < 2; ++dt) {
#pragma unroll
            for (int r = 0; r < 4; ++r) {
                int krow = wk0 + kt * 16 + q * 4 + r;
                part[((size_t)(bh * KL_ + krow) * NS2_ + xc) * 36 + dt * 16 + c] = acc[kt][dt][r];
            }
        }
        if (q == 0) {
            int krow = wk0 + kt * 16 + c;
            part[((size_t)(bh * KL_ + krow) * NS2_ + xc) * 36 + 32] = lsum[kt];
        }
    }
}

// K4: merge over NS2_ chunks
__global__ __launch_bounds__(256) void merge_cached(const float* __restrict__ part,
                                                    float* __restrict__ kout_pre) {
    const int tid = threadIdx.x;
    const int ri = tid >> 5, d = tid & 31;
    const int row = blockIdx.x * 8 + ri;
    float l = 0.f, a = 0.f;
#pragma unroll 4
    for (int c = 0; c < NS2_; ++c) {
        const float* p = &part[((size_t)row * NS2_ + c) * 36];
        l += p[32];
        a += p[d];
    }
    int k = row & (KL_ - 1);
    int bh = row >> 7;
    int h = bh & (H_ - 1), b = bh >> 3;
    kout_pre[(size_t)(b * KL_ + k) * DIM_ + h * HD_ + d] = a / l;
}

// ===========================================================================
// attn_x_mfma v5 (unchanged)
// ===========================================================================
__global__ __launch_bounds__(256) void attn_x_mfma(const unsigned short* __restrict__ qxh,
                                                   const unsigned short* __restrict__ Kk_bf,
                                                   const unsigned short* __restrict__ VT_bf,
                                                   const unsigned short* __restrict__ rp16,
                                                   const unsigned int* __restrict__ mbits,
                                                   const float* __restrict__ dis_embed,
                                                   const float* __restrict__ polar_emb,
                                                   const int* __restrict__ main_ori,
                                                   unsigned short* __restrict__ oh,
                                                   unsigned short* __restrict__ ol) {
    const int b = blockIdx.z, h = blockIdx.y;
    const int x0 = blockIdx.x * 64;
    const int tid = threadIdx.x;
    const int wave = tid >> 6, lane = tid & 63;
    const int c = lane & 15, q = lane >> 4;

    __shared__ __align__(16) unsigned short P_s[4][16][136];
    __shared__ unsigned short rp_s[KL_][72];
    __shared__ unsigned int msk_s[64][5];
    __shared__ float de_h[NDIS_];
    __shared__ float pe[PB_];
    __shared__ int mo_s[KL_];

    const size_t bh = (size_t)(b * H_ + h);
    if (tid < NDIS_) de_h[tid] = dis_embed[tid * H_ + h];
    if (tid < PB_) pe[tid] = polar_emb[tid];
    if (tid < KL_) mo_s[tid] = main_ori[bh * KL_ + tid];
    {
        int xr = tid >> 2, kg = tid & 3;
        msk_s[xr][kg] = mbits[(bh * XL_ + x0 + xr) * 4 + kg];
    }
    __syncthreads();

#pragma unroll
    for (int i = 0; i < 8; ++i) {
        int id = tid + 256 * i;
        int k = id >> 4, ch = id & 15;
        uint2 v = *(const uint2*)&rp16[((size_t)(b * KL_ + k)) * XL_ + x0 + ch * 4];
        int mo = mo_s[k];
        const unsigned short* pv = (const unsigned short*)&v;
        unsigned short outv[4];
#pragma unroll
        for (int j = 0; j < 4; ++j) {
            int np = (((pv[j] >> 8) & 7) - mo) & 7;
            outv[j] = (unsigned short)((pv[j] & 0x7F) | (np << 8));
        }
        *(uint2*)&rp_s[k][ch * 4] = *(uint2*)&outv[0];
    }
    __syncthreads();

    v8s aq = *(const v8s*)&qxh[(size_t)(b * XL_ + x0 + wave * 16 + c) * DIM_ + h * HD_ + q * 8];

    const unsigned short* KkB = &Kk_bf[(size_t)bh * KL_ * HD_];
    v4f S[8];
#pragma unroll
    for (int t = 0; t < 8; ++t) {
        v8s bk = *(const v8s*)&KkB[(size_t)(t * 16 + c) * HD_ + q * 8];
        S[t] = __builtin_amdgcn_mfma_f32_16x16x32_bf16(aq, bk, (v4f){0.f, 0.f, 0.f, 0.f}, 0, 0, 0);
    }

    const int xloc = wave * 16;
    float lr[4] = {0.f, 0.f, 0.f, 0.f};
#pragma unroll
    for (int t = 0; t < 8; ++t) {
#pragma unroll
        for (int r = 0; r < 4; ++r) {
            int krow = t * 16 + c;
            int xrow = q * 4 + r;
            unsigned short rp = rp_s[krow][xloc + xrow];
            int mbit = (msk_s[xloc + xrow][krow >> 5] >> (krow & 31)) & 1;
            float sval = S[t][r] * SCALE_;
            float tval = (mbit ? -25.0f : sval) + de_h[rp & 0x7f] + pe[(rp >> 8) & 7];
            float p = __expf(tval);
            unsigned short pb = f2bf(p);
            P_s[wave][xrow][krow] = pb;
            lr[r] += bf2f(pb);
        }
    }
#pragma unroll
    for (int r = 0; r < 4; ++r) {
#pragma unroll
        for (int m = 1; m < 16; m <<= 1) lr[r] += __shfl_xor(lr[r], m);
    }
    __syncthreads();

    const unsigned short* VTB = &VT_bf[(size_t)bh * HD_ * KL_];
    v4f O0 = {0.f, 0.f, 0.f, 0.f}, O1 = {0.f, 0.f, 0.f, 0.f};
#pragma unroll
    for (int kc = 0; kc < 4; ++kc) {
        v8s ap = *(v8s*)&P_s[wave][c][kc * 32 + q * 8];
        v8s bv0 = *(const v8s*)&VTB[(size_t)c * KL_ + kc * 32 + q * 8];
        v8s bv1 = *(const v8s*)&VTB[(size_t)(16 + c) * KL_ + kc * 32 + q * 8];
        O0 = __builtin_amdgcn_mfma_f32_16x16x32_bf16(ap, bv0, O0, 0, 0, 0);
        O1 = __builtin_amdgcn_mfma_f32_16x16x32_bf16(ap, bv1, O1, 0, 0, 0);
    }

#pragma unroll
    for (int r = 0; r < 4; ++r) {
        int xg = x0 + wave * 16 + q * 4 + r;
        float inv = 1.0f / lr[r];
        size_t obase = (size_t)(b * XL_ + xg) * DIM_ + h * HD_;
        float v0 = O0[r] * inv;
        float v1 = O1[r] * inv;
        unsigned short h0, l0, h1, l1;
        cvt_hilo(v0, h0, l0);
        cvt_hilo(v1, h1, l1);
        oh[obase + c] = h0;
        ol[obase + c] = l0;
        oh[obase + 16 + c] = h1;
        ol[obase + 16 + c] = l1;
    }
}

// ---------------------------------------------------------------------------
extern "C" void kernel_launch(void* const* d_in, const int* in_sizes, int n_in,
                              void* d_out, int out_size, void* d_ws, size_t ws_size,
                              hipStream_t stream) {
    const float* x         = (const float*)d_in[0];
    const float* kernal    = (const float*)d_in[1];
    const int* rd          = (const int*)d_in[2];
    const int* polar_pos   = (const int*)d_in[3];
    const int* att_mask    = (const int*)d_in[4];
    const float* W_qkv     = (const float*)d_in[5];
    const float* dis_embed = (const float*)d_in[6];
    const float* polar_emb = (const float*)d_in[7];
    const float* W_proj    = (const float*)d_in[8];
    const float* b_proj    = (const float*)d_in[9];
    float* out             = (float*)d_out;

    char* base = (char*)d_ws;
    size_t off = 0;
    auto alloc = [&](size_t bytes) { void* p = base + off; off = (off + bytes + 255) & ~255ULL; return p; };
    const size_t MX = (size_t)B_ * XL_;

    unsigned short* VTx = (unsigned short*)alloc((size_t)B_ * H_ * HD_ * XL_ * 2);
    unsigned short* qxh = (unsigned short*)alloc(MX * DIM_ * 2);
    unsigned short* kxh = (unsigned short*)alloc(MX * DIM_ * 2);
    unsigned short* kxl = (unsigned short*)alloc(MX * DIM_ * 2);
    float* binspart  = (float*)alloc((size_t)B_ * H_ * KL_ * NCH2_ * PB_ * 4);
    float* kout_pre  = (float*)alloc((size_t)B_ * KL_ * DIM_ * 4);
    int* main_ori    = (int*)alloc(B_ * H_ * KL_ * 4);
    float* part      = (float*)alloc((size_t)B_ * H_ * KL_ * NS2_ * 36 * 4);
    __hip_bfloat16* Sg = (__hip_bfloat16*)alloc((size_t)B_ * H_ * KL_ * XL_ * 2);
    unsigned short* wph = (unsigned short*)alloc((size_t)DIM_ * DIM_ * 2);
    unsigned short* wpl = (unsigned short*)alloc((size_t)DIM_ * DIM_ * 2);
    unsigned short* wqh = (unsigned short*)alloc((size_t)TDIM_ * DIM_ * 2);
    unsigned short* wql = (unsigned short*)alloc((size_t)TDIM_ * DIM_ * 2);
    unsigned int* mbits = (unsigned int*)alloc((size_t)B_ * H_ * XL_ * (KL_ / 32) * 4);
    unsigned int* pp4   = (unsigned int*)alloc((size_t)B_ * KL_ * (XL_ / 8) * 4);
    unsigned short* rp16 = (unsigned short*)alloc((size_t)B_ * KL_ * XL_ * 2);
    unsigned short* Kqh_g = (unsigned short*)alloc((size_t)B_ * H_ * KL_ * HD_ * 2);
    unsigned short* Kql_g = (unsigned short*)alloc((size_t)B_ * H_ * KL_ * HD_ * 2);
    unsigned short* Kk_bf = (unsigned short*)alloc((size_t)B_ * H_ * KL_ * HD_ * 2);
    unsigned short* VT_bf = (unsigned short*)alloc((size_t)B_ * H_ * HD_ * KL_ * 2);

    // oh/ol alias into Sg region (written by attn_x after flash consumed Sg)
    unsigned short* oh = (unsigned short*)Sg;
    unsigned short* ol = oh + MX * DIM_;

    // --- fused preamble (1 launch) ---
    preamble<<<dim3(NB_PACK_ + NB_WQ_ + NB_WP_ + NB_PP_), 256, 0, stream>>>(
        att_mask, W_qkv, W_proj, polar_pos, rd, mbits, wqh, wql, wph, wpl, pp4, rp16);

    // --- qkv projections (BM=64: 1536 blocks = 6/CU) ---
    gemm_qkv<<<dim3((TDIM_ / 128) * (MX / 64)), 256, 0, stream>>>(
        x, wqh, wql, MX, TDIM_, DIM_, qxh, kxh, kxl, VTx);
    gemm64_qkv<<<dim3(TDIM_ / 64, (B_ * KL_) / 64), 256, 0, stream>>>(
        kernal, W_qkv, Kqh_g, Kql_g, Kk_bf, VT_bf, B_ * KL_, TDIM_, DIM_);

    // --- k-direction ---
    score_bins_mfma4<<<dim3(NCH2_, H_, B_), 256, 0, stream>>>(
        kxh, kxl, Kqh_g, Kql_g, rp16, mbits, dis_embed, Sg, binspart);
    bins_argmax<<<dim3(B_ * H_ * KL_ / 4), 256, 0, stream>>>(binspart, main_ori);
    flash_mfma<<<dim3(NS2_, H_, B_), 256, 0, stream>>>(
        Sg, pp4, VTx, polar_emb, main_ori, part);
    merge_cached<<<dim3(B_ * H_ * KL_ / 8), 256, 0, stream>>>(part, kout_pre);

    // --- x-direction ---
    attn_x_mfma<<<dim3(XL_ / 64, H_, B_), 256, 0, stream>>>(
        qxh, Kk_bf, VT_bf, rp16, mbits, dis_embed, polar_emb, main_ori, oh, ol);

    // --- output projections (BM=64: 512 blocks = 2/CU) ---
    gemm_out<<<dim3((DIM_ / 128) * (MX / 64)), 256, 0, stream>>>(
        oh, ol, wph, wpl, out, b_proj, MX, DIM_, DIM_);
    gemm64<<<dim3(DIM_ / 64, (B_ * KL_) / 64), 256, 0, stream>>>(
        kout_pre, W_proj, out + (size_t)B_ * XL_ * DIM_, b_proj, B_ * KL_, DIM_, DIM_);
}